// Round 3
// baseline (1250.558 us; speedup 1.0000x reference)
//
#include <hip/hip_runtime.h>
#include <hip/hip_bf16.h>
#include <math.h>

#define N_DRUG 20000
#define N_GENE 40000
#define HID 128
#define NEDGE 800000
#define NBATCH 4096

// ---------- helpers ----------
__device__ inline float gelu_exact(float x) {
    return 0.5f * x * (1.f + erff(x * 0.70710678118654752f));
}

// ---------- 1. fuse relation matrices + p_rel scale into k/v projection weights ----------
__global__ void fuse_weights(const float* __restrict__ kW, const float* __restrict__ kb,
                             const float* __restrict__ qW, const float* __restrict__ qb,
                             const float* __restrict__ vW, const float* __restrict__ vb,
                             const float* __restrict__ a_rel, const float* __restrict__ m_rel,
                             const float* __restrict__ p_rel,
                             float* __restrict__ BF, float* __restrict__ BB) {
    int idx = blockIdx.x * 256 + threadIdx.x;          // over 2*2*128*384
    if (idx >= 2 * 2 * 128 * 384) return;
    int j = idx % 384;
    int k = (idx / 384) % 128;
    int lt = idx / (384 * 128);                        // l*2 + t
    const float rs = 0.17677669529663687f;             // 1/sqrt(32)
    float w, b;
    if (j < 128) {
        w = qW[(lt * 128 + k) * 128 + j];
        b = qb[lt * 128 + j];
    } else if (j < 256) {
        int c = j - 128, h = c >> 5, e = c & 31;
        float scale = p_rel[lt * 4 + h] * rs;
        const float* ar = a_rel + ((lt * 4 + h) * 32) * 32;   // [d][e]
        const float* kWr = kW + (lt * 128 + k) * 128 + h * 32;
        const float* kbr = kb + lt * 128 + h * 32;
        float s = 0.f, sb = 0.f;
        for (int d = 0; d < 32; d++) { float a = ar[d * 32 + e]; s += kWr[d] * a; sb += kbr[d] * a; }
        w = s * scale; b = sb * scale;
    } else {
        int c = j - 256, h = c >> 5, e = c & 31;
        const float* mr = m_rel + ((lt * 4 + h) * 32) * 32;
        const float* vWr = vW + (lt * 128 + k) * 128 + h * 32;
        const float* vbr = vb + lt * 128 + h * 32;
        float s = 0.f, sb = 0.f;
        for (int d = 0; d < 32; d++) { float m = mr[d * 32 + e]; s += vWr[d] * m; sb += vbr[d] * m; }
        w = s; b = sb;
    }
    BF[(lt * 128 + k) * 384 + j] = w;
    if (k == 0) BB[lt * 384 + j] = b;
}

// ---------- 2. f32 GEMM: C[N,M] = A[N,128] @ B[128,M] + bias ----------
// mode 0: plain, write C with ldc.
// mode 1: g=sigmoid(*skipPtr); C = relu(g*(acc+bias) + (1-g)*Xcur), ldc=128.
// mode 2: QKV split write: cols<128 -> Q (=C, ld 128); cols>=128 -> KV packed:
//         KV[node*256 + 4*(e/2) + (e&1)] for k elem e, +2 for v elem e.
__global__ __launch_bounds__(256) void gemm128(const float* __restrict__ A, int N,
                                               const float* __restrict__ B, int ldb,
                                               const float* __restrict__ bias,
                                               float* __restrict__ C, int ldc,
                                               int mode, const float* __restrict__ skipPtr,
                                               const float* __restrict__ Xcur,
                                               float* __restrict__ KV) {
    __shared__ float As[128][64];   // [k][row ^ swz(k)]
    __shared__ float Bs[128][64];   // [k][jj]
    const int tid = threadIdx.x;
    const int rowBase = blockIdx.y * 64;
    const int colBase = blockIdx.x * 64;

#pragma unroll
    for (int it = 0; it < 8; ++it) {
        int lin = it * 256 + tid;            // 0..2047 float4 units
        int row = lin >> 5;
        int kq  = lin & 31;
        float4 av = make_float4(0.f, 0.f, 0.f, 0.f);
        int gr = rowBase + row;
        if (gr < N) av = *(const float4*)(A + (size_t)gr * 128 + kq * 4);
        int rs = row ^ ((kq & 7) << 2);
        As[kq * 4 + 0][rs] = av.x;
        As[kq * 4 + 1][rs] = av.y;
        As[kq * 4 + 2][rs] = av.z;
        As[kq * 4 + 3][rs] = av.w;
        int bk = lin >> 4;
        int jq = lin & 15;
        float4 bv = *(const float4*)(B + (size_t)bk * ldb + colBase + jq * 4);
        *(float4*)&Bs[bk][jq * 4] = bv;
    }
    __syncthreads();

    const int tr = tid >> 4, tc = tid & 15;
    float acc[4][4] = {};
#pragma unroll 8
    for (int k = 0; k < 128; k++) {
        int swz = (((k >> 2) & 7) << 2);
        float4 a4 = *(const float4*)&As[k][(tr * 4) ^ swz];
        float4 b4 = *(const float4*)&Bs[k][tc * 4];
        float ar[4] = {a4.x, a4.y, a4.z, a4.w};
        float br[4] = {b4.x, b4.y, b4.z, b4.w};
#pragma unroll
        for (int i = 0; i < 4; i++)
#pragma unroll
            for (int j = 0; j < 4; j++) acc[i][j] += ar[i] * br[j];
    }

    float g = 0.f;
    if (mode == 1) g = 1.f / (1.f + expf(-skipPtr[0]));
    const int gc = colBase + tc * 4;
    float4 bb = *(const float4*)(bias + gc);
    float bias4[4] = {bb.x, bb.y, bb.z, bb.w};
#pragma unroll
    for (int i = 0; i < 4; i++) {
        int gr = rowBase + tr * 4 + i;
        if (gr >= N) continue;
        float o[4];
#pragma unroll
        for (int j = 0; j < 4; j++) o[j] = acc[i][j] + bias4[j];
        if (mode == 1) {
            float4 xv = *(const float4*)(Xcur + (size_t)gr * 128 + gc);
            float xr[4] = {xv.x, xv.y, xv.z, xv.w};
#pragma unroll
            for (int j = 0; j < 4; j++) o[j] = fmaxf(g * o[j] + (1.f - g) * xr[j], 0.f);
            *(float4*)(C + (size_t)gr * 128 + gc) = make_float4(o[0], o[1], o[2], o[3]);
        } else if (mode == 0) {
            *(float4*)(C + (size_t)gr * ldc + gc) = make_float4(o[0], o[1], o[2], o[3]);
        } else {
            if (gc < 128) {
                *(float4*)(C + (size_t)gr * 128 + gc) = make_float4(o[0], o[1], o[2], o[3]);
            } else if (gc < 256) {
                int e = gc - 128;   // k elems e..e+3 -> 2e+{0,1}, 2e+4+{0,1}
                float* base = KV + (size_t)gr * 256 + 2 * e;
                *(float2*)(base + 0) = make_float2(o[0], o[1]);
                *(float2*)(base + 4) = make_float2(o[2], o[3]);
            } else {
                int c = gc - 256;   // v elems c..c+3 -> 2c+2+{0,1}, 2c+6+{0,1}
                float* base = KV + (size_t)gr * 256 + 2 * c;
                *(float2*)(base + 2) = make_float2(o[0], o[1]);
                *(float2*)(base + 6) = make_float2(o[2], o[3]);
            }
        }
    }
}

// ---------- 3. CSR build: histogram ----------
__global__ void hist_kernel(const int* __restrict__ dst, int* __restrict__ cnt) {
    int e = blockIdx.x * 256 + threadIdx.x;
    if (e < NEDGE) atomicAdd(cnt + dst[e], 1);
}

// ---------- 4. CSR build: fast one-block exclusive scan (chunk per thread) ----------
__global__ __launch_bounds__(1024) void exscan_fast(const int* __restrict__ cnt, int n,
                                                    int* __restrict__ rowStart) {
    __shared__ int tmp[1024];
    int t = threadIdx.x;
    int chunk = (n + 1023) >> 10;
    int b = t * chunk; if (b > n) b = n;
    int e = b + chunk; if (e > n) e = n;
    int s = 0;
    for (int i = b; i < e; ++i) s += cnt[i];
    tmp[t] = s;
    __syncthreads();
    for (int off = 1; off < 1024; off <<= 1) {
        int add = (t >= off) ? tmp[t - off] : 0;
        __syncthreads();
        tmp[t] += add;
        __syncthreads();
    }
    int run = tmp[t] - s;    // exclusive prefix of this chunk
    for (int i = b; i < e; ++i) { rowStart[i] = run; run += cnt[i]; }
    if (t == 1023) rowStart[n] = tmp[1023];
}

// ---------- 5. CSR build: scatter src ids by dst ----------
__global__ void scatter_kernel(const int* __restrict__ src, const int* __restrict__ dst,
                               const int* __restrict__ rowStart, int* __restrict__ cursor,
                               int* __restrict__ srcSorted) {
    int e = blockIdx.x * 256 + threadIdx.x;
    if (e < NEDGE) {
        int d = dst[e];
        int pos = rowStart[d] + atomicAdd(cursor + d, 1);
        srcSorted[pos] = src[e];
    }
}

// ---------- 6. fused per-destination attention (packed-KV float4 gather, depth-4 prefetch) ----------
// One 64-lane wave per dst node. Lane l holds dims {2l,2l+1}. Head h = lanes [16h,16h+16).
__global__ __launch_bounds__(256) void fused_attn(const int* __restrict__ rowStart,
                                                  const int* __restrict__ srcSorted,
                                                  const float* __restrict__ Q,    // dst q [N][128]
                                                  const float* __restrict__ KV,   // src packed [N][256]
                                                  float* __restrict__ out, int Ndst) {
    int node = (blockIdx.x * 256 + threadIdx.x) >> 6;
    int lane = threadIdx.x & 63;
    if (node >= Ndst) return;
    float2 q = *(const float2*)(Q + (size_t)node * 128 + 2 * lane);
    int beg = rowStart[node], end = rowStart[node + 1];
    float m = -INFINITY, s = 0.f, ax = 0.f, ay = 0.f;

#define LDKV(jj) (*(const float4*)(KV + ((size_t)__shfl(sids, (jj)) << 8) + (lane << 2)))
#define UPD(kv)                                                        \
    {                                                                  \
        float part = q.x * (kv).x + q.y * (kv).y;                      \
        part += __shfl_xor(part, 1);                                   \
        part += __shfl_xor(part, 2);                                   \
        part += __shfl_xor(part, 4);                                   \
        part += __shfl_xor(part, 8);                                   \
        float mn = fmaxf(m, part);                                     \
        float scl = expf(m - mn);                                      \
        float a = expf(part - mn);                                     \
        s = s * scl + a;                                               \
        ax = ax * scl + a * (kv).z;                                    \
        ay = ay * scl + a * (kv).w;                                    \
        m = mn;                                                        \
    }

    for (int base = beg; base < end; base += 64) {
        int rem = end - base;
        int m64 = rem < 64 ? rem : 64;
        int sids = (base + lane < end) ? srcSorted[base + lane] : 0;
        float4 c0 = LDKV(0);
        float4 c1 = (m64 > 1) ? LDKV(1) : c0;
        float4 c2 = (m64 > 2) ? LDKV(2) : c0;
        float4 c3 = (m64 > 3) ? LDKV(3) : c0;
        int j = 0;
        for (;;) {
            UPD(c0); { int jn = j + 4; if (jn < m64) c0 = LDKV(jn); } if (++j >= m64) break;
            UPD(c1); { int jn = j + 4; if (jn < m64) c1 = LDKV(jn); } if (++j >= m64) break;
            UPD(c2); { int jn = j + 4; if (jn < m64) c2 = LDKV(jn); } if (++j >= m64) break;
            UPD(c3); { int jn = j + 4; if (jn < m64) c3 = LDKV(jn); } if (++j >= m64) break;
        }
    }
#undef LDKV
#undef UPD

    float den = s + 1e-16f;
    float2 r = make_float2(gelu_exact(ax / den), gelu_exact(ay / den));
    *(float2*)(out + (size_t)node * 128 + 2 * lane) = r;
}

// ---------- 7. column sum over genes ----------
__global__ __launch_bounds__(128) void colsum(const float* __restrict__ X, int N,
                                              float* __restrict__ out) {
    int c = threadIdx.x;   // 128
    float s = 0.f;
    for (int r = blockIdx.x; r < N; r += gridDim.x) s += X[(size_t)r * 128 + c];
    atomicAdd(out + c, s);
}

// ---------- 8. predictor MLP ----------
__global__ __launch_bounds__(128) void predictor(const float* __restrict__ Xd,
                                                 const float* __restrict__ gsum,
                                                 const int* __restrict__ didx,
                                                 const float* __restrict__ pW1,
                                                 const float* __restrict__ pb1,
                                                 const float* __restrict__ pW2,
                                                 const float* __restrict__ pb2,
                                                 float* __restrict__ out) {
    __shared__ float comb[256];
    __shared__ float red[128];
    int b = blockIdx.x, t = threadIdx.x;
    int dn = didx[b];
    comb[t]       = Xd[(size_t)dn * 128 + t];
    comb[128 + t] = gsum[t] * (1.f / 40000.f);
    __syncthreads();
    float acc = pb1[t];
    for (int i = 0; i < 256; i++) acc += comb[i] * pW1[i * 128 + t];
    acc = fmaxf(acc, 0.f);
    red[t] = acc * pW2[t];
    __syncthreads();
    for (int sft = 64; sft > 0; sft >>= 1) {
        if (t < sft) red[t] += red[t + sft];
        __syncthreads();
    }
    if (t == 0) out[b] = red[0] + pb2[0];
}

// ---------- launch ----------
extern "C" void kernel_launch(void* const* d_in, const int* in_sizes, int n_in,
                              void* d_out, int out_size, void* d_ws, size_t ws_size,
                              hipStream_t stream) {
    const float* x_drug = (const float*)d_in[0];
    const float* x_gene = (const float*)d_in[1];
    const float* kW = (const float*)d_in[2];
    const float* kb = (const float*)d_in[3];
    const float* qW = (const float*)d_in[4];
    const float* qb = (const float*)d_in[5];
    const float* vW = (const float*)d_in[6];
    const float* vb = (const float*)d_in[7];
    const float* aW = (const float*)d_in[8];
    const float* ab = (const float*)d_in[9];
    const float* skip = (const float*)d_in[10];
    const float* a_rel = (const float*)d_in[11];
    const float* m_rel = (const float*)d_in[12];
    const float* p_rel = (const float*)d_in[13];
    const float* pW1 = (const float*)d_in[14];
    const float* pb1 = (const float*)d_in[15];
    const float* pW2 = (const float*)d_in[16];
    const float* pb2 = (const float*)d_in[17];
    const int* e_dg_s = (const int*)d_in[18];
    const int* e_dg_d = (const int*)d_in[19];
    const int* e_gd_s = (const int*)d_in[20];
    const int* e_gd_d = (const int*)d_in[21];
    const int* drug_idx = (const int*)d_in[22];

    float* ws = (float*)d_ws;
    // workspace layout (float section)
    float* BF    = ws;                                  // 196608
    float* BB    = BF + 196608;                         // 3072
    float* QD    = BB + 3072;                           // 20000*128
    float* QG    = QD + (size_t)N_DRUG * 128;           // 40000*128
    float* KVD   = QG + (size_t)N_GENE * 128;           // 20000*256
    float* KVG   = KVD + (size_t)N_DRUG * 256;          // 40000*256
    float* XD0   = KVG + (size_t)N_GENE * 256;
    float* XD1   = XD0 + (size_t)N_DRUG * 128;
    float* XG0   = XD1 + (size_t)N_DRUG * 128;
    float* XG1   = XG0 + (size_t)N_GENE * 128;
    float* NUMG  = XG1 + (size_t)N_GENE * 128;          // 40000*128
    float* NUMD  = NUMG + (size_t)N_GENE * 128;         // 20000*128
    float* GSUM  = NUMD + (size_t)N_DRUG * 128;         // 128
    // int section (CSR)
    int* rowG  = (int*)(GSUM + 128);                    // 40001
    int* rowD  = rowG + 40001;                          // 20001
    int* cntG  = rowD + 20001;                          // 40000 (also cursor)
    int* cntD  = cntG + 40000;                          // 20000 (also cursor)
    int* srcG  = cntD + 20000;                          // 800000
    int* srcD  = srcG + NEDGE;                          // 800000

    fuse_weights<<<768, 256, 0, stream>>>(kW, kb, qW, qb, vW, vb, a_rel, m_rel, p_rel, BF, BB);

    // ---- build CSR by destination ----
    const int gridE = (NEDGE + 255) / 256;
    hipMemsetAsync(cntG, 0, 40000 * sizeof(int), stream);
    hipMemsetAsync(cntD, 0, 20000 * sizeof(int), stream);
    hist_kernel<<<gridE, 256, 0, stream>>>(e_dg_d, cntG);
    hist_kernel<<<gridE, 256, 0, stream>>>(e_gd_d, cntD);
    exscan_fast<<<1, 1024, 0, stream>>>(cntG, N_GENE, rowG);
    exscan_fast<<<1, 1024, 0, stream>>>(cntD, N_DRUG, rowD);
    hipMemsetAsync(cntG, 0, 40000 * sizeof(int), stream);
    hipMemsetAsync(cntD, 0, 20000 * sizeof(int), stream);
    scatter_kernel<<<gridE, 256, 0, stream>>>(e_dg_s, e_dg_d, rowG, cntG, srcG);
    scatter_kernel<<<gridE, 256, 0, stream>>>(e_gd_s, e_gd_d, rowD, cntD, srcD);

    const float* xd_cur = x_drug;
    const float* xg_cur = x_gene;
    float* xd_bufs[2] = {XD0, XD1};
    float* xg_bufs[2] = {XG0, XG1};

    const int gridD = (N_DRUG + 63) / 64;   // 313
    const int gridG = (N_GENE + 63) / 64;   // 625

    for (int l = 0; l < 2; ++l) {
        const float* BFd = BF + (size_t)(l * 2 + 0) * 49152;
        const float* BFg = BF + (size_t)(l * 2 + 1) * 49152;
        const float* BBd = BB + (size_t)(l * 2 + 0) * 384;
        const float* BBg = BB + (size_t)(l * 2 + 1) * 384;

        gemm128<<<dim3(6, gridD), 256, 0, stream>>>(xd_cur, N_DRUG, BFd, 384, BBd, QD, 128, 2, nullptr, nullptr, KVD);
        gemm128<<<dim3(6, gridG), 256, 0, stream>>>(xg_cur, N_GENE, BFg, 384, BBg, QG, 128, 2, nullptr, nullptr, KVG);

        // edge type 0: drug -> gene  (dst genes): q from QG, k/v from KVD
        fused_attn<<<(N_GENE + 3) / 4, 256, 0, stream>>>(rowG, srcG, QG, KVD, NUMG, N_GENE);
        // edge type 1: gene -> drug  (dst drugs): q from QD, k/v from KVG
        fused_attn<<<(N_DRUG + 3) / 4, 256, 0, stream>>>(rowD, srcD, QD, KVG, NUMD, N_DRUG);

        float* xd_next = xd_bufs[l];
        float* xg_next = xg_bufs[l];
        gemm128<<<dim3(2, gridD), 256, 0, stream>>>(NUMD, N_DRUG, aW + (size_t)(l * 2 + 0) * 16384, 128,
                                                    ab + (size_t)(l * 2 + 0) * 128, xd_next, 128,
                                                    1, skip + (l * 2 + 0), xd_cur, nullptr);
        gemm128<<<dim3(2, gridG), 256, 0, stream>>>(NUMG, N_GENE, aW + (size_t)(l * 2 + 1) * 16384, 128,
                                                    ab + (size_t)(l * 2 + 1) * 128, xg_next, 128,
                                                    1, skip + (l * 2 + 1), xg_cur, nullptr);
        xd_cur = xd_next;
        xg_cur = xg_next;
    }

    hipMemsetAsync(GSUM, 0, 128 * sizeof(float), stream);
    colsum<<<256, 128, 0, stream>>>(xg_cur, N_GENE, GSUM);
    predictor<<<NBATCH, 128, 0, stream>>>(xd_cur, GSUM, drug_idx, pW1, pb1, pW2, pb2, (float*)d_out);
}

// Round 4
// 844.850 us; speedup vs baseline: 1.4802x; 1.4802x over previous
//
#include <hip/hip_runtime.h>
#include <hip/hip_bf16.h>
#include <math.h>

#define N_DRUG 20000
#define N_GENE 40000
#define HID 128
#define NEDGE 800000
#define NBATCH 4096

typedef unsigned short u16;
typedef unsigned int u32;
typedef __attribute__((ext_vector_type(8))) short short8;
typedef __attribute__((ext_vector_type(4))) float f32x4;

// ---------- helpers ----------
__device__ inline float gelu_exact(float x) {
    return 0.5f * x * (1.f + erff(x * 0.70710678118654752f));
}
__device__ inline u16 f2bf(float f) {                 // RNE f32 -> bf16
    u32 u = __float_as_uint(f);
    u += 0x7fffu + ((u >> 16) & 1u);
    return (u16)(u >> 16);
}
__device__ inline float bflo(u32 u) { return __uint_as_float(u << 16); }
__device__ inline float bfhi(u32 u) { return __uint_as_float(u & 0xffff0000u); }

// LDS tile addressing: row-major [row][256B of k], XOR-swizzled within 256B row
#define SWZ(row, kbyte) ((row) * 256 + ((kbyte) ^ (((row) & 7) << 4)))

// ---------- 1. fuse relation matrices into k/v weights; emit transposed bf16 ----------
// BFt[lt][j=384][k=128] bf16 ; BB[lt][384] f32.
// j<128: qW; 128..256: kW @ a_rel * p/sqrt(D); 256..384: vW @ m_rel
__global__ void fuse_weights(const float* __restrict__ kW, const float* __restrict__ kb,
                             const float* __restrict__ qW, const float* __restrict__ qb,
                             const float* __restrict__ vW, const float* __restrict__ vb,
                             const float* __restrict__ a_rel, const float* __restrict__ m_rel,
                             const float* __restrict__ p_rel,
                             u16* __restrict__ BFt, float* __restrict__ BB) {
    int idx = blockIdx.x * 256 + threadIdx.x;          // over 2*2*128*384
    if (idx >= 2 * 2 * 128 * 384) return;
    int j = idx % 384;
    int k = (idx / 384) % 128;
    int lt = idx / (384 * 128);                        // l*2 + t
    const float rs = 0.17677669529663687f;             // 1/sqrt(32)
    float w, b;
    if (j < 128) {
        w = qW[(lt * 128 + k) * 128 + j];
        b = qb[lt * 128 + j];
    } else if (j < 256) {
        int c = j - 128, h = c >> 5, e = c & 31;
        float scale = p_rel[lt * 4 + h] * rs;
        const float* ar = a_rel + ((lt * 4 + h) * 32) * 32;   // [d][e]
        const float* kWr = kW + (lt * 128 + k) * 128 + h * 32;
        const float* kbr = kb + lt * 128 + h * 32;
        float s = 0.f, sb = 0.f;
        for (int d = 0; d < 32; d++) { float a = ar[d * 32 + e]; s += kWr[d] * a; sb += kbr[d] * a; }
        w = s * scale; b = sb * scale;
    } else {
        int c = j - 256, h = c >> 5, e = c & 31;
        const float* mr = m_rel + ((lt * 4 + h) * 32) * 32;
        const float* vWr = vW + (lt * 128 + k) * 128 + h * 32;
        const float* vbr = vb + lt * 128 + h * 32;
        float s = 0.f, sb = 0.f;
        for (int d = 0; d < 32; d++) { float m = mr[d * 32 + e]; s += vWr[d] * m; sb += vbr[d] * m; }
        w = s; b = sb;
    }
    BFt[((size_t)lt * 384 + j) * 128 + k] = f2bf(w);
    if (k == 0) BB[lt * 384 + j] = b;
}

// ---------- 1b. transpose aW to bf16: aWt[lt][j=128][k=128] ----------
__global__ void prep_awt(const float* __restrict__ aW, u16* __restrict__ aWt) {
    int idx = blockIdx.x * 256 + threadIdx.x;          // 2*2*128*128 = 65536
    if (idx >= 65536) return;
    int k = idx & 127, j = (idx >> 7) & 127, lt = idx >> 14;
    aWt[idx] = f2bf(aW[((size_t)lt * 128 + k) * 128 + j]);
}

// ---------- 2. MFMA bf16 GEMM: C[N,M] = A[N,128] @ B[128,M] + bias ----------
// Bt: [M][128] bf16 (transposed weights). Block: 256 thr = 4 waves, tile 128 rows x 64 cols.
// afmt 0: A f32 [N][128]; afmt 1: A bf16 [N][128].
// mode 2 (QKV): col<128 -> Q f32 [N][128]; col 128..255 -> K packed; 256..383 -> V packed
//               into KVo bf16 [N][256] as {k2l,k2l+1,v2l,v2l+1} per lane l.
// mode 1 (out proj): g=sigmoid(*skipPtr); o=relu(g*(acc+bias)+(1-g)*Xcur);
//               write Xn f32 [N][128] and Xb bf16 [N][128].
__global__ __launch_bounds__(256) void gemm_mfma(const float* __restrict__ Af,
                                                 const u16* __restrict__ Ab, int afmt, int N,
                                                 const u16* __restrict__ Bt,
                                                 const float* __restrict__ bias,
                                                 int mode,
                                                 float* __restrict__ Q, u16* __restrict__ KVo,
                                                 const float* __restrict__ skipPtr,
                                                 const float* __restrict__ Xcur,
                                                 float* __restrict__ Xn, u16* __restrict__ Xb) {
    __shared__ char As[128 * 256];   // 128 rows x 128 k bf16, swizzled
    __shared__ char Bs[64 * 256];    // 64 cols x 128 k bf16, swizzled
    const int tid = threadIdx.x;
    const int rowBase = blockIdx.y * 128;
    const int colBase = blockIdx.x * 64;

    if (afmt == 0) {
#pragma unroll
        for (int it = 0; it < 16; ++it) {
            int lin = it * 256 + tid;           // 4096 float4 groups (4 k each)
            int row = lin >> 5, kq = lin & 31;
            int gr = rowBase + row;
            float4 av = make_float4(0.f, 0.f, 0.f, 0.f);
            if (gr < N) av = *(const float4*)(Af + (size_t)gr * 128 + kq * 4);
            uint2 p;
            p.x = (u32)f2bf(av.x) | ((u32)f2bf(av.y) << 16);
            p.y = (u32)f2bf(av.z) | ((u32)f2bf(av.w) << 16);
            *(uint2*)(As + SWZ(row, kq * 8)) = p;
        }
    } else {
#pragma unroll
        for (int it = 0; it < 8; ++it) {
            int lin = it * 256 + tid;           // 2048 groups of 8 bf16 (16B)
            int row = lin >> 4, kq = lin & 15;
            int gr = rowBase + row;
            uint4 v = make_uint4(0, 0, 0, 0);
            if (gr < N) v = *(const uint4*)(Ab + (size_t)gr * 128 + kq * 8);
            *(uint4*)(As + SWZ(row, kq * 16)) = v;
        }
    }
#pragma unroll
    for (int it = 0; it < 4; ++it) {
        int lin = it * 256 + tid;               // 1024 groups
        int j = lin >> 4, kq = lin & 15;
        uint4 v = *(const uint4*)(Bt + (size_t)(colBase + j) * 128 + kq * 8);
        *(uint4*)(Bs + SWZ(j, kq * 16)) = v;
    }
    __syncthreads();

    const int w = tid >> 6, lane = tid & 63;
    const int r15 = lane & 15;
    const int klo = (lane >> 4) << 4;           // this lane's k byte offset (8 bf16)
    f32x4 acc[2][4];
#pragma unroll
    for (int mt = 0; mt < 2; ++mt)
#pragma unroll
        for (int nt = 0; nt < 4; ++nt) acc[mt][nt] = (f32x4){0.f, 0.f, 0.f, 0.f};

#pragma unroll
    for (int kb = 0; kb < 4; ++kb) {
        int kbyte = kb * 64 + klo;
        short8 af[2], bf[4];
#pragma unroll
        for (int mt = 0; mt < 2; ++mt) {
            int row = w * 32 + mt * 16 + r15;
            af[mt] = *(short8*)(As + SWZ(row, kbyte));
        }
#pragma unroll
        for (int nt = 0; nt < 4; ++nt) {
            int col = nt * 16 + r15;
            bf[nt] = *(short8*)(Bs + SWZ(col, kbyte));
        }
#pragma unroll
        for (int mt = 0; mt < 2; ++mt)
#pragma unroll
            for (int nt = 0; nt < 4; ++nt)
                acc[mt][nt] = __builtin_amdgcn_mfma_f32_16x16x32_bf16(af[mt], bf[nt], acc[mt][nt], 0, 0, 0);
    }

    float g = 0.f;
    if (mode == 1) g = 1.f / (1.f + expf(-skipPtr[0]));
#pragma unroll
    for (int nt = 0; nt < 4; ++nt) {
        int col = colBase + nt * 16 + r15;
        float bi = bias[col];
#pragma unroll
        for (int mt = 0; mt < 2; ++mt) {
#pragma unroll
            for (int r = 0; r < 4; ++r) {
                int grow = rowBase + w * 32 + mt * 16 + ((lane >> 4) << 2) + r;
                if (grow >= N) continue;
                float val = acc[mt][nt][r] + bi;
                if (mode == 2) {
                    if (col < 128) {
                        Q[(size_t)grow * 128 + col] = val;
                    } else if (col < 256) {
                        int e = col - 128;
                        KVo[(size_t)grow * 256 + 4 * (e >> 1) + (e & 1)] = f2bf(val);
                    } else {
                        int c = col - 256;
                        KVo[(size_t)grow * 256 + 4 * (c >> 1) + 2 + (c & 1)] = f2bf(val);
                    }
                } else {
                    float x = Xcur[(size_t)grow * 128 + col];
                    float o = fmaxf(g * val + (1.f - g) * x, 0.f);
                    Xn[(size_t)grow * 128 + col] = o;
                    Xb[(size_t)grow * 128 + col] = f2bf(o);
                }
            }
        }
    }
}

// ---------- 3. CSR build: histogram ----------
__global__ void hist_kernel(const int* __restrict__ dst, int* __restrict__ cnt) {
    int e = blockIdx.x * 256 + threadIdx.x;
    if (e < NEDGE) atomicAdd(cnt + dst[e], 1);
}

// ---------- 4. CSR build: one-block exclusive scan (chunk per thread) ----------
__global__ __launch_bounds__(1024) void exscan_fast(const int* __restrict__ cnt, int n,
                                                    int* __restrict__ rowStart) {
    __shared__ int tmp[1024];
    int t = threadIdx.x;
    int chunk = (n + 1023) >> 10;
    int b = t * chunk; if (b > n) b = n;
    int e = b + chunk; if (e > n) e = n;
    int s = 0;
    for (int i = b; i < e; ++i) s += cnt[i];
    tmp[t] = s;
    __syncthreads();
    for (int off = 1; off < 1024; off <<= 1) {
        int add = (t >= off) ? tmp[t - off] : 0;
        __syncthreads();
        tmp[t] += add;
        __syncthreads();
    }
    int run = tmp[t] - s;
    for (int i = b; i < e; ++i) { rowStart[i] = run; run += cnt[i]; }
    if (t == 1023) rowStart[n] = tmp[1023];
}

// ---------- 5. CSR build: scatter src ids by dst ----------
__global__ void scatter_kernel(const int* __restrict__ src, const int* __restrict__ dst,
                               const int* __restrict__ rowStart, int* __restrict__ cursor,
                               int* __restrict__ srcSorted) {
    int e = blockIdx.x * 256 + threadIdx.x;
    if (e < NEDGE) {
        int d = dst[e];
        int pos = rowStart[d] + atomicAdd(cursor + d, 1);
        srcSorted[pos] = src[e];
    }
}

// ---------- 6. fused per-destination attention (bf16 packed-KV uint2 gather) ----------
// One 64-lane wave per dst node. Lane l holds dims {2l,2l+1}. Head h = lanes [16h,16h+16).
// Writes out as bf16 [N][128].
__global__ __launch_bounds__(256) void fused_attn(const int* __restrict__ rowStart,
                                                  const int* __restrict__ srcSorted,
                                                  const float* __restrict__ Q,   // dst q f32 [N][128]
                                                  const u16* __restrict__ KV,    // src bf16 packed [N][256]
                                                  u16* __restrict__ out, int Ndst) {
    int node = (blockIdx.x * 256 + threadIdx.x) >> 6;
    int lane = threadIdx.x & 63;
    if (node >= Ndst) return;
    float2 q = *(const float2*)(Q + (size_t)node * 128 + 2 * lane);
    int beg = rowStart[node], end = rowStart[node + 1];
    float m = -INFINITY, s = 0.f, ax = 0.f, ay = 0.f;

#define LDKV(jj) (*(const uint2*)(KV + (((size_t)__shfl(sids, (jj))) << 8) + (lane << 2)))
#define UPD(u)                                                         \
    {                                                                  \
        float kx = bflo((u).x), ky = bfhi((u).x);                      \
        float vx = bflo((u).y), vy = bfhi((u).y);                      \
        float part = q.x * kx + q.y * ky;                              \
        part += __shfl_xor(part, 1);                                   \
        part += __shfl_xor(part, 2);                                   \
        part += __shfl_xor(part, 4);                                   \
        part += __shfl_xor(part, 8);                                   \
        float mn = fmaxf(m, part);                                     \
        float scl = expf(m - mn);                                      \
        float a = expf(part - mn);                                     \
        s = s * scl + a;                                               \
        ax = ax * scl + a * vx;                                        \
        ay = ay * scl + a * vy;                                        \
        m = mn;                                                        \
    }

    for (int base = beg; base < end; base += 64) {
        int rem = end - base;
        int m64 = rem < 64 ? rem : 64;
        int sids = (base + lane < end) ? srcSorted[base + lane] : 0;
        uint2 c0 = LDKV(0);
        uint2 c1 = (m64 > 1) ? LDKV(1) : c0;
        uint2 c2 = (m64 > 2) ? LDKV(2) : c0;
        uint2 c3 = (m64 > 3) ? LDKV(3) : c0;
        int j = 0;
        for (;;) {
            UPD(c0); { int jn = j + 4; if (jn < m64) c0 = LDKV(jn); } if (++j >= m64) break;
            UPD(c1); { int jn = j + 4; if (jn < m64) c1 = LDKV(jn); } if (++j >= m64) break;
            UPD(c2); { int jn = j + 4; if (jn < m64) c2 = LDKV(jn); } if (++j >= m64) break;
            UPD(c3); { int jn = j + 4; if (jn < m64) c3 = LDKV(jn); } if (++j >= m64) break;
        }
    }
#undef LDKV
#undef UPD

    float den = s + 1e-16f;
    float r0 = gelu_exact(ax / den);
    float r1 = gelu_exact(ay / den);
    *(u32*)(out + (size_t)node * 128 + 2 * lane) = (u32)f2bf(r0) | ((u32)f2bf(r1) << 16);
}

// ---------- 7. column sum over genes (f32 input) ----------
__global__ __launch_bounds__(128) void colsum(const float* __restrict__ X, int N,
                                              float* __restrict__ out) {
    int c = threadIdx.x;
    float s = 0.f;
    for (int r = blockIdx.x; r < N; r += gridDim.x) s += X[(size_t)r * 128 + c];
    atomicAdd(out + c, s);
}

// ---------- 8. predictor MLP ----------
__global__ __launch_bounds__(128) void predictor(const float* __restrict__ Xd,
                                                 const float* __restrict__ gsum,
                                                 const int* __restrict__ didx,
                                                 const float* __restrict__ pW1,
                                                 const float* __restrict__ pb1,
                                                 const float* __restrict__ pW2,
                                                 const float* __restrict__ pb2,
                                                 float* __restrict__ out) {
    __shared__ float comb[256];
    __shared__ float red[128];
    int b = blockIdx.x, t = threadIdx.x;
    int dn = didx[b];
    comb[t]       = Xd[(size_t)dn * 128 + t];
    comb[128 + t] = gsum[t] * (1.f / 40000.f);
    __syncthreads();
    float acc = pb1[t];
    for (int i = 0; i < 256; i++) acc += comb[i] * pW1[i * 128 + t];
    acc = fmaxf(acc, 0.f);
    red[t] = acc * pW2[t];
    __syncthreads();
    for (int sft = 64; sft > 0; sft >>= 1) {
        if (t < sft) red[t] += red[t + sft];
        __syncthreads();
    }
    if (t == 0) out[b] = red[0] + pb2[0];
}

// ---------- launch ----------
extern "C" void kernel_launch(void* const* d_in, const int* in_sizes, int n_in,
                              void* d_out, int out_size, void* d_ws, size_t ws_size,
                              hipStream_t stream) {
    const float* x_drug = (const float*)d_in[0];
    const float* x_gene = (const float*)d_in[1];
    const float* kW = (const float*)d_in[2];
    const float* kb = (const float*)d_in[3];
    const float* qW = (const float*)d_in[4];
    const float* qb = (const float*)d_in[5];
    const float* vW = (const float*)d_in[6];
    const float* vb = (const float*)d_in[7];
    const float* aW = (const float*)d_in[8];
    const float* ab = (const float*)d_in[9];
    const float* skip = (const float*)d_in[10];
    const float* a_rel = (const float*)d_in[11];
    const float* m_rel = (const float*)d_in[12];
    const float* p_rel = (const float*)d_in[13];
    const float* pW1 = (const float*)d_in[14];
    const float* pb1 = (const float*)d_in[15];
    const float* pW2 = (const float*)d_in[16];
    const float* pb2 = (const float*)d_in[17];
    const int* e_dg_s = (const int*)d_in[18];
    const int* e_dg_d = (const int*)d_in[19];
    const int* e_gd_s = (const int*)d_in[20];
    const int* e_gd_d = (const int*)d_in[21];
    const int* drug_idx = (const int*)d_in[22];

    // ---- workspace layout (byte offsets) ----
    char* base = (char*)d_ws;
    size_t off = 0;
    auto alloc = [&](size_t bytes) { char* p = base + off; off += (bytes + 255) & ~(size_t)255; return p; };
    float* QD   = (float*)alloc((size_t)N_DRUG * 128 * 4);
    float* QG   = (float*)alloc((size_t)N_GENE * 128 * 4);
    u16*   KVD  = (u16*)alloc((size_t)N_DRUG * 256 * 2);
    u16*   KVG  = (u16*)alloc((size_t)N_GENE * 256 * 2);
    float* XD0  = (float*)alloc((size_t)N_DRUG * 128 * 4);
    float* XD1  = (float*)alloc((size_t)N_DRUG * 128 * 4);
    float* XG0  = (float*)alloc((size_t)N_GENE * 128 * 4);
    float* XG1  = (float*)alloc((size_t)N_GENE * 128 * 4);
    u16*   XDb  = (u16*)alloc((size_t)N_DRUG * 128 * 2);
    u16*   XGb  = (u16*)alloc((size_t)N_GENE * 128 * 2);
    u16*   NUMD = (u16*)alloc((size_t)N_DRUG * 128 * 2);
    u16*   NUMG = (u16*)alloc((size_t)N_GENE * 128 * 2);
    u16*   BFt  = (u16*)alloc((size_t)2 * 2 * 384 * 128 * 2);
    float* BB   = (float*)alloc((size_t)2 * 2 * 384 * 4);
    u16*   aWt  = (u16*)alloc((size_t)2 * 2 * 128 * 128 * 2);
    float* GSUM = (float*)alloc(128 * 4);
    int* rowG = (int*)alloc(40001 * 4);
    int* rowD = (int*)alloc(20001 * 4);
    int* cntG = (int*)alloc(40000 * 4);
    int* cntD = (int*)alloc(20000 * 4);
    int* srcG = (int*)alloc((size_t)NEDGE * 4);
    int* srcD = (int*)alloc((size_t)NEDGE * 4);

    fuse_weights<<<768, 256, 0, stream>>>(kW, kb, qW, qb, vW, vb, a_rel, m_rel, p_rel, BFt, BB);
    prep_awt<<<256, 256, 0, stream>>>(aW, aWt);

    // ---- build CSR by destination ----
    const int gridE = (NEDGE + 255) / 256;
    hipMemsetAsync(cntG, 0, 40000 * sizeof(int), stream);
    hipMemsetAsync(cntD, 0, 20000 * sizeof(int), stream);
    hist_kernel<<<gridE, 256, 0, stream>>>(e_dg_d, cntG);
    hist_kernel<<<gridE, 256, 0, stream>>>(e_gd_d, cntD);
    exscan_fast<<<1, 1024, 0, stream>>>(cntG, N_GENE, rowG);
    exscan_fast<<<1, 1024, 0, stream>>>(cntD, N_DRUG, rowD);
    hipMemsetAsync(cntG, 0, 40000 * sizeof(int), stream);
    hipMemsetAsync(cntD, 0, 20000 * sizeof(int), stream);
    scatter_kernel<<<gridE, 256, 0, stream>>>(e_dg_s, e_dg_d, rowG, cntG, srcG);
    scatter_kernel<<<gridE, 256, 0, stream>>>(e_gd_s, e_gd_d, rowD, cntD, srcD);

    const float* xd_cur = x_drug;
    const float* xg_cur = x_gene;
    float* xd_bufs[2] = {XD0, XD1};
    float* xg_bufs[2] = {XG0, XG1};

    const int gyD = (N_DRUG + 127) / 128;   // 157
    const int gyG = (N_GENE + 127) / 128;   // 313

    for (int l = 0; l < 2; ++l) {
        const u16* BFtd = BFt + (size_t)(l * 2 + 0) * 384 * 128;
        const u16* BFtg = BFt + (size_t)(l * 2 + 1) * 384 * 128;
        const float* BBd = BB + (size_t)(l * 2 + 0) * 384;
        const float* BBg = BB + (size_t)(l * 2 + 1) * 384;
        int afmt = (l == 0) ? 0 : 1;

        gemm_mfma<<<dim3(6, gyD), 256, 0, stream>>>(xd_cur, XDb, afmt, N_DRUG, BFtd, BBd, 2,
                                                    QD, KVD, nullptr, nullptr, nullptr, nullptr);
        gemm_mfma<<<dim3(6, gyG), 256, 0, stream>>>(xg_cur, XGb, afmt, N_GENE, BFtg, BBg, 2,
                                                    QG, KVG, nullptr, nullptr, nullptr, nullptr);

        // edge type 0: drug -> gene  (dst genes): q from QG, k/v from KVD
        fused_attn<<<(N_GENE + 3) / 4, 256, 0, stream>>>(rowG, srcG, QG, KVD, NUMG, N_GENE);
        // edge type 1: gene -> drug  (dst drugs): q from QD, k/v from KVG
        fused_attn<<<(N_DRUG + 3) / 4, 256, 0, stream>>>(rowD, srcD, QD, KVG, NUMD, N_DRUG);

        float* xd_next = xd_bufs[l];
        float* xg_next = xg_bufs[l];
        gemm_mfma<<<dim3(2, gyD), 256, 0, stream>>>(nullptr, NUMD, 1, N_DRUG,
                                                    aWt + (size_t)(l * 2 + 0) * 16384,
                                                    ab + (size_t)(l * 2 + 0) * 128, 1,
                                                    nullptr, nullptr, skip + (l * 2 + 0), xd_cur,
                                                    xd_next, XDb);
        gemm_mfma<<<dim3(2, gyG), 256, 0, stream>>>(nullptr, NUMG, 1, N_GENE,
                                                    aWt + (size_t)(l * 2 + 1) * 16384,
                                                    ab + (size_t)(l * 2 + 1) * 128, 1,
                                                    nullptr, nullptr, skip + (l * 2 + 1), xg_cur,
                                                    xg_next, XGb);
        xd_cur = xd_next;
        xg_cur = xg_next;
    }

    hipMemsetAsync(GSUM, 0, 128 * sizeof(float), stream);
    colsum<<<256, 128, 0, stream>>>(xg_cur, N_GENE, GSUM);
    predictor<<<NBATCH, 128, 0, stream>>>(xd_cur, GSUM, drug_idx, pW1, pb1, pW2, pb2, (float*)d_out);
}

// Round 5
// 745.296 us; speedup vs baseline: 1.6779x; 1.1336x over previous
//
#include <hip/hip_runtime.h>
#include <hip/hip_bf16.h>
#include <math.h>

#define N_DRUG 20000
#define N_GENE 40000
#define HID 128
#define NEDGE 800000
#define NBATCH 4096

typedef unsigned short u16;
typedef unsigned int u32;
typedef __attribute__((ext_vector_type(8))) short short8;
typedef __attribute__((ext_vector_type(4))) float f32x4;

// ---------- helpers ----------
__device__ inline float gelu_exact(float x) {
    return 0.5f * x * (1.f + erff(x * 0.70710678118654752f));
}
__device__ inline u16 f2bf(float f) {                 // RNE f32 -> bf16
    u32 u = __float_as_uint(f);
    u += 0x7fffu + ((u >> 16) & 1u);
    return (u16)(u >> 16);
}
__device__ inline float bflo(u32 u) { return __uint_as_float(u << 16); }
__device__ inline float bfhi(u32 u) { return __uint_as_float(u & 0xffff0000u); }
__device__ inline u32 pkbf(float a, float b) { return (u32)f2bf(a) | ((u32)f2bf(b) << 16); }

// LDS tile addressing: row-major [row][256B of k], XOR-swizzled within 256B row
#define SWZ(row, kbyte) ((row) * 256 + ((kbyte) ^ (((row) & 7) << 4)))

// ---------- 1. fuse relation matrices into k/v weights; emit transposed bf16 ----------
// BFt[lt][j=384][k=128] bf16 ; BB[lt][384] f32.
// j<128: qW; 128..256: kW @ a_rel * p/sqrt(D); 256..384: vW @ m_rel
__global__ void fuse_weights(const float* __restrict__ kW, const float* __restrict__ kb,
                             const float* __restrict__ qW, const float* __restrict__ qb,
                             const float* __restrict__ vW, const float* __restrict__ vb,
                             const float* __restrict__ a_rel, const float* __restrict__ m_rel,
                             const float* __restrict__ p_rel,
                             u16* __restrict__ BFt, float* __restrict__ BB) {
    int idx = blockIdx.x * 256 + threadIdx.x;          // over 2*2*128*384
    if (idx >= 2 * 2 * 128 * 384) return;
    int j = idx % 384;
    int k = (idx / 384) % 128;
    int lt = idx / (384 * 128);                        // l*2 + t
    const float rs = 0.17677669529663687f;             // 1/sqrt(32)
    float w, b;
    if (j < 128) {
        w = qW[(lt * 128 + k) * 128 + j];
        b = qb[lt * 128 + j];
    } else if (j < 256) {
        int c = j - 128, h = c >> 5, e = c & 31;
        float scale = p_rel[lt * 4 + h] * rs;
        const float* ar = a_rel + ((lt * 4 + h) * 32) * 32;   // [d][e]
        const float* kWr = kW + (lt * 128 + k) * 128 + h * 32;
        const float* kbr = kb + lt * 128 + h * 32;
        float s = 0.f, sb = 0.f;
        for (int d = 0; d < 32; d++) { float a = ar[d * 32 + e]; s += kWr[d] * a; sb += kbr[d] * a; }
        w = s * scale; b = sb * scale;
    } else {
        int c = j - 256, h = c >> 5, e = c & 31;
        const float* mr = m_rel + ((lt * 4 + h) * 32) * 32;
        const float* vWr = vW + (lt * 128 + k) * 128 + h * 32;
        const float* vbr = vb + lt * 128 + h * 32;
        float s = 0.f, sb = 0.f;
        for (int d = 0; d < 32; d++) { float m = mr[d * 32 + e]; s += vWr[d] * m; sb += vbr[d] * m; }
        w = s; b = sb;
    }
    BFt[((size_t)lt * 384 + j) * 128 + k] = f2bf(w);
    if (k == 0) BB[lt * 384 + j] = b;
}

// ---------- 1b. transpose aW to bf16: aWt[lt][j=128][k=128] ----------
__global__ void prep_awt(const float* __restrict__ aW, u16* __restrict__ aWt) {
    int idx = blockIdx.x * 256 + threadIdx.x;          // 2*2*128*128 = 65536
    if (idx >= 65536) return;
    int k = idx & 127, j = (idx >> 7) & 127, lt = idx >> 14;
    aWt[idx] = f2bf(aW[((size_t)lt * 128 + k) * 128 + j]);
}

// ---------- 2. MFMA bf16 GEMM: C[N,M] = A[N,128] @ B[128,M] + bias ----------
// A staged once per block; loop colTiles of 64 cols. Block: 256 thr = 4 waves, 128 rows.
// afmt 0: A f32 [N][128]; afmt 1: A bf16 [N][128].
// mode 2 (QKV): col<128 -> Q f32 [N][128]; col 128..255 -> KV[n*256 + (col-128)] (k);
//               col 256..383 -> KV[n*256 + 128 + (col-256)] (v), bf16.
// mode 1 (out proj): g=sigmoid(*skipPtr); o=relu(g*(acc+bias)+(1-g)*Xcur);
//               write Xn f32 [N][128] and Xb bf16 [N][128].
__global__ __launch_bounds__(256) void gemm_mfma(const float* __restrict__ Af,
                                                 const u16* __restrict__ Ab, int afmt, int N,
                                                 const u16* __restrict__ Bt,
                                                 const float* __restrict__ bias,
                                                 int colTiles, int mode,
                                                 float* __restrict__ Q, u16* __restrict__ KVo,
                                                 const float* __restrict__ skipPtr,
                                                 const float* __restrict__ Xcur,
                                                 float* __restrict__ Xn, u16* __restrict__ Xb) {
    __shared__ char As[128 * 256];   // 128 rows x 128 k bf16, swizzled
    __shared__ char Bs[64 * 256];    // 64 cols x 128 k bf16, swizzled
    const int tid = threadIdx.x;
    const int rowBase = blockIdx.y * 128;

    if (afmt == 0) {
#pragma unroll
        for (int it = 0; it < 16; ++it) {
            int lin = it * 256 + tid;           // 4096 float4 groups (4 k each)
            int row = lin >> 5, kq = lin & 31;
            int gr = rowBase + row;
            float4 av = make_float4(0.f, 0.f, 0.f, 0.f);
            if (gr < N) av = *(const float4*)(Af + (size_t)gr * 128 + kq * 4);
            uint2 p;
            p.x = pkbf(av.x, av.y);
            p.y = pkbf(av.z, av.w);
            *(uint2*)(As + SWZ(row, kq * 8)) = p;
        }
    } else {
#pragma unroll
        for (int it = 0; it < 8; ++it) {
            int lin = it * 256 + tid;           // 2048 groups of 8 bf16 (16B)
            int row = lin >> 4, kq = lin & 15;
            int gr = rowBase + row;
            uint4 v = make_uint4(0, 0, 0, 0);
            if (gr < N) v = *(const uint4*)(Ab + (size_t)gr * 128 + kq * 8);
            *(uint4*)(As + SWZ(row, kq * 16)) = v;
        }
    }

    const int w = tid >> 6, lane = tid & 63;
    const int r15 = lane & 15;
    const int klo = (lane >> 4) << 4;           // this lane's k byte offset (8 bf16)
    float g = 0.f;
    if (mode == 1) g = 1.f / (1.f + expf(-skipPtr[0]));

    for (int ct = 0; ct < colTiles; ++ct) {
        const int colBase = (blockIdx.x * colTiles + ct) * 64;
        __syncthreads();   // Bs free (prev tile fully consumed) / As staged
#pragma unroll
        for (int it = 0; it < 4; ++it) {
            int lin = it * 256 + tid;               // 1024 groups
            int j = lin >> 4, kq = lin & 15;
            uint4 v = *(const uint4*)(Bt + (size_t)(colBase + j) * 128 + kq * 8);
            *(uint4*)(Bs + SWZ(j, kq * 16)) = v;
        }
        __syncthreads();

        f32x4 acc[2][4];
#pragma unroll
        for (int mt = 0; mt < 2; ++mt)
#pragma unroll
            for (int nt = 0; nt < 4; ++nt) acc[mt][nt] = (f32x4){0.f, 0.f, 0.f, 0.f};

#pragma unroll
        for (int kb = 0; kb < 4; ++kb) {
            int kbyte = kb * 64 + klo;
            short8 af[2], bf[4];
#pragma unroll
            for (int mt = 0; mt < 2; ++mt) {
                int row = w * 32 + mt * 16 + r15;
                af[mt] = *(short8*)(As + SWZ(row, kbyte));
            }
#pragma unroll
            for (int nt = 0; nt < 4; ++nt) {
                int col = nt * 16 + r15;
                bf[nt] = *(short8*)(Bs + SWZ(col, kbyte));
            }
#pragma unroll
            for (int mt = 0; mt < 2; ++mt)
#pragma unroll
                for (int nt = 0; nt < 4; ++nt)
                    acc[mt][nt] = __builtin_amdgcn_mfma_f32_16x16x32_bf16(af[mt], bf[nt], acc[mt][nt], 0, 0, 0);
        }

#pragma unroll
        for (int nt = 0; nt < 4; ++nt) {
            int col = colBase + nt * 16 + r15;
            float bi = bias[col];
#pragma unroll
            for (int mt = 0; mt < 2; ++mt) {
#pragma unroll
                for (int r = 0; r < 4; ++r) {
                    int grow = rowBase + w * 32 + mt * 16 + ((lane >> 4) << 2) + r;
                    if (grow >= N) continue;
                    float val = acc[mt][nt][r] + bi;
                    if (mode == 2) {
                        if (col < 128) {
                            Q[(size_t)grow * 128 + col] = val;
                        } else if (col < 256) {
                            KVo[(size_t)grow * 256 + (col - 128)] = f2bf(val);
                        } else {
                            KVo[(size_t)grow * 256 + 128 + (col - 256)] = f2bf(val);
                        }
                    } else {
                        float x = Xcur[(size_t)grow * 128 + col];
                        float o = fmaxf(g * val + (1.f - g) * x, 0.f);
                        Xn[(size_t)grow * 128 + col] = o;
                        Xb[(size_t)grow * 128 + col] = f2bf(o);
                    }
                }
            }
        }
    }
}

// ---------- 3. CSR build: histogram ----------
__global__ void hist_kernel(const int* __restrict__ dst, int* __restrict__ cnt) {
    int e = blockIdx.x * 256 + threadIdx.x;
    if (e < NEDGE) atomicAdd(cnt + dst[e], 1);
}

// ---------- 4. CSR build: one-block exclusive scan (chunk per thread) ----------
__global__ __launch_bounds__(1024) void exscan_fast(const int* __restrict__ cnt, int n,
                                                    int* __restrict__ rowStart) {
    __shared__ int tmp[1024];
    int t = threadIdx.x;
    int chunk = (n + 1023) >> 10;
    int b = t * chunk; if (b > n) b = n;
    int e = b + chunk; if (e > n) e = n;
    int s = 0;
    for (int i = b; i < e; ++i) s += cnt[i];
    tmp[t] = s;
    __syncthreads();
    for (int off = 1; off < 1024; off <<= 1) {
        int add = (t >= off) ? tmp[t - off] : 0;
        __syncthreads();
        tmp[t] += add;
        __syncthreads();
    }
    int run = tmp[t] - s;
    for (int i = b; i < e; ++i) { rowStart[i] = run; run += cnt[i]; }
    if (t == 1023) rowStart[n] = tmp[1023];
}

// ---------- 5. CSR build: scatter src ids by dst ----------
__global__ void scatter_kernel(const int* __restrict__ src, const int* __restrict__ dst,
                               const int* __restrict__ rowStart, int* __restrict__ cursor,
                               int* __restrict__ srcSorted) {
    int e = blockIdx.x * 256 + threadIdx.x;
    if (e < NEDGE) {
        int d = dst[e];
        int pos = rowStart[d] + atomicAdd(cursor + d, 1);
        srcSorted[pos] = src[e];
    }
}

// ---------- 6. fused per-destination attention, 4 edges per wave iteration ----------
// One 64-lane wave per dst node. g=lane>>4 (edge slot), sl=lane&15 (dims [8sl,8sl+8)).
// Head h = sl>>2. KV row: [k[128], v[128]] bf16. No max-tracking (alpha is O(1): shift-
// invariant softmax, exp can't overflow for |alpha| < ~80; measured |alpha| < ~3).
__global__ __launch_bounds__(256) void fused_attn(const int* __restrict__ rowStart,
                                                  const int* __restrict__ srcSorted,
                                                  const float* __restrict__ Q,   // [N][128] f32
                                                  const u16* __restrict__ KV,    // [N][256] bf16
                                                  u16* __restrict__ out, int Ndst) {
    int node = (blockIdx.x * 256 + threadIdx.x) >> 6;
    int lane = threadIdx.x & 63;
    if (node >= Ndst) return;
    const int g = lane >> 4;
    const int sl = lane & 15;

    float qr[8];
    {
        float4 q0 = *(const float4*)(Q + (size_t)node * 128 + sl * 8);
        float4 q1 = *(const float4*)(Q + (size_t)node * 128 + sl * 8 + 4);
        qr[0] = q0.x; qr[1] = q0.y; qr[2] = q0.z; qr[3] = q0.w;
        qr[4] = q1.x; qr[5] = q1.y; qr[6] = q1.z; qr[7] = q1.w;
    }
    int beg = rowStart[node], end = rowStart[node + 1];
    float s = 0.f;
    float acc[8] = {0.f, 0.f, 0.f, 0.f, 0.f, 0.f, 0.f, 0.f};

#define FETCH(t, kk, vv)                                                \
    {                                                                   \
        int sid = __shfl(sids, 4 * (t) + g);                            \
        const u16* rowp = KV + ((size_t)sid << 8);                      \
        kk = *(const uint4*)(rowp + sl * 8);                            \
        vv = *(const uint4*)(rowp + 128 + sl * 8);                      \
    }
#define COMPUTE(t, kk, vv)                                              \
    {                                                                   \
        float part = qr[0] * bflo(kk.x) + qr[1] * bfhi(kk.x)            \
                   + qr[2] * bflo(kk.y) + qr[3] * bfhi(kk.y)            \
                   + qr[4] * bflo(kk.z) + qr[5] * bfhi(kk.z)            \
                   + qr[6] * bflo(kk.w) + qr[7] * bfhi(kk.w);           \
        part += __shfl_xor(part, 1);                                    \
        part += __shfl_xor(part, 2);                                    \
        float a = (base + 4 * (t) + g < end) ? __expf(part) : 0.f;      \
        s += a;                                                         \
        acc[0] += a * bflo(vv.x); acc[1] += a * bfhi(vv.x);             \
        acc[2] += a * bflo(vv.y); acc[3] += a * bfhi(vv.y);             \
        acc[4] += a * bflo(vv.z); acc[5] += a * bfhi(vv.z);             \
        acc[6] += a * bflo(vv.w); acc[7] += a * bfhi(vv.w);             \
    }

    for (int base = beg; base < end; base += 64) {
        int bn = end - base; if (bn > 64) bn = 64;
        int ld = base + lane; if (ld > end - 1) ld = end - 1;
        int sids = srcSorted[ld];
        int nIter = (bn + 3) >> 2;
        uint4 k0, v0, k1, v1;
        FETCH(0, k0, v0);
        for (int t = 0; t < nIter; t += 2) {
            if (t + 1 < nIter) FETCH(t + 1, k1, v1);
            COMPUTE(t, k0, v0);
            if (t + 1 >= nIter) break;
            if (t + 2 < nIter) FETCH(t + 2, k0, v0);
            COMPUTE(t + 1, k1, v1);
        }
    }
#undef FETCH
#undef COMPUTE

    // cross-group reduce (sum over the 4 edge slots)
    s += __shfl_xor(s, 16);
    s += __shfl_xor(s, 32);
#pragma unroll
    for (int j = 0; j < 8; ++j) {
        acc[j] += __shfl_xor(acc[j], 16);
        acc[j] += __shfl_xor(acc[j], 32);
    }
    if (lane < 16) {
        float inv = 1.f / (s + 1e-16f);
        float r0 = gelu_exact(acc[0] * inv), r1 = gelu_exact(acc[1] * inv);
        float r2 = gelu_exact(acc[2] * inv), r3 = gelu_exact(acc[3] * inv);
        float r4 = gelu_exact(acc[4] * inv), r5 = gelu_exact(acc[5] * inv);
        float r6 = gelu_exact(acc[6] * inv), r7 = gelu_exact(acc[7] * inv);
        uint4 o;
        o.x = pkbf(r0, r1); o.y = pkbf(r2, r3); o.z = pkbf(r4, r5); o.w = pkbf(r6, r7);
        *(uint4*)(out + (size_t)node * 128 + sl * 8) = o;
    }
}

// ---------- 7. column sum over genes (f32 input) ----------
__global__ __launch_bounds__(128) void colsum(const float* __restrict__ X, int N,
                                              float* __restrict__ out) {
    int c = threadIdx.x;
    float s = 0.f;
    for (int r = blockIdx.x; r < N; r += gridDim.x) s += X[(size_t)r * 128 + c];
    atomicAdd(out + c, s);
}

// ---------- 8. predictor MLP ----------
__global__ __launch_bounds__(128) void predictor(const float* __restrict__ Xd,
                                                 const float* __restrict__ gsum,
                                                 const int* __restrict__ didx,
                                                 const float* __restrict__ pW1,
                                                 const float* __restrict__ pb1,
                                                 const float* __restrict__ pW2,
                                                 const float* __restrict__ pb2,
                                                 float* __restrict__ out) {
    __shared__ float comb[256];
    __shared__ float red[128];
    int b = blockIdx.x, t = threadIdx.x;
    int dn = didx[b];
    comb[t]       = Xd[(size_t)dn * 128 + t];
    comb[128 + t] = gsum[t] * (1.f / 40000.f);
    __syncthreads();
    float acc = pb1[t];
    for (int i = 0; i < 256; i++) acc += comb[i] * pW1[i * 128 + t];
    acc = fmaxf(acc, 0.f);
    red[t] = acc * pW2[t];
    __syncthreads();
    for (int sft = 64; sft > 0; sft >>= 1) {
        if (t < sft) red[t] += red[t + sft];
        __syncthreads();
    }
    if (t == 0) out[b] = red[0] + pb2[0];
}

// ---------- launch ----------
extern "C" void kernel_launch(void* const* d_in, const int* in_sizes, int n_in,
                              void* d_out, int out_size, void* d_ws, size_t ws_size,
                              hipStream_t stream) {
    const float* x_drug = (const float*)d_in[0];
    const float* x_gene = (const float*)d_in[1];
    const float* kW = (const float*)d_in[2];
    const float* kb = (const float*)d_in[3];
    const float* qW = (const float*)d_in[4];
    const float* qb = (const float*)d_in[5];
    const float* vW = (const float*)d_in[6];
    const float* vb = (const float*)d_in[7];
    const float* aW = (const float*)d_in[8];
    const float* ab = (const float*)d_in[9];
    const float* skip = (const float*)d_in[10];
    const float* a_rel = (const float*)d_in[11];
    const float* m_rel = (const float*)d_in[12];
    const float* p_rel = (const float*)d_in[13];
    const float* pW1 = (const float*)d_in[14];
    const float* pb1 = (const float*)d_in[15];
    const float* pW2 = (const float*)d_in[16];
    const float* pb2 = (const float*)d_in[17];
    const int* e_dg_s = (const int*)d_in[18];
    const int* e_dg_d = (const int*)d_in[19];
    const int* e_gd_s = (const int*)d_in[20];
    const int* e_gd_d = (const int*)d_in[21];
    const int* drug_idx = (const int*)d_in[22];

    // ---- workspace layout ----
    char* base = (char*)d_ws;
    size_t off = 0;
    auto alloc = [&](size_t bytes) { char* p = base + off; off += (bytes + 255) & ~(size_t)255; return p; };
    float* QD   = (float*)alloc((size_t)N_DRUG * 128 * 4);
    float* QG   = (float*)alloc((size_t)N_GENE * 128 * 4);
    u16*   KVD  = (u16*)alloc((size_t)N_DRUG * 256 * 2);
    u16*   KVG  = (u16*)alloc((size_t)N_GENE * 256 * 2);
    float* XD0  = (float*)alloc((size_t)N_DRUG * 128 * 4);
    float* XD1  = (float*)alloc((size_t)N_DRUG * 128 * 4);
    float* XG0  = (float*)alloc((size_t)N_GENE * 128 * 4);
    float* XG1  = (float*)alloc((size_t)N_GENE * 128 * 4);
    u16*   XDb  = (u16*)alloc((size_t)N_DRUG * 128 * 2);
    u16*   XGb  = (u16*)alloc((size_t)N_GENE * 128 * 2);
    u16*   NUMD = (u16*)alloc((size_t)N_DRUG * 128 * 2);
    u16*   NUMG = (u16*)alloc((size_t)N_GENE * 128 * 2);
    u16*   BFt  = (u16*)alloc((size_t)2 * 2 * 384 * 128 * 2);
    float* BB   = (float*)alloc((size_t)2 * 2 * 384 * 4);
    u16*   aWt  = (u16*)alloc((size_t)2 * 2 * 128 * 128 * 2);
    float* GSUM = (float*)alloc(128 * 4);
    int* rowG = (int*)alloc(40001 * 4);
    int* rowD = (int*)alloc(20001 * 4);
    int* cntG = (int*)alloc(40000 * 4);
    int* cntD = (int*)alloc(20000 * 4);
    int* srcG = (int*)alloc((size_t)NEDGE * 4);
    int* srcD = (int*)alloc((size_t)NEDGE * 4);

    fuse_weights<<<768, 256, 0, stream>>>(kW, kb, qW, qb, vW, vb, a_rel, m_rel, p_rel, BFt, BB);
    prep_awt<<<256, 256, 0, stream>>>(aW, aWt);

    // ---- build CSR by destination ----
    const int gridE = (NEDGE + 255) / 256;
    hipMemsetAsync(cntG, 0, 40000 * sizeof(int), stream);
    hipMemsetAsync(cntD, 0, 20000 * sizeof(int), stream);
    hist_kernel<<<gridE, 256, 0, stream>>>(e_dg_d, cntG);
    hist_kernel<<<gridE, 256, 0, stream>>>(e_gd_d, cntD);
    exscan_fast<<<1, 1024, 0, stream>>>(cntG, N_GENE, rowG);
    exscan_fast<<<1, 1024, 0, stream>>>(cntD, N_DRUG, rowD);
    hipMemsetAsync(cntG, 0, 40000 * sizeof(int), stream);
    hipMemsetAsync(cntD, 0, 20000 * sizeof(int), stream);
    scatter_kernel<<<gridE, 256, 0, stream>>>(e_dg_s, e_dg_d, rowG, cntG, srcG);
    scatter_kernel<<<gridE, 256, 0, stream>>>(e_gd_s, e_gd_d, rowD, cntD, srcD);

    const float* xd_cur = x_drug;
    const float* xg_cur = x_gene;
    float* xd_bufs[2] = {XD0, XD1};
    float* xg_bufs[2] = {XG0, XG1};

    const int gyD = (N_DRUG + 127) / 128;   // 157
    const int gyG = (N_GENE + 127) / 128;   // 313

    for (int l = 0; l < 2; ++l) {
        const u16* BFtd = BFt + (size_t)(l * 2 + 0) * 384 * 128;
        const u16* BFtg = BFt + (size_t)(l * 2 + 1) * 384 * 128;
        const float* BBd = BB + (size_t)(l * 2 + 0) * 384;
        const float* BBg = BB + (size_t)(l * 2 + 1) * 384;
        int afmt = (l == 0) ? 0 : 1;

        // QKV: grid.x=2 blocks of 3 col-tiles each (A staged once per block)
        gemm_mfma<<<dim3(2, gyD), 256, 0, stream>>>(xd_cur, XDb, afmt, N_DRUG, BFtd, BBd, 3, 2,
                                                    QD, KVD, nullptr, nullptr, nullptr, nullptr);
        gemm_mfma<<<dim3(2, gyG), 256, 0, stream>>>(xg_cur, XGb, afmt, N_GENE, BFtg, BBg, 3, 2,
                                                    QG, KVG, nullptr, nullptr, nullptr, nullptr);

        // edge type 0: drug -> gene  (dst genes): q from QG, k/v from KVD
        fused_attn<<<(N_GENE + 3) / 4, 256, 0, stream>>>(rowG, srcG, QG, KVD, NUMG, N_GENE);
        // edge type 1: gene -> drug  (dst drugs): q from QD, k/v from KVG
        fused_attn<<<(N_DRUG + 3) / 4, 256, 0, stream>>>(rowD, srcD, QD, KVG, NUMD, N_DRUG);

        float* xd_next = xd_bufs[l];
        float* xg_next = xg_bufs[l];
        gemm_mfma<<<dim3(1, gyD), 256, 0, stream>>>(nullptr, NUMD, 1, N_DRUG,
                                                    aWt + (size_t)(l * 2 + 0) * 16384,
                                                    ab + (size_t)(l * 2 + 0) * 128, 2, 1,
                                                    nullptr, nullptr, skip + (l * 2 + 0), xd_cur,
                                                    xd_next, XDb);
        gemm_mfma<<<dim3(1, gyG), 256, 0, stream>>>(nullptr, NUMG, 1, N_GENE,
                                                    aWt + (size_t)(l * 2 + 1) * 16384,
                                                    ab + (size_t)(l * 2 + 1) * 128, 2, 1,
                                                    nullptr, nullptr, skip + (l * 2 + 1), xg_cur,
                                                    xg_next, XGb);
        xd_cur = xd_next;
        xg_cur = xg_next;
    }

    hipMemsetAsync(GSUM, 0, 128 * sizeof(float), stream);
    colsum<<<256, 128, 0, stream>>>(xg_cur, N_GENE, GSUM);
    predictor<<<NBATCH, 128, 0, stream>>>(xd_cur, GSUM, drug_idx, pW1, pb1, pW2, pb2, (float*)d_out);
}

// Round 6
// 666.980 us; speedup vs baseline: 1.8750x; 1.1174x over previous
//
#include <hip/hip_runtime.h>
#include <hip/hip_bf16.h>
#include <math.h>

#define N_DRUG 20000
#define N_GENE 40000
#define HID 128
#define NEDGE 800000
#define NBATCH 4096

typedef unsigned short u16;
typedef unsigned int u32;
typedef __attribute__((ext_vector_type(8))) short short8;
typedef __attribute__((ext_vector_type(4))) float f32x4;

// ---------- helpers ----------
__device__ inline float gelu_exact(float x) {
    return 0.5f * x * (1.f + erff(x * 0.70710678118654752f));
}
__device__ inline u16 f2bf(float f) {                 // RNE f32 -> bf16
    u32 u = __float_as_uint(f);
    u += 0x7fffu + ((u >> 16) & 1u);
    return (u16)(u >> 16);
}
__device__ inline float bflo(u32 u) { return __uint_as_float(u << 16); }
__device__ inline float bfhi(u32 u) { return __uint_as_float(u & 0xffff0000u); }
__device__ inline u32 pkbf(float a, float b) { return (u32)f2bf(a) | ((u32)f2bf(b) << 16); }

// LDS tile addressing: row-major [row][256B of k], XOR-swizzled within 256B row
#define SWZ(row, kbyte) ((row) * 256 + ((kbyte) ^ (((row) & 7) << 4)))

// ---------- 1. fuse relation matrices into k/v weights; emit transposed bf16 ----------
// BFt[lt][j=384][k=128] bf16 ; BB[lt][384] f32.
// j<128: qW; 128..256: kW @ a_rel * p/sqrt(D); 256..384: vW @ m_rel
__global__ void fuse_weights(const float* __restrict__ kW, const float* __restrict__ kb,
                             const float* __restrict__ qW, const float* __restrict__ qb,
                             const float* __restrict__ vW, const float* __restrict__ vb,
                             const float* __restrict__ a_rel, const float* __restrict__ m_rel,
                             const float* __restrict__ p_rel,
                             u16* __restrict__ BFt, float* __restrict__ BB) {
    int idx = blockIdx.x * 256 + threadIdx.x;          // over 2*2*128*384
    if (idx >= 2 * 2 * 128 * 384) return;
    int j = idx % 384;
    int k = (idx / 384) % 128;
    int lt = idx / (384 * 128);                        // l*2 + t
    const float rs = 0.17677669529663687f;             // 1/sqrt(32)
    float w, b;
    if (j < 128) {
        w = qW[(lt * 128 + k) * 128 + j];
        b = qb[lt * 128 + j];
    } else if (j < 256) {
        int c = j - 128, h = c >> 5, e = c & 31;
        float scale = p_rel[lt * 4 + h] * rs;
        const float* ar = a_rel + ((lt * 4 + h) * 32) * 32;   // [d][e]
        const float* kWr = kW + (lt * 128 + k) * 128 + h * 32;
        const float* kbr = kb + lt * 128 + h * 32;
        float s = 0.f, sb = 0.f;
        for (int d = 0; d < 32; d++) { float a = ar[d * 32 + e]; s += kWr[d] * a; sb += kbr[d] * a; }
        w = s * scale; b = sb * scale;
    } else {
        int c = j - 256, h = c >> 5, e = c & 31;
        const float* mr = m_rel + ((lt * 4 + h) * 32) * 32;
        const float* vWr = vW + (lt * 128 + k) * 128 + h * 32;
        const float* vbr = vb + lt * 128 + h * 32;
        float s = 0.f, sb = 0.f;
        for (int d = 0; d < 32; d++) { float m = mr[d * 32 + e]; s += vWr[d] * m; sb += vbr[d] * m; }
        w = s; b = sb;
    }
    BFt[((size_t)lt * 384 + j) * 128 + k] = f2bf(w);
    if (k == 0) BB[lt * 384 + j] = b;
}

// ---------- 1b. transpose aW to bf16: aWt[lt][j=128][k=128] ----------
__global__ void prep_awt(const float* __restrict__ aW, u16* __restrict__ aWt) {
    int idx = blockIdx.x * 256 + threadIdx.x;          // 2*2*128*128 = 65536
    if (idx >= 65536) return;
    int k = idx & 127, j = (idx >> 7) & 127, lt = idx >> 14;
    aWt[idx] = f2bf(aW[((size_t)lt * 128 + k) * 128 + j]);
}

// ---------- 2. MFMA bf16 GEMM: C[N,M] = A[N,128] @ B[128,M] + bias ----------
// A staged once per block; loop colTiles of 64 cols. Block: 256 thr = 4 waves, 128 rows.
// afmt 0: A f32 [N][128]; afmt 1: A bf16 [N][128].
// mode 2 (QKV): col<128 -> Q f32 [N][128]; col 128..255 -> KV[n*256 + (col-128)] (k);
//               col 256..383 -> KV[n*256 + 128 + (col-256)] (v), bf16.
// mode 1 (out proj): g=sigmoid(*skipPtr); o=relu(g*(acc+bias)+(1-g)*Xcur);
//               write Xn f32 [N][128] and Xb bf16 [N][128].
__global__ __launch_bounds__(256) void gemm_mfma(const float* __restrict__ Af,
                                                 const u16* __restrict__ Ab, int afmt, int N,
                                                 const u16* __restrict__ Bt,
                                                 const float* __restrict__ bias,
                                                 int colTiles, int mode,
                                                 float* __restrict__ Q, u16* __restrict__ KVo,
                                                 const float* __restrict__ skipPtr,
                                                 const float* __restrict__ Xcur,
                                                 float* __restrict__ Xn, u16* __restrict__ Xb) {
    __shared__ char As[128 * 256];   // 128 rows x 128 k bf16, swizzled
    __shared__ char Bs[64 * 256];    // 64 cols x 128 k bf16, swizzled
    const int tid = threadIdx.x;
    const int rowBase = blockIdx.y * 128;

    if (afmt == 0) {
#pragma unroll
        for (int it = 0; it < 16; ++it) {
            int lin = it * 256 + tid;           // 4096 float4 groups (4 k each)
            int row = lin >> 5, kq = lin & 31;
            int gr = rowBase + row;
            float4 av = make_float4(0.f, 0.f, 0.f, 0.f);
            if (gr < N) av = *(const float4*)(Af + (size_t)gr * 128 + kq * 4);
            uint2 p;
            p.x = pkbf(av.x, av.y);
            p.y = pkbf(av.z, av.w);
            *(uint2*)(As + SWZ(row, kq * 8)) = p;
        }
    } else {
#pragma unroll
        for (int it = 0; it < 8; ++it) {
            int lin = it * 256 + tid;           // 2048 groups of 8 bf16 (16B)
            int row = lin >> 4, kq = lin & 15;
            int gr = rowBase + row;
            uint4 v = make_uint4(0, 0, 0, 0);
            if (gr < N) v = *(const uint4*)(Ab + (size_t)gr * 128 + kq * 8);
            *(uint4*)(As + SWZ(row, kq * 16)) = v;
        }
    }

    const int w = tid >> 6, lane = tid & 63;
    const int r15 = lane & 15;
    const int klo = (lane >> 4) << 4;           // this lane's k byte offset (8 bf16)
    float g = 0.f;
    if (mode == 1) g = 1.f / (1.f + expf(-skipPtr[0]));

    for (int ct = 0; ct < colTiles; ++ct) {
        const int colBase = (blockIdx.x * colTiles + ct) * 64;
        __syncthreads();   // Bs free (prev tile fully consumed) / As staged
#pragma unroll
        for (int it = 0; it < 4; ++it) {
            int lin = it * 256 + tid;               // 1024 groups
            int j = lin >> 4, kq = lin & 15;
            uint4 v = *(const uint4*)(Bt + (size_t)(colBase + j) * 128 + kq * 8);
            *(uint4*)(Bs + SWZ(j, kq * 16)) = v;
        }
        __syncthreads();

        f32x4 acc[2][4];
#pragma unroll
        for (int mt = 0; mt < 2; ++mt)
#pragma unroll
            for (int nt = 0; nt < 4; ++nt) acc[mt][nt] = (f32x4){0.f, 0.f, 0.f, 0.f};

#pragma unroll
        for (int kb = 0; kb < 4; ++kb) {
            int kbyte = kb * 64 + klo;
            short8 af[2], bf[4];
#pragma unroll
            for (int mt = 0; mt < 2; ++mt) {
                int row = w * 32 + mt * 16 + r15;
                af[mt] = *(short8*)(As + SWZ(row, kbyte));
            }
#pragma unroll
            for (int nt = 0; nt < 4; ++nt) {
                int col = nt * 16 + r15;
                bf[nt] = *(short8*)(Bs + SWZ(col, kbyte));
            }
#pragma unroll
            for (int mt = 0; mt < 2; ++mt)
#pragma unroll
                for (int nt = 0; nt < 4; ++nt)
                    acc[mt][nt] = __builtin_amdgcn_mfma_f32_16x16x32_bf16(af[mt], bf[nt], acc[mt][nt], 0, 0, 0);
        }

#pragma unroll
        for (int nt = 0; nt < 4; ++nt) {
            int col = colBase + nt * 16 + r15;
            float bi = bias[col];
#pragma unroll
            for (int mt = 0; mt < 2; ++mt) {
#pragma unroll
                for (int r = 0; r < 4; ++r) {
                    int grow = rowBase + w * 32 + mt * 16 + ((lane >> 4) << 2) + r;
                    if (grow >= N) continue;
                    float val = acc[mt][nt][r] + bi;
                    if (mode == 2) {
                        if (col < 128) {
                            Q[(size_t)grow * 128 + col] = val;
                        } else if (col < 256) {
                            KVo[(size_t)grow * 256 + (col - 128)] = f2bf(val);
                        } else {
                            KVo[(size_t)grow * 256 + 128 + (col - 256)] = f2bf(val);
                        }
                    } else {
                        float x = Xcur[(size_t)grow * 128 + col];
                        float o = fmaxf(g * val + (1.f - g) * x, 0.f);
                        Xn[(size_t)grow * 128 + col] = o;
                        Xb[(size_t)grow * 128 + col] = f2bf(o);
                    }
                }
            }
        }
    }
}

// ---------- 3. CSR build: histogram ----------
__global__ void hist_kernel(const int* __restrict__ dst, int* __restrict__ cnt) {
    int e = blockIdx.x * 256 + threadIdx.x;
    if (e < NEDGE) atomicAdd(cnt + dst[e], 1);
}

// ---------- 4. CSR build: hierarchical scan over both count arrays ----------
// 15 blocks: b<10 -> G (n=40000), else D (n=20000). 4096 elems/block, 16/thread.
#define SCAN_NBG 10
#define SCAN_NBD 5
__global__ __launch_bounds__(256) void scan_local(const int* __restrict__ cntG,
                                                  const int* __restrict__ cntD,
                                                  int* __restrict__ outG, int* __restrict__ outD,
                                                  int* __restrict__ bsum) {
    __shared__ int tmp[256];
    int b = blockIdx.x, t = threadIdx.x;
    const int* cnt; int* out; int n; int cbase;
    if (b < SCAN_NBG) { cnt = cntG; out = outG; n = N_GENE; cbase = b * 4096; }
    else { cnt = cntD; out = outD; n = N_DRUG; cbase = (b - SCAN_NBG) * 4096; }
    int base = cbase + t * 16;
    int v[16], s = 0;
#pragma unroll
    for (int i = 0; i < 16; ++i) { int idx = base + i; v[i] = (idx < n) ? cnt[idx] : 0; s += v[i]; }
    tmp[t] = s;
    __syncthreads();
    for (int off = 1; off < 256; off <<= 1) {
        int add = (t >= off) ? tmp[t - off] : 0;
        __syncthreads();
        tmp[t] += add;
        __syncthreads();
    }
    int run = tmp[t] - s;
#pragma unroll
    for (int i = 0; i < 16; ++i) { int idx = base + i; if (idx < n) out[idx] = run; run += v[i]; }
    if (t == 255) bsum[b] = tmp[255];
}

__global__ void scan_bsum(int* __restrict__ bsum) {
    if (threadIdx.x == 0) {
        int run = 0;
        for (int i = 0; i < SCAN_NBG; ++i) { int v = bsum[i]; bsum[i] = run; run += v; }
        run = 0;
        for (int i = SCAN_NBG; i < SCAN_NBG + SCAN_NBD; ++i) { int v = bsum[i]; bsum[i] = run; run += v; }
    }
}

__global__ __launch_bounds__(256) void scan_add(int* __restrict__ outG, int* __restrict__ outD,
                                                const int* __restrict__ bsum) {
    int b = blockIdx.x, t = threadIdx.x;
    int* out; int n; int cbase;
    if (b < SCAN_NBG) { out = outG; n = N_GENE; cbase = b * 4096; }
    else { out = outD; n = N_DRUG; cbase = (b - SCAN_NBG) * 4096; }
    int o = bsum[b];
    int base = cbase + t * 16;
#pragma unroll
    for (int i = 0; i < 16; ++i) { int idx = base + i; if (idx < n) out[idx] += o; }
    if (t == 0 && b == SCAN_NBG - 1) outG[N_GENE] = NEDGE;
    if (t == 0 && b == SCAN_NBG + SCAN_NBD - 1) outD[N_DRUG] = NEDGE;
}

// ---------- 5. CSR build: scatter src ids by dst (count-down cursor = counts array) ----------
__global__ void scatter_kernel(const int* __restrict__ src, const int* __restrict__ dst,
                               const int* __restrict__ rowStart, int* __restrict__ cursor,
                               int* __restrict__ srcSorted) {
    int e = blockIdx.x * 256 + threadIdx.x;
    if (e < NEDGE) {
        int d = dst[e];
        int pos = rowStart[d] + atomicSub(cursor + d, 1) - 1;
        srcSorted[pos] = src[e];
    }
}

// ---------- 6. fused per-destination attention, 4 edges per wave iteration ----------
// One 64-lane wave per dst node. g=lane>>4 (edge slot), sl=lane&15 (dims [8sl,8sl+8)).
// Head h = sl>>2. KV row: [k[128], v[128]] bf16. No max-tracking (alpha is O(1): shift-
// invariant softmax, exp can't overflow for |alpha| < ~80; measured |alpha| < ~3).
__global__ __launch_bounds__(256) void fused_attn(const int* __restrict__ rowStart,
                                                  const int* __restrict__ srcSorted,
                                                  const float* __restrict__ Q,   // [N][128] f32
                                                  const u16* __restrict__ KV,    // [N][256] bf16
                                                  u16* __restrict__ out, int Ndst) {
    int node = (blockIdx.x * 256 + threadIdx.x) >> 6;
    int lane = threadIdx.x & 63;
    if (node >= Ndst) return;
    const int g = lane >> 4;
    const int sl = lane & 15;

    float qr[8];
    {
        float4 q0 = *(const float4*)(Q + (size_t)node * 128 + sl * 8);
        float4 q1 = *(const float4*)(Q + (size_t)node * 128 + sl * 8 + 4);
        qr[0] = q0.x; qr[1] = q0.y; qr[2] = q0.z; qr[3] = q0.w;
        qr[4] = q1.x; qr[5] = q1.y; qr[6] = q1.z; qr[7] = q1.w;
    }
    int beg = rowStart[node], end = rowStart[node + 1];
    float s = 0.f;
    float acc[8] = {0.f, 0.f, 0.f, 0.f, 0.f, 0.f, 0.f, 0.f};

#define FETCH(t, kk, vv)                                                \
    {                                                                   \
        int sid = __shfl(sids, 4 * (t) + g);                            \
        const u16* rowp = KV + ((size_t)sid << 8);                      \
        kk = *(const uint4*)(rowp + sl * 8);                            \
        vv = *(const uint4*)(rowp + 128 + sl * 8);                      \
    }
#define COMPUTE(t, kk, vv)                                              \
    {                                                                   \
        float part = qr[0] * bflo(kk.x) + qr[1] * bfhi(kk.x)            \
                   + qr[2] * bflo(kk.y) + qr[3] * bfhi(kk.y)            \
                   + qr[4] * bflo(kk.z) + qr[5] * bfhi(kk.z)            \
                   + qr[6] * bflo(kk.w) + qr[7] * bfhi(kk.w);           \
        part += __shfl_xor(part, 1);                                    \
        part += __shfl_xor(part, 2);                                    \
        float a = (base + 4 * (t) + g < end) ? __expf(part) : 0.f;      \
        s += a;                                                         \
        acc[0] += a * bflo(vv.x); acc[1] += a * bfhi(vv.x);             \
        acc[2] += a * bflo(vv.y); acc[3] += a * bfhi(vv.y);             \
        acc[4] += a * bflo(vv.z); acc[5] += a * bfhi(vv.z);             \
        acc[6] += a * bflo(vv.w); acc[7] += a * bfhi(vv.w);             \
    }

    for (int base = beg; base < end; base += 64) {
        int bn = end - base; if (bn > 64) bn = 64;
        int ld = base + lane; if (ld > end - 1) ld = end - 1;
        int sids = srcSorted[ld];
        int nIter = (bn + 3) >> 2;
        uint4 k0, v0, k1, v1;
        FETCH(0, k0, v0);
        for (int t = 0; t < nIter; t += 2) {
            if (t + 1 < nIter) FETCH(t + 1, k1, v1);
            COMPUTE(t, k0, v0);
            if (t + 1 >= nIter) break;
            if (t + 2 < nIter) FETCH(t + 2, k0, v0);
            COMPUTE(t + 1, k1, v1);
        }
    }
#undef FETCH
#undef COMPUTE

    // cross-group reduce (sum over the 4 edge slots)
    s += __shfl_xor(s, 16);
    s += __shfl_xor(s, 32);
#pragma unroll
    for (int j = 0; j < 8; ++j) {
        acc[j] += __shfl_xor(acc[j], 16);
        acc[j] += __shfl_xor(acc[j], 32);
    }
    if (lane < 16) {
        float inv = 1.f / (s + 1e-16f);
        float r0 = gelu_exact(acc[0] * inv), r1 = gelu_exact(acc[1] * inv);
        float r2 = gelu_exact(acc[2] * inv), r3 = gelu_exact(acc[3] * inv);
        float r4 = gelu_exact(acc[4] * inv), r5 = gelu_exact(acc[5] * inv);
        float r6 = gelu_exact(acc[6] * inv), r7 = gelu_exact(acc[7] * inv);
        uint4 o;
        o.x = pkbf(r0, r1); o.y = pkbf(r2, r3); o.z = pkbf(r4, r5); o.w = pkbf(r6, r7);
        *(uint4*)(out + (size_t)node * 128 + sl * 8) = o;
    }
}

// ---------- 7. column sum over genes (f32 input) ----------
__global__ __launch_bounds__(128) void colsum(const float* __restrict__ X, int N,
                                              float* __restrict__ out) {
    int c = threadIdx.x;
    float s = 0.f;
    for (int r = blockIdx.x; r < N; r += gridDim.x) s += X[(size_t)r * 128 + c];
    atomicAdd(out + c, s);
}

// ---------- 8. predictor MLP ----------
__global__ __launch_bounds__(128) void predictor(const float* __restrict__ Xd,
                                                 const float* __restrict__ gsum,
                                                 const int* __restrict__ didx,
                                                 const float* __restrict__ pW1,
                                                 const float* __restrict__ pb1,
                                                 const float* __restrict__ pW2,
                                                 const float* __restrict__ pb2,
                                                 float* __restrict__ out) {
    __shared__ float comb[256];
    __shared__ float red[128];
    int b = blockIdx.x, t = threadIdx.x;
    int dn = didx[b];
    comb[t]       = Xd[(size_t)dn * 128 + t];
    comb[128 + t] = gsum[t] * (1.f / 40000.f);
    __syncthreads();
    float acc = pb1[t];
    for (int i = 0; i < 256; i++) acc += comb[i] * pW1[i * 128 + t];
    acc = fmaxf(acc, 0.f);
    red[t] = acc * pW2[t];
    __syncthreads();
    for (int sft = 64; sft > 0; sft >>= 1) {
        if (t < sft) red[t] += red[t + sft];
        __syncthreads();
    }
    if (t == 0) out[b] = red[0] + pb2[0];
}

// ---------- launch ----------
extern "C" void kernel_launch(void* const* d_in, const int* in_sizes, int n_in,
                              void* d_out, int out_size, void* d_ws, size_t ws_size,
                              hipStream_t stream) {
    const float* x_drug = (const float*)d_in[0];
    const float* x_gene = (const float*)d_in[1];
    const float* kW = (const float*)d_in[2];
    const float* kb = (const float*)d_in[3];
    const float* qW = (const float*)d_in[4];
    const float* qb = (const float*)d_in[5];
    const float* vW = (const float*)d_in[6];
    const float* vb = (const float*)d_in[7];
    const float* aW = (const float*)d_in[8];
    const float* ab = (const float*)d_in[9];
    const float* skip = (const float*)d_in[10];
    const float* a_rel = (const float*)d_in[11];
    const float* m_rel = (const float*)d_in[12];
    const float* p_rel = (const float*)d_in[13];
    const float* pW1 = (const float*)d_in[14];
    const float* pb1 = (const float*)d_in[15];
    const float* pW2 = (const float*)d_in[16];
    const float* pb2 = (const float*)d_in[17];
    const int* e_dg_s = (const int*)d_in[18];
    const int* e_dg_d = (const int*)d_in[19];
    const int* e_gd_s = (const int*)d_in[20];
    const int* e_gd_d = (const int*)d_in[21];
    const int* drug_idx = (const int*)d_in[22];

    // ---- workspace layout ----
    char* base = (char*)d_ws;
    size_t off = 0;
    auto alloc = [&](size_t bytes) { char* p = base + off; off += (bytes + 255) & ~(size_t)255; return p; };
    float* QD   = (float*)alloc((size_t)N_DRUG * 128 * 4);
    float* QG   = (float*)alloc((size_t)N_GENE * 128 * 4);
    u16*   KVD  = (u16*)alloc((size_t)N_DRUG * 256 * 2);
    u16*   KVG  = (u16*)alloc((size_t)N_GENE * 256 * 2);
    float* XD0  = (float*)alloc((size_t)N_DRUG * 128 * 4);
    float* XD1  = (float*)alloc((size_t)N_DRUG * 128 * 4);
    float* XG0  = (float*)alloc((size_t)N_GENE * 128 * 4);
    float* XG1  = (float*)alloc((size_t)N_GENE * 128 * 4);
    u16*   XDb  = (u16*)alloc((size_t)N_DRUG * 128 * 2);
    u16*   XGb  = (u16*)alloc((size_t)N_GENE * 128 * 2);
    u16*   NUMD = (u16*)alloc((size_t)N_DRUG * 128 * 2);
    u16*   NUMG = (u16*)alloc((size_t)N_GENE * 128 * 2);
    u16*   BFt  = (u16*)alloc((size_t)2 * 2 * 384 * 128 * 2);
    float* BB   = (float*)alloc((size_t)2 * 2 * 384 * 4);
    u16*   aWt  = (u16*)alloc((size_t)2 * 2 * 128 * 128 * 2);
    float* GSUM = (float*)alloc(128 * 4);
    int* rowG = (int*)alloc(40001 * 4);
    int* rowD = (int*)alloc(20001 * 4);
    int* cntG = (int*)alloc(40000 * 4);
    int* cntD = (int*)alloc(20000 * 4);
    int* bsum = (int*)alloc(64 * 4);
    int* srcG = (int*)alloc((size_t)NEDGE * 4);
    int* srcD = (int*)alloc((size_t)NEDGE * 4);

    fuse_weights<<<768, 256, 0, stream>>>(kW, kb, qW, qb, vW, vb, a_rel, m_rel, p_rel, BFt, BB);
    prep_awt<<<256, 256, 0, stream>>>(aW, aWt);

    // ---- build CSR by destination ----
    const int gridE = (NEDGE + 255) / 256;
    hipMemsetAsync(cntG, 0, 40000 * sizeof(int), stream);
    hipMemsetAsync(cntD, 0, 20000 * sizeof(int), stream);
    hist_kernel<<<gridE, 256, 0, stream>>>(e_dg_d, cntG);
    hist_kernel<<<gridE, 256, 0, stream>>>(e_gd_d, cntD);
    scan_local<<<SCAN_NBG + SCAN_NBD, 256, 0, stream>>>(cntG, cntD, rowG, rowD, bsum);
    scan_bsum<<<1, 64, 0, stream>>>(bsum);
    scan_add<<<SCAN_NBG + SCAN_NBD, 256, 0, stream>>>(rowG, rowD, bsum);
    // counts still intact in cntG/cntD -> use as count-down cursors (no re-memset)
    scatter_kernel<<<gridE, 256, 0, stream>>>(e_dg_s, e_dg_d, rowG, cntG, srcG);
    scatter_kernel<<<gridE, 256, 0, stream>>>(e_gd_s, e_gd_d, rowD, cntD, srcD);

    const float* xd_cur = x_drug;
    const float* xg_cur = x_gene;
    float* xd_bufs[2] = {XD0, XD1};
    float* xg_bufs[2] = {XG0, XG1};

    const int gyD = (N_DRUG + 127) / 128;   // 157
    const int gyG = (N_GENE + 127) / 128;   // 313

    for (int l = 0; l < 2; ++l) {
        const u16* BFtd = BFt + (size_t)(l * 2 + 0) * 384 * 128;
        const u16* BFtg = BFt + (size_t)(l * 2 + 1) * 384 * 128;
        const float* BBd = BB + (size_t)(l * 2 + 0) * 384;
        const float* BBg = BB + (size_t)(l * 2 + 1) * 384;
        int afmt = (l == 0) ? 0 : 1;

        // QKV: grid.x=2 blocks of 3 col-tiles each (A staged once per block)
        gemm_mfma<<<dim3(2, gyD), 256, 0, stream>>>(xd_cur, XDb, afmt, N_DRUG, BFtd, BBd, 3, 2,
                                                    QD, KVD, nullptr, nullptr, nullptr, nullptr);
        gemm_mfma<<<dim3(2, gyG), 256, 0, stream>>>(xg_cur, XGb, afmt, N_GENE, BFtg, BBg, 3, 2,
                                                    QG, KVG, nullptr, nullptr, nullptr, nullptr);

        // edge type 0: drug -> gene  (dst genes): q from QG, k/v from KVD
        fused_attn<<<(N_GENE + 3) / 4, 256, 0, stream>>>(rowG, srcG, QG, KVD, NUMG, N_GENE);
        // edge type 1: gene -> drug  (dst drugs): q from QD, k/v from KVG
        fused_attn<<<(N_DRUG + 3) / 4, 256, 0, stream>>>(rowD, srcD, QD, KVG, NUMD, N_DRUG);

        float* xd_next = xd_bufs[l];
        float* xg_next = xg_bufs[l];
        gemm_mfma<<<dim3(1, gyD), 256, 0, stream>>>(nullptr, NUMD, 1, N_DRUG,
                                                    aWt + (size_t)(l * 2 + 0) * 16384,
                                                    ab + (size_t)(l * 2 + 0) * 128, 2, 1,
                                                    nullptr, nullptr, skip + (l * 2 + 0), xd_cur,
                                                    xd_next, XDb);
        gemm_mfma<<<dim3(1, gyG), 256, 0, stream>>>(nullptr, NUMG, 1, N_GENE,
                                                    aWt + (size_t)(l * 2 + 1) * 16384,
                                                    ab + (size_t)(l * 2 + 1) * 128, 2, 1,
                                                    nullptr, nullptr, skip + (l * 2 + 1), xg_cur,
                                                    xg_next, XGb);
        xd_cur = xd_next;
        xg_cur = xg_next;
    }

    hipMemsetAsync(GSUM, 0, 128 * sizeof(float), stream);
    colsum<<<256, 128, 0, stream>>>(xg_cur, N_GENE, GSUM);
    predictor<<<NBATCH, 128, 0, stream>>>(xd_cur, GSUM, drug_idx, pW1, pb1, pW2, pb2, (float*)d_out);
}

// Round 7
// 629.153 us; speedup vs baseline: 1.9877x; 1.0601x over previous
//
#include <hip/hip_runtime.h>
#include <hip/hip_bf16.h>
#include <math.h>

#define N_DRUG 20000
#define N_GENE 40000
#define HID 128
#define NEDGE 800000
#define NBATCH 4096

typedef unsigned short u16;
typedef unsigned int u32;
typedef __attribute__((ext_vector_type(8))) short short8;
typedef __attribute__((ext_vector_type(4))) float f32x4;

// ---------- helpers ----------
__device__ inline float gelu_exact(float x) {
    return 0.5f * x * (1.f + erff(x * 0.70710678118654752f));
}
__device__ inline u16 f2bf(float f) {                 // RNE f32 -> bf16
    u32 u = __float_as_uint(f);
    u += 0x7fffu + ((u >> 16) & 1u);
    return (u16)(u >> 16);
}
__device__ inline float bflo(u32 u) { return __uint_as_float(u << 16); }
__device__ inline float bfhi(u32 u) { return __uint_as_float(u & 0xffff0000u); }
__device__ inline float bf2f(u16 u) { return __uint_as_float(((u32)u) << 16); }
__device__ inline u32 pkbf(float a, float b) { return (u32)f2bf(a) | ((u32)f2bf(b) << 16); }

// LDS tile addressing: row-major [row][256B of k], XOR-swizzled within 256B row
#define SWZ(row, kbyte) ((row) * 256 + ((kbyte) ^ (((row) & 7) << 4)))

// ---------- 1. fuse relation matrices into k/v weights; emit transposed bf16 ----------
__global__ void fuse_weights(const float* __restrict__ kW, const float* __restrict__ kb,
                             const float* __restrict__ qW, const float* __restrict__ qb,
                             const float* __restrict__ vW, const float* __restrict__ vb,
                             const float* __restrict__ a_rel, const float* __restrict__ m_rel,
                             const float* __restrict__ p_rel,
                             u16* __restrict__ BFt, float* __restrict__ BB) {
    int idx = blockIdx.x * 256 + threadIdx.x;          // over 2*2*128*384
    if (idx >= 2 * 2 * 128 * 384) return;
    int j = idx % 384;
    int k = (idx / 384) % 128;
    int lt = idx / (384 * 128);                        // l*2 + t
    const float rs = 0.17677669529663687f;             // 1/sqrt(32)
    float w, b;
    if (j < 128) {
        w = qW[(lt * 128 + k) * 128 + j];
        b = qb[lt * 128 + j];
    } else if (j < 256) {
        int c = j - 128, h = c >> 5, e = c & 31;
        float scale = p_rel[lt * 4 + h] * rs;
        const float* ar = a_rel + ((lt * 4 + h) * 32) * 32;   // [d][e]
        const float* kWr = kW + (lt * 128 + k) * 128 + h * 32;
        const float* kbr = kb + lt * 128 + h * 32;
        float s = 0.f, sb = 0.f;
        for (int d = 0; d < 32; d++) { float a = ar[d * 32 + e]; s += kWr[d] * a; sb += kbr[d] * a; }
        w = s * scale; b = sb * scale;
    } else {
        int c = j - 256, h = c >> 5, e = c & 31;
        const float* mr = m_rel + ((lt * 4 + h) * 32) * 32;
        const float* vWr = vW + (lt * 128 + k) * 128 + h * 32;
        const float* vbr = vb + lt * 128 + h * 32;
        float s = 0.f, sb = 0.f;
        for (int d = 0; d < 32; d++) { float m = mr[d * 32 + e]; s += vWr[d] * m; sb += vbr[d] * m; }
        w = s; b = sb;
    }
    BFt[((size_t)lt * 384 + j) * 128 + k] = f2bf(w);
    if (k == 0) BB[lt * 384 + j] = b;
}

// ---------- 1b. transpose aW to bf16: aWt[lt][j=128][k=128]; W1a^T bf16 ----------
__global__ void prep_awt(const float* __restrict__ aW, u16* __restrict__ aWt) {
    int idx = blockIdx.x * 256 + threadIdx.x;          // 2*2*128*128 = 65536
    if (idx >= 65536) return;
    int k = idx & 127, j = (idx >> 7) & 127, lt = idx >> 14;
    aWt[idx] = f2bf(aW[((size_t)lt * 128 + k) * 128 + j]);
}
__global__ void prep_w1at(const float* __restrict__ pW1, u16* __restrict__ W1at) {
    int idx = blockIdx.x * 256 + threadIdx.x;          // 16384
    if (idx >= 16384) return;
    int k = idx & 127, j = idx >> 7;                   // k<128 rows of pW1 (drug half)
    W1at[idx] = f2bf(pW1[(size_t)k * 128 + j]);
}

// ---------- 2. merged MFMA bf16 GEMM over both node types ----------
struct GArgs {
    const float* Af0; const float* Af1;   // f32 A (afmt 0)
    const u16* Ab0;  const u16* Ab1;      // bf16 A (afmt 1)
    int N0; int N1; int gy0;
    const u16* Bt0;  const u16* Bt1;      // [M][128] bf16 transposed weights
    const float* bias0; const float* bias1;
    u16* QB0; u16* QB1;                   // mode2: Q bf16 [N][128]
    u16* KV0; u16* KV1;                   // mode2: [k|v] bf16 [N][256]
    const float* skip0; const float* skip1;
    const float* Xc0; const float* Xc1;   // mode1: skip input f32
    float* Xn0; float* Xn1;               // mode1: f32 out (if writeF32)
    u16* Xb0; u16* Xb1;                   // mode1: bf16 out
    int afmt; int colTiles; int mode; int writeF32;
};

__global__ __launch_bounds__(256) void gemm_mfma(GArgs a) {
    __shared__ char As[128 * 256];   // 128 rows x 128 k bf16, swizzled
    __shared__ char Bs[64 * 256];    // 64 cols x 128 k bf16, swizzled
    const int tid = threadIdx.x;
    const int set = (blockIdx.y < (unsigned)a.gy0) ? 0 : 1;
    const int by = set ? (blockIdx.y - a.gy0) : blockIdx.y;
    const int rowBase = by * 128;
    const int N = set ? a.N1 : a.N0;
    const float* Af = set ? a.Af1 : a.Af0;
    const u16* Ab = set ? a.Ab1 : a.Ab0;
    const u16* Bt = set ? a.Bt1 : a.Bt0;
    const float* bias = set ? a.bias1 : a.bias0;
    u16* QB = set ? a.QB1 : a.QB0;
    u16* KV = set ? a.KV1 : a.KV0;
    const float* skipPtr = set ? a.skip1 : a.skip0;
    const float* Xcur = set ? a.Xc1 : a.Xc0;
    float* Xn = set ? a.Xn1 : a.Xn0;
    u16* Xb = set ? a.Xb1 : a.Xb0;

    if (a.afmt == 0) {
#pragma unroll
        for (int it = 0; it < 16; ++it) {
            int lin = it * 256 + tid;           // 4096 float4 groups (4 k each)
            int row = lin >> 5, kq = lin & 31;
            int gr = rowBase + row;
            float4 av = make_float4(0.f, 0.f, 0.f, 0.f);
            if (gr < N) av = *(const float4*)(Af + (size_t)gr * 128 + kq * 4);
            uint2 p;
            p.x = pkbf(av.x, av.y);
            p.y = pkbf(av.z, av.w);
            *(uint2*)(As + SWZ(row, kq * 8)) = p;
        }
    } else {
#pragma unroll
        for (int it = 0; it < 8; ++it) {
            int lin = it * 256 + tid;           // 2048 groups of 8 bf16 (16B)
            int row = lin >> 4, kq = lin & 15;
            int gr = rowBase + row;
            uint4 v = make_uint4(0, 0, 0, 0);
            if (gr < N) v = *(const uint4*)(Ab + (size_t)gr * 128 + kq * 8);
            *(uint4*)(As + SWZ(row, kq * 16)) = v;
        }
    }

    const int w = tid >> 6, lane = tid & 63;
    const int r15 = lane & 15;
    const int klo = (lane >> 4) << 4;           // this lane's k byte offset (8 bf16)
    float g = 0.f;
    if (a.mode == 1) g = 1.f / (1.f + expf(-skipPtr[0]));

    for (int ct = 0; ct < a.colTiles; ++ct) {
        const int colBase = (blockIdx.x * a.colTiles + ct) * 64;
        __syncthreads();   // Bs free / As staged
#pragma unroll
        for (int it = 0; it < 4; ++it) {
            int lin = it * 256 + tid;               // 1024 groups
            int j = lin >> 4, kq = lin & 15;
            uint4 v = *(const uint4*)(Bt + (size_t)(colBase + j) * 128 + kq * 8);
            *(uint4*)(Bs + SWZ(j, kq * 16)) = v;
        }
        __syncthreads();

        f32x4 acc[2][4];
#pragma unroll
        for (int mt = 0; mt < 2; ++mt)
#pragma unroll
            for (int nt = 0; nt < 4; ++nt) acc[mt][nt] = (f32x4){0.f, 0.f, 0.f, 0.f};

#pragma unroll
        for (int kb = 0; kb < 4; ++kb) {
            int kbyte = kb * 64 + klo;
            short8 af[2], bf[4];
#pragma unroll
            for (int mt = 0; mt < 2; ++mt) {
                int row = w * 32 + mt * 16 + r15;
                af[mt] = *(short8*)(As + SWZ(row, kbyte));
            }
#pragma unroll
            for (int nt = 0; nt < 4; ++nt) {
                int col = nt * 16 + r15;
                bf[nt] = *(short8*)(Bs + SWZ(col, kbyte));
            }
#pragma unroll
            for (int mt = 0; mt < 2; ++mt)
#pragma unroll
                for (int nt = 0; nt < 4; ++nt)
                    acc[mt][nt] = __builtin_amdgcn_mfma_f32_16x16x32_bf16(af[mt], bf[nt], acc[mt][nt], 0, 0, 0);
        }

#pragma unroll
        for (int nt = 0; nt < 4; ++nt) {
            int col = colBase + nt * 16 + r15;
            float bi = bias[col];
#pragma unroll
            for (int mt = 0; mt < 2; ++mt) {
#pragma unroll
                for (int r = 0; r < 4; ++r) {
                    int grow = rowBase + w * 32 + mt * 16 + ((lane >> 4) << 2) + r;
                    if (grow >= N) continue;
                    float val = acc[mt][nt][r] + bi;
                    if (a.mode == 2) {
                        if (col < 128) {
                            QB[(size_t)grow * 128 + col] = f2bf(val);
                        } else if (col < 256) {
                            KV[(size_t)grow * 256 + (col - 128)] = f2bf(val);
                        } else {
                            KV[(size_t)grow * 256 + 128 + (col - 256)] = f2bf(val);
                        }
                    } else {
                        float x = Xcur[(size_t)grow * 128 + col];
                        float o = fmaxf(g * val + (1.f - g) * x, 0.f);
                        if (a.writeF32) Xn[(size_t)grow * 128 + col] = o;
                        Xb[(size_t)grow * 128 + col] = f2bf(o);
                    }
                }
            }
        }
    }
}

// ---------- 3. CSR build: merged histogram ----------
__global__ void hist2(const int* __restrict__ d0, int* __restrict__ c0,
                      const int* __restrict__ d1, int* __restrict__ c1, int gridE) {
    int b = blockIdx.x;
    const int* d; int* c; int bb;
    if (b < gridE) { d = d0; c = c0; bb = b; } else { d = d1; c = c1; bb = b - gridE; }
    int e = bb * 256 + threadIdx.x;
    if (e < NEDGE) atomicAdd(c + d[e], 1);
}

// ---------- 4. CSR build: hierarchical scan over both count arrays ----------
#define SCAN_NBG 10
#define SCAN_NBD 5
__global__ __launch_bounds__(256) void scan_local(const int* __restrict__ cntG,
                                                  const int* __restrict__ cntD,
                                                  int* __restrict__ outG, int* __restrict__ outD,
                                                  int* __restrict__ bsum) {
    __shared__ int tmp[256];
    int b = blockIdx.x, t = threadIdx.x;
    const int* cnt; int* out; int n; int cbase;
    if (b < SCAN_NBG) { cnt = cntG; out = outG; n = N_GENE; cbase = b * 4096; }
    else { cnt = cntD; out = outD; n = N_DRUG; cbase = (b - SCAN_NBG) * 4096; }
    int base = cbase + t * 16;
    int v[16], s = 0;
#pragma unroll
    for (int i = 0; i < 16; ++i) { int idx = base + i; v[i] = (idx < n) ? cnt[idx] : 0; s += v[i]; }
    tmp[t] = s;
    __syncthreads();
    for (int off = 1; off < 256; off <<= 1) {
        int add = (t >= off) ? tmp[t - off] : 0;
        __syncthreads();
        tmp[t] += add;
        __syncthreads();
    }
    int run = tmp[t] - s;
#pragma unroll
    for (int i = 0; i < 16; ++i) { int idx = base + i; if (idx < n) out[idx] = run; run += v[i]; }
    if (t == 255) bsum[b] = tmp[255];
}

__global__ void scan_bsum(int* __restrict__ bsum) {
    if (threadIdx.x == 0) {
        int run = 0;
        for (int i = 0; i < SCAN_NBG; ++i) { int v = bsum[i]; bsum[i] = run; run += v; }
        run = 0;
        for (int i = SCAN_NBG; i < SCAN_NBG + SCAN_NBD; ++i) { int v = bsum[i]; bsum[i] = run; run += v; }
    }
}

__global__ __launch_bounds__(256) void scan_add(int* __restrict__ outG, int* __restrict__ outD,
                                                const int* __restrict__ bsum) {
    int b = blockIdx.x, t = threadIdx.x;
    int* out; int n; int cbase;
    if (b < SCAN_NBG) { out = outG; n = N_GENE; cbase = b * 4096; }
    else { out = outD; n = N_DRUG; cbase = (b - SCAN_NBG) * 4096; }
    int o = bsum[b];
    int base = cbase + t * 16;
#pragma unroll
    for (int i = 0; i < 16; ++i) { int idx = base + i; if (idx < n) out[idx] += o; }
    if (t == 0 && b == SCAN_NBG - 1) outG[N_GENE] = NEDGE;
    if (t == 0 && b == SCAN_NBG + SCAN_NBD - 1) outD[N_DRUG] = NEDGE;
}

// ---------- 5. CSR build: merged scatter (count-down cursor) ----------
__global__ void scatter2(const int* __restrict__ s0, const int* __restrict__ d0,
                         const int* __restrict__ r0, int* __restrict__ cur0, int* __restrict__ o0,
                         const int* __restrict__ s1, const int* __restrict__ d1,
                         const int* __restrict__ r1, int* __restrict__ cur1, int* __restrict__ o1,
                         int gridE) {
    int b = blockIdx.x;
    const int *src, *dst, *row; int *cursor, *outp; int bb;
    if (b < gridE) { src = s0; dst = d0; row = r0; cursor = cur0; outp = o0; bb = b; }
    else { src = s1; dst = d1; row = r1; cursor = cur1; outp = o1; bb = b - gridE; }
    int e = bb * 256 + threadIdx.x;
    if (e < NEDGE) {
        int d = dst[e];
        int pos = row[d] + atomicSub(cursor + d, 1) - 1;
        outp[pos] = src[e];
    }
}

// ---------- 6. merged fused attention (both edge types), bf16 Q, 4-deep prefetch ----------
// One 64-lane wave per dst node. g=lane>>4 (edge slot), sl=lane&15 (dims [8sl,8sl+8)).
// No max-tracking (softmax shift-invariant; |alpha| ~ 3 << 80).
__global__ __launch_bounds__(256) void fused_attn(const int* __restrict__ rowG,
                                                  const int* __restrict__ srcG,
                                                  const u16* __restrict__ QGB,
                                                  const u16* __restrict__ KVD,
                                                  u16* __restrict__ NUMG,
                                                  const int* __restrict__ rowD,
                                                  const int* __restrict__ srcD,
                                                  const u16* __restrict__ QDB,
                                                  const u16* __restrict__ KVG,
                                                  u16* __restrict__ NUMD) {
    int node = (blockIdx.x * 256 + threadIdx.x) >> 6;
    int lane = threadIdx.x & 63;
    const int* rowStart; const int* srcSorted; const u16* Qb; const u16* KV; u16* out; int nd;
    if (node < N_GENE) { rowStart = rowG; srcSorted = srcG; Qb = QGB; KV = KVD; out = NUMG; nd = node; }
    else if (node < N_GENE + N_DRUG) { rowStart = rowD; srcSorted = srcD; Qb = QDB; KV = KVG; out = NUMD; nd = node - N_GENE; }
    else return;
    const int g = lane >> 4;
    const int sl = lane & 15;

    float qr[8];
    {
        uint4 qv = *(const uint4*)(Qb + (size_t)nd * 128 + sl * 8);
        qr[0] = bflo(qv.x); qr[1] = bfhi(qv.x);
        qr[2] = bflo(qv.y); qr[3] = bfhi(qv.y);
        qr[4] = bflo(qv.z); qr[5] = bfhi(qv.z);
        qr[6] = bflo(qv.w); qr[7] = bfhi(qv.w);
    }
    int beg = rowStart[nd], end = rowStart[nd + 1];
    float s = 0.f;
    float acc[8] = {0.f, 0.f, 0.f, 0.f, 0.f, 0.f, 0.f, 0.f};

#define FETCH(t, kk, vv)                                                \
    {                                                                   \
        int sid = __shfl(sids, 4 * (t) + g);                            \
        const u16* rowp = KV + ((size_t)sid << 8);                      \
        kk = *(const uint4*)(rowp + sl * 8);                            \
        vv = *(const uint4*)(rowp + 128 + sl * 8);                      \
    }
#define COMPUTE(t, kk, vv)                                              \
    {                                                                   \
        float part = qr[0] * bflo(kk.x) + qr[1] * bfhi(kk.x)            \
                   + qr[2] * bflo(kk.y) + qr[3] * bfhi(kk.y)            \
                   + qr[4] * bflo(kk.z) + qr[5] * bfhi(kk.z)            \
                   + qr[6] * bflo(kk.w) + qr[7] * bfhi(kk.w);           \
        part += __shfl_xor(part, 1);                                    \
        part += __shfl_xor(part, 2);                                    \
        float a = (base + 4 * (t) + g < end) ? __expf(part) : 0.f;      \
        s += a;                                                         \
        acc[0] += a * bflo(vv.x); acc[1] += a * bfhi(vv.x);             \
        acc[2] += a * bflo(vv.y); acc[3] += a * bfhi(vv.y);             \
        acc[4] += a * bflo(vv.z); acc[5] += a * bfhi(vv.z);             \
        acc[6] += a * bflo(vv.w); acc[7] += a * bfhi(vv.w);             \
    }

    for (int base = beg; base < end; base += 64) {
        int bn = end - base; if (bn > 64) bn = 64;
        int ld = base + lane; if (ld > end - 1) ld = end - 1;
        int sids = srcSorted[ld];
        int nIter = (bn + 3) >> 2;
        uint4 k0, v0, k1, v1, k2, v2, k3, v3;
        FETCH(0, k0, v0);
        if (1 < nIter) FETCH(1, k1, v1);
        if (2 < nIter) FETCH(2, k2, v2);
        if (3 < nIter) FETCH(3, k3, v3);
        int t = 0;
        for (;;) {
            COMPUTE(t, k0, v0); { int jn = t + 4; if (jn < nIter) FETCH(jn, k0, v0); } if (++t >= nIter) break;
            COMPUTE(t, k1, v1); { int jn = t + 4; if (jn < nIter) FETCH(jn, k1, v1); } if (++t >= nIter) break;
            COMPUTE(t, k2, v2); { int jn = t + 4; if (jn < nIter) FETCH(jn, k2, v2); } if (++t >= nIter) break;
            COMPUTE(t, k3, v3); { int jn = t + 4; if (jn < nIter) FETCH(jn, k3, v3); } if (++t >= nIter) break;
        }
    }
#undef FETCH
#undef COMPUTE

    // cross-group reduce (sum over the 4 edge slots)
    s += __shfl_xor(s, 16);
    s += __shfl_xor(s, 32);
#pragma unroll
    for (int j = 0; j < 8; ++j) {
        acc[j] += __shfl_xor(acc[j], 16);
        acc[j] += __shfl_xor(acc[j], 32);
    }
    if (lane < 16) {
        float inv = 1.f / (s + 1e-16f);
        float r0 = gelu_exact(acc[0] * inv), r1 = gelu_exact(acc[1] * inv);
        float r2 = gelu_exact(acc[2] * inv), r3 = gelu_exact(acc[3] * inv);
        float r4 = gelu_exact(acc[4] * inv), r5 = gelu_exact(acc[5] * inv);
        float r6 = gelu_exact(acc[6] * inv), r7 = gelu_exact(acc[7] * inv);
        uint4 o;
        o.x = pkbf(r0, r1); o.y = pkbf(r2, r3); o.z = pkbf(r4, r5); o.w = pkbf(r6, r7);
        *(uint4*)(out + (size_t)nd * 128 + sl * 8) = o;
    }
}

// ---------- 7. column sum over genes (bf16 input) ----------
__global__ __launch_bounds__(128) void colsum_bf(const u16* __restrict__ X, int N,
                                                 float* __restrict__ out) {
    int c = threadIdx.x;
    float s = 0.f;
    for (int r = blockIdx.x; r < N; r += gridDim.x) s += bf2f(X[(size_t)r * 128 + c]);
    atomicAdd(out + c, s);
}

// ---------- 8a. c2 = gene_mean @ W1b + pb1 ----------
__global__ __launch_bounds__(128) void c2_kernel(const float* __restrict__ gsum,
                                                 const float* __restrict__ pW1,
                                                 const float* __restrict__ pb1,
                                                 float* __restrict__ c2) {
    int j = threadIdx.x;
    float s = pb1[j];
    for (int k = 0; k < 128; ++k)
        s += gsum[k] * (1.f / 40000.f) * pW1[(size_t)(128 + k) * 128 + j];
    c2[j] = s;
}

// ---------- 8b. predictor: out = relu(xd[didx] @ W1a + c2) @ pW2 + pb2 ----------
// Block: 256 thr = 4 waves, 128 batch rows. Grid 32.
__global__ __launch_bounds__(256) void predictor_mfma(const u16* __restrict__ Xdb,
                                                      const int* __restrict__ didx,
                                                      const u16* __restrict__ W1at,
                                                      const float* __restrict__ c2,
                                                      const float* __restrict__ pW2,
                                                      const float* __restrict__ pb2,
                                                      float* __restrict__ out) {
    __shared__ char As[128 * 256];
    __shared__ char Bs[128 * 256];
    const int tid = threadIdx.x;
    const int rowBase = blockIdx.x * 128;

#pragma unroll
    for (int it = 0; it < 8; ++it) {
        int lin = it * 256 + tid;               // 2048 groups (row, 8 bf16)
        int row = lin >> 4, kq = lin & 15;
        int dn = didx[rowBase + row];
        uint4 v = *(const uint4*)(Xdb + (size_t)dn * 128 + kq * 8);
        *(uint4*)(As + SWZ(row, kq * 16)) = v;
        uint4 wv = *(const uint4*)(W1at + (size_t)row * 128 + kq * 8);
        *(uint4*)(Bs + SWZ(row, kq * 16)) = wv;
    }
    __syncthreads();

    const int w = tid >> 6, lane = tid & 63;
    const int r15 = lane & 15;
    const int klo = (lane >> 4) << 4;
    f32x4 acc[2][8];
#pragma unroll
    for (int mt = 0; mt < 2; ++mt)
#pragma unroll
        for (int nt = 0; nt < 8; ++nt) acc[mt][nt] = (f32x4){0.f, 0.f, 0.f, 0.f};

#pragma unroll
    for (int kb = 0; kb < 4; ++kb) {
        int kbyte = kb * 64 + klo;
        short8 af[2], bf[8];
#pragma unroll
        for (int mt = 0; mt < 2; ++mt) af[mt] = *(short8*)(As + SWZ(w * 32 + mt * 16 + r15, kbyte));
#pragma unroll
        for (int nt = 0; nt < 8; ++nt) bf[nt] = *(short8*)(Bs + SWZ(nt * 16 + r15, kbyte));
#pragma unroll
        for (int mt = 0; mt < 2; ++mt)
#pragma unroll
            for (int nt = 0; nt < 8; ++nt)
                acc[mt][nt] = __builtin_amdgcn_mfma_f32_16x16x32_bf16(af[mt], bf[nt], acc[mt][nt], 0, 0, 0);
    }

    float c2v[8], w2v[8];
#pragma unroll
    for (int nt = 0; nt < 8; ++nt) {
        int col = nt * 16 + r15;
        c2v[nt] = c2[col];
        w2v[nt] = pW2[col];
    }
    float bias2 = pb2[0];
#pragma unroll
    for (int mt = 0; mt < 2; ++mt) {
#pragma unroll
        for (int r = 0; r < 4; ++r) {
            float rsum = 0.f;
#pragma unroll
            for (int nt = 0; nt < 8; ++nt)
                rsum += fmaxf(acc[mt][nt][r] + c2v[nt], 0.f) * w2v[nt];
            rsum += __shfl_xor(rsum, 1);
            rsum += __shfl_xor(rsum, 2);
            rsum += __shfl_xor(rsum, 4);
            rsum += __shfl_xor(rsum, 8);
            if (r15 == 0)
                out[rowBase + w * 32 + mt * 16 + ((lane >> 4) << 2) + r] = rsum + bias2;
        }
    }
}

// ---------- launch ----------
extern "C" void kernel_launch(void* const* d_in, const int* in_sizes, int n_in,
                              void* d_out, int out_size, void* d_ws, size_t ws_size,
                              hipStream_t stream) {
    const float* x_drug = (const float*)d_in[0];
    const float* x_gene = (const float*)d_in[1];
    const float* kW = (const float*)d_in[2];
    const float* kb = (const float*)d_in[3];
    const float* qW = (const float*)d_in[4];
    const float* qb = (const float*)d_in[5];
    const float* vW = (const float*)d_in[6];
    const float* vb = (const float*)d_in[7];
    const float* aW = (const float*)d_in[8];
    const float* ab = (const float*)d_in[9];
    const float* skip = (const float*)d_in[10];
    const float* a_rel = (const float*)d_in[11];
    const float* m_rel = (const float*)d_in[12];
    const float* p_rel = (const float*)d_in[13];
    const float* pW1 = (const float*)d_in[14];
    const float* pb1 = (const float*)d_in[15];
    const float* pW2 = (const float*)d_in[16];
    const float* pb2 = (const float*)d_in[17];
    const int* e_dg_s = (const int*)d_in[18];
    const int* e_dg_d = (const int*)d_in[19];
    const int* e_gd_s = (const int*)d_in[20];
    const int* e_gd_d = (const int*)d_in[21];
    const int* drug_idx = (const int*)d_in[22];

    // ---- workspace layout ----
    char* base = (char*)d_ws;
    size_t off = 0;
    auto alloc = [&](size_t bytes) { char* p = base + off; off += (bytes + 255) & ~(size_t)255; return p; };
    u16*   QDB  = (u16*)alloc((size_t)N_DRUG * 128 * 2);
    u16*   QGB  = (u16*)alloc((size_t)N_GENE * 128 * 2);
    u16*   KVD  = (u16*)alloc((size_t)N_DRUG * 256 * 2);
    u16*   KVG  = (u16*)alloc((size_t)N_GENE * 256 * 2);
    float* XD0  = (float*)alloc((size_t)N_DRUG * 128 * 4);
    float* XG0  = (float*)alloc((size_t)N_GENE * 128 * 4);
    u16*   XDb  = (u16*)alloc((size_t)N_DRUG * 128 * 2);
    u16*   XGb  = (u16*)alloc((size_t)N_GENE * 128 * 2);
    u16*   NUMD = (u16*)alloc((size_t)N_DRUG * 128 * 2);
    u16*   NUMG = (u16*)alloc((size_t)N_GENE * 128 * 2);
    u16*   BFt  = (u16*)alloc((size_t)2 * 2 * 384 * 128 * 2);
    float* BB   = (float*)alloc((size_t)2 * 2 * 384 * 4);
    u16*   aWt  = (u16*)alloc((size_t)2 * 2 * 128 * 128 * 2);
    u16*   W1at = (u16*)alloc((size_t)128 * 128 * 2);
    float* GSUM = (float*)alloc(128 * 4);
    float* C2   = (float*)alloc(128 * 4);
    int* rowG = (int*)alloc(40001 * 4);
    int* rowD = (int*)alloc(20001 * 4);
    int* cntG = (int*)alloc(40000 * 4);
    int* cntD = (int*)alloc(20000 * 4);
    int* bsum = (int*)alloc(64 * 4);
    int* srcG = (int*)alloc((size_t)NEDGE * 4);
    int* srcD = (int*)alloc((size_t)NEDGE * 4);

    fuse_weights<<<768, 256, 0, stream>>>(kW, kb, qW, qb, vW, vb, a_rel, m_rel, p_rel, BFt, BB);
    prep_awt<<<256, 256, 0, stream>>>(aW, aWt);
    prep_w1at<<<64, 256, 0, stream>>>(pW1, W1at);

    // ---- build CSR by destination ----
    const int gridE = (NEDGE + 255) / 256;
    hipMemsetAsync(cntG, 0, 40000 * sizeof(int), stream);
    hipMemsetAsync(cntD, 0, 20000 * sizeof(int), stream);
    hist2<<<2 * gridE, 256, 0, stream>>>(e_dg_d, cntG, e_gd_d, cntD, gridE);
    scan_local<<<SCAN_NBG + SCAN_NBD, 256, 0, stream>>>(cntG, cntD, rowG, rowD, bsum);
    scan_bsum<<<1, 64, 0, stream>>>(bsum);
    scan_add<<<SCAN_NBG + SCAN_NBD, 256, 0, stream>>>(rowG, rowD, bsum);
    scatter2<<<2 * gridE, 256, 0, stream>>>(e_dg_s, e_dg_d, rowG, cntG, srcG,
                                            e_gd_s, e_gd_d, rowD, cntD, srcD, gridE);

    const int gyD = (N_DRUG + 127) / 128;   // 157
    const int gyG = (N_GENE + 127) / 128;   // 313
    const int gyT = gyD + gyG;              // 470

    const float* xd_cur = x_drug;
    const float* xg_cur = x_gene;

    for (int l = 0; l < 2; ++l) {
        GArgs qa = {};
        qa.Af0 = xd_cur; qa.Af1 = xg_cur;
        qa.Ab0 = XDb;    qa.Ab1 = XGb;
        qa.N0 = N_DRUG;  qa.N1 = N_GENE; qa.gy0 = gyD;
        qa.Bt0 = BFt + (size_t)(l * 2 + 0) * 384 * 128;
        qa.Bt1 = BFt + (size_t)(l * 2 + 1) * 384 * 128;
        qa.bias0 = BB + (size_t)(l * 2 + 0) * 384;
        qa.bias1 = BB + (size_t)(l * 2 + 1) * 384;
        qa.QB0 = QDB; qa.QB1 = QGB; qa.KV0 = KVD; qa.KV1 = KVG;
        qa.afmt = (l == 0) ? 0 : 1; qa.colTiles = 3; qa.mode = 2; qa.writeF32 = 0;
        gemm_mfma<<<dim3(2, gyT), 256, 0, stream>>>(qa);

        fused_attn<<<(N_GENE + N_DRUG + 3) / 4, 256, 0, stream>>>(
            rowG, srcG, QGB, KVD, NUMG, rowD, srcD, QDB, KVG, NUMD);

        GArgs oa = {};
        oa.Ab0 = NUMD; oa.Ab1 = NUMG;
        oa.N0 = N_DRUG; oa.N1 = N_GENE; oa.gy0 = gyD;
        oa.Bt0 = aWt + (size_t)(l * 2 + 0) * 16384;
        oa.Bt1 = aWt + (size_t)(l * 2 + 1) * 16384;
        oa.bias0 = ab + (size_t)(l * 2 + 0) * 128;
        oa.bias1 = ab + (size_t)(l * 2 + 1) * 128;
        oa.skip0 = skip + (l * 2 + 0); oa.skip1 = skip + (l * 2 + 1);
        oa.Xc0 = xd_cur; oa.Xc1 = xg_cur;
        oa.Xn0 = XD0; oa.Xn1 = XG0;
        oa.Xb0 = XDb; oa.Xb1 = XGb;
        oa.afmt = 1; oa.colTiles = 2; oa.mode = 1; oa.writeF32 = (l == 0) ? 1 : 0;
        gemm_mfma<<<dim3(1, gyT), 256, 0, stream>>>(oa);

        xd_cur = XD0;
        xg_cur = XG0;
    }

    hipMemsetAsync(GSUM, 0, 128 * sizeof(float), stream);
    colsum_bf<<<256, 128, 0, stream>>>(XGb, N_GENE, GSUM);
    c2_kernel<<<1, 128, 0, stream>>>(GSUM, pW1, pb1, C2);
    predictor_mfma<<<NBATCH / 128, 256, 0, stream>>>(XDb, drug_idx, W1at, C2, pW2, pb2, (float*)d_out);
}

// Round 8
// 525.016 us; speedup vs baseline: 2.3819x; 1.1984x over previous
//
#include <hip/hip_runtime.h>
#include <hip/hip_bf16.h>
#include <math.h>

#define N_DRUG 20000
#define N_GENE 40000
#define HID 128
#define NEDGE 800000
#define NBATCH 4096

typedef unsigned short u16;
typedef unsigned int u32;
typedef __attribute__((ext_vector_type(8))) short short8;
typedef __attribute__((ext_vector_type(4))) float f32x4;

// ---------- helpers ----------
__device__ inline float gelu_exact(float x) {
    return 0.5f * x * (1.f + erff(x * 0.70710678118654752f));
}
__device__ inline u16 f2bf(float f) {                 // RNE f32 -> bf16
    u32 u = __float_as_uint(f);
    u += 0x7fffu + ((u >> 16) & 1u);
    return (u16)(u >> 16);
}
__device__ inline float bflo(u32 u) { return __uint_as_float(u << 16); }
__device__ inline float bfhi(u32 u) { return __uint_as_float(u & 0xffff0000u); }
__device__ inline float bf2f(u16 u) { return __uint_as_float(((u32)u) << 16); }
__device__ inline u32 pkbf(float a, float b) { return (u32)f2bf(a) | ((u32)f2bf(b) << 16); }

// LDS tile addressing: row-major [row][256B of k], XOR-swizzled within 256B row
#define SWZ(row, kbyte) ((row) * 256 + ((kbyte) ^ (((row) & 7) << 4)))

// ---------- 1. fuse relation matrices into k/v weights; emit transposed bf16 ----------
__global__ void fuse_weights(const float* __restrict__ kW, const float* __restrict__ kb,
                             const float* __restrict__ qW, const float* __restrict__ qb,
                             const float* __restrict__ vW, const float* __restrict__ vb,
                             const float* __restrict__ a_rel, const float* __restrict__ m_rel,
                             const float* __restrict__ p_rel,
                             u16* __restrict__ BFt, float* __restrict__ BB) {
    int idx = blockIdx.x * 256 + threadIdx.x;          // over 2*2*128*384
    if (idx >= 2 * 2 * 128 * 384) return;
    int j = idx % 384;
    int k = (idx / 384) % 128;
    int lt = idx / (384 * 128);                        // l*2 + t
    const float rs = 0.17677669529663687f;             // 1/sqrt(32)
    float w, b;
    if (j < 128) {
        w = qW[(lt * 128 + k) * 128 + j];
        b = qb[lt * 128 + j];
    } else if (j < 256) {
        int c = j - 128, h = c >> 5, e = c & 31;
        float scale = p_rel[lt * 4 + h] * rs;
        const float* ar = a_rel + ((lt * 4 + h) * 32) * 32;   // [d][e]
        const float* kWr = kW + (lt * 128 + k) * 128 + h * 32;
        const float* kbr = kb + lt * 128 + h * 32;
        float s = 0.f, sb = 0.f;
        for (int d = 0; d < 32; d++) { float a = ar[d * 32 + e]; s += kWr[d] * a; sb += kbr[d] * a; }
        w = s * scale; b = sb * scale;
    } else {
        int c = j - 256, h = c >> 5, e = c & 31;
        const float* mr = m_rel + ((lt * 4 + h) * 32) * 32;
        const float* vWr = vW + (lt * 128 + k) * 128 + h * 32;
        const float* vbr = vb + lt * 128 + h * 32;
        float s = 0.f, sb = 0.f;
        for (int d = 0; d < 32; d++) { float m = mr[d * 32 + e]; s += vWr[d] * m; sb += vbr[d] * m; }
        w = s; b = sb;
    }
    BFt[((size_t)lt * 384 + j) * 128 + k] = f2bf(w);
    if (k == 0) BB[lt * 384 + j] = b;
}

// ---------- 1b. transpose aW to bf16: aWt[lt][j=128][k=128]; W1a^T bf16 ----------
__global__ void prep_awt(const float* __restrict__ aW, u16* __restrict__ aWt) {
    int idx = blockIdx.x * 256 + threadIdx.x;          // 2*2*128*128 = 65536
    if (idx >= 65536) return;
    int k = idx & 127, j = (idx >> 7) & 127, lt = idx >> 14;
    aWt[idx] = f2bf(aW[((size_t)lt * 128 + k) * 128 + j]);
}
__global__ void prep_w1at(const float* __restrict__ pW1, u16* __restrict__ W1at) {
    int idx = blockIdx.x * 256 + threadIdx.x;          // 16384
    if (idx >= 16384) return;
    int k = idx & 127, j = idx >> 7;                   // k<128 rows of pW1 (drug half)
    W1at[idx] = f2bf(pW1[(size_t)k * 128 + j]);
}

// ---------- 2. merged MFMA bf16 GEMM over both node types ----------
// Swapped-operand MFMA: mfma(bf, af) yields C^T fragments -> lane holds 4 consecutive
// COLUMNS of one row -> vectorized epilogue stores (uint2 bf16 / float4 f32).
struct GArgs {
    const float* Af0; const float* Af1;   // f32 A (afmt 0)
    const u16* Ab0;  const u16* Ab1;      // bf16 A (afmt 1)
    int N0; int N1; int gy0;
    const u16* Bt0;  const u16* Bt1;      // [M][128] bf16 transposed weights
    const float* bias0; const float* bias1;
    u16* QB0; u16* QB1;                   // mode2: Q bf16 [N][128]
    u16* KV0; u16* KV1;                   // mode2: [k|v] bf16 [N][256]
    const float* skip0; const float* skip1;
    const float* Xc0; const float* Xc1;   // mode1: skip input f32
    float* Xn0; float* Xn1;               // mode1: f32 out (if writeF32)
    u16* Xb0; u16* Xb1;                   // mode1: bf16 out
    int afmt; int colTiles; int mode; int writeF32;
};

__global__ __launch_bounds__(256) void gemm_mfma(GArgs a) {
    __shared__ char As[128 * 256];   // 128 rows x 128 k bf16, swizzled
    __shared__ char Bs[64 * 256];    // 64 cols x 128 k bf16, swizzled
    const int tid = threadIdx.x;
    const int set = (blockIdx.y < (unsigned)a.gy0) ? 0 : 1;
    const int by = set ? (blockIdx.y - a.gy0) : blockIdx.y;
    const int rowBase = by * 128;
    const int N = set ? a.N1 : a.N0;
    const float* Af = set ? a.Af1 : a.Af0;
    const u16* Ab = set ? a.Ab1 : a.Ab0;
    const u16* Bt = set ? a.Bt1 : a.Bt0;
    const float* bias = set ? a.bias1 : a.bias0;
    u16* QB = set ? a.QB1 : a.QB0;
    u16* KV = set ? a.KV1 : a.KV0;
    const float* skipPtr = set ? a.skip1 : a.skip0;
    const float* Xcur = set ? a.Xc1 : a.Xc0;
    float* Xn = set ? a.Xn1 : a.Xn0;
    u16* Xb = set ? a.Xb1 : a.Xb0;

    if (a.afmt == 0) {
#pragma unroll
        for (int it = 0; it < 16; ++it) {
            int lin = it * 256 + tid;           // 4096 float4 groups (4 k each)
            int row = lin >> 5, kq = lin & 31;
            int gr = rowBase + row;
            float4 av = make_float4(0.f, 0.f, 0.f, 0.f);
            if (gr < N) av = *(const float4*)(Af + (size_t)gr * 128 + kq * 4);
            uint2 p;
            p.x = pkbf(av.x, av.y);
            p.y = pkbf(av.z, av.w);
            *(uint2*)(As + SWZ(row, kq * 8)) = p;
        }
    } else {
#pragma unroll
        for (int it = 0; it < 8; ++it) {
            int lin = it * 256 + tid;           // 2048 groups of 8 bf16 (16B)
            int row = lin >> 4, kq = lin & 15;
            int gr = rowBase + row;
            uint4 v = make_uint4(0, 0, 0, 0);
            if (gr < N) v = *(const uint4*)(Ab + (size_t)gr * 128 + kq * 8);
            *(uint4*)(As + SWZ(row, kq * 16)) = v;
        }
    }

    const int w = tid >> 6, lane = tid & 63;
    const int r15 = lane & 15;
    const int klo = (lane >> 4) << 4;           // this lane's k byte offset (8 bf16)
    const int cq = (lane >> 4) << 2;            // col quad offset within 16-col tile
    float g = 0.f;
    if (a.mode == 1) g = 1.f / (1.f + expf(-skipPtr[0]));

    for (int ct = 0; ct < a.colTiles; ++ct) {
        const int colBase = (blockIdx.x * a.colTiles + ct) * 64;
        __syncthreads();   // Bs free / As staged
#pragma unroll
        for (int it = 0; it < 4; ++it) {
            int lin = it * 256 + tid;               // 1024 groups
            int j = lin >> 4, kq = lin & 15;
            uint4 v = *(const uint4*)(Bt + (size_t)(colBase + j) * 128 + kq * 8);
            *(uint4*)(Bs + SWZ(j, kq * 16)) = v;
        }
        __syncthreads();

        f32x4 acc[2][4];
#pragma unroll
        for (int mt = 0; mt < 2; ++mt)
#pragma unroll
            for (int nt = 0; nt < 4; ++nt) acc[mt][nt] = (f32x4){0.f, 0.f, 0.f, 0.f};

#pragma unroll
        for (int kb = 0; kb < 4; ++kb) {
            int kbyte = kb * 64 + klo;
            short8 af[2], bf[4];
#pragma unroll
            for (int mt = 0; mt < 2; ++mt) {
                int row = w * 32 + mt * 16 + r15;
                af[mt] = *(short8*)(As + SWZ(row, kbyte));
            }
#pragma unroll
            for (int nt = 0; nt < 4; ++nt) {
                int col = nt * 16 + r15;
                bf[nt] = *(short8*)(Bs + SWZ(col, kbyte));
            }
            // swapped operands: acc = C^T fragment (lane: row=r15-tile, 4 consecutive cols)
#pragma unroll
            for (int mt = 0; mt < 2; ++mt)
#pragma unroll
                for (int nt = 0; nt < 4; ++nt)
                    acc[mt][nt] = __builtin_amdgcn_mfma_f32_16x16x32_bf16(bf[nt], af[mt], acc[mt][nt], 0, 0, 0);
        }

#pragma unroll
        for (int mt = 0; mt < 2; ++mt) {
            int grow = rowBase + w * 32 + mt * 16 + r15;
            if (grow >= N) continue;
#pragma unroll
            for (int nt = 0; nt < 4; ++nt) {
                int col = colBase + nt * 16 + cq;   // 4 consecutive cols
                float4 bi = *(const float4*)(bias + col);
                float v0 = acc[mt][nt][0] + bi.x;
                float v1 = acc[mt][nt][1] + bi.y;
                float v2 = acc[mt][nt][2] + bi.z;
                float v3 = acc[mt][nt][3] + bi.w;
                if (a.mode == 2) {
                    uint2 p; p.x = pkbf(v0, v1); p.y = pkbf(v2, v3);
                    if (col < 128) {
                        *(uint2*)(QB + (size_t)grow * 128 + col) = p;
                    } else if (col < 256) {
                        *(uint2*)(KV + (size_t)grow * 256 + (col - 128)) = p;
                    } else {
                        *(uint2*)(KV + (size_t)grow * 256 + 128 + (col - 256)) = p;
                    }
                } else {
                    float4 xv = *(const float4*)(Xcur + (size_t)grow * 128 + col);
                    float o0 = fmaxf(g * v0 + (1.f - g) * xv.x, 0.f);
                    float o1 = fmaxf(g * v1 + (1.f - g) * xv.y, 0.f);
                    float o2 = fmaxf(g * v2 + (1.f - g) * xv.z, 0.f);
                    float o3 = fmaxf(g * v3 + (1.f - g) * xv.w, 0.f);
                    if (a.writeF32)
                        *(float4*)(Xn + (size_t)grow * 128 + col) = make_float4(o0, o1, o2, o3);
                    uint2 p; p.x = pkbf(o0, o1); p.y = pkbf(o2, o3);
                    *(uint2*)(Xb + (size_t)grow * 128 + col) = p;
                }
            }
        }
    }
}

// ---------- 3. CSR build: merged histogram ----------
__global__ void hist2(const int* __restrict__ d0, int* __restrict__ c0,
                      const int* __restrict__ d1, int* __restrict__ c1, int gridE) {
    int b = blockIdx.x;
    const int* d; int* c; int bb;
    if (b < gridE) { d = d0; c = c0; bb = b; } else { d = d1; c = c1; bb = b - gridE; }
    int e = bb * 256 + threadIdx.x;
    if (e < NEDGE) atomicAdd(c + d[e], 1);
}

// ---------- 4. CSR build: hierarchical scan over both count arrays ----------
#define SCAN_NBG 10
#define SCAN_NBD 5
__global__ __launch_bounds__(256) void scan_local(const int* __restrict__ cntG,
                                                  const int* __restrict__ cntD,
                                                  int* __restrict__ outG, int* __restrict__ outD,
                                                  int* __restrict__ bsum) {
    __shared__ int tmp[256];
    int b = blockIdx.x, t = threadIdx.x;
    const int* cnt; int* out; int n; int cbase;
    if (b < SCAN_NBG) { cnt = cntG; out = outG; n = N_GENE; cbase = b * 4096; }
    else { cnt = cntD; out = outD; n = N_DRUG; cbase = (b - SCAN_NBG) * 4096; }
    int base = cbase + t * 16;
    int v[16], s = 0;
#pragma unroll
    for (int i = 0; i < 16; ++i) { int idx = base + i; v[i] = (idx < n) ? cnt[idx] : 0; s += v[i]; }
    tmp[t] = s;
    __syncthreads();
    for (int off = 1; off < 256; off <<= 1) {
        int add = (t >= off) ? tmp[t - off] : 0;
        __syncthreads();
        tmp[t] += add;
        __syncthreads();
    }
    int run = tmp[t] - s;
#pragma unroll
    for (int i = 0; i < 16; ++i) { int idx = base + i; if (idx < n) out[idx] = run; run += v[i]; }
    if (t == 255) bsum[b] = tmp[255];
}

__global__ void scan_bsum(int* __restrict__ bsum) {
    if (threadIdx.x == 0) {
        int run = 0;
        for (int i = 0; i < SCAN_NBG; ++i) { int v = bsum[i]; bsum[i] = run; run += v; }
        run = 0;
        for (int i = SCAN_NBG; i < SCAN_NBG + SCAN_NBD; ++i) { int v = bsum[i]; bsum[i] = run; run += v; }
    }
}

__global__ __launch_bounds__(256) void scan_add(int* __restrict__ outG, int* __restrict__ outD,
                                                const int* __restrict__ bsum) {
    int b = blockIdx.x, t = threadIdx.x;
    int* out; int n; int cbase;
    if (b < SCAN_NBG) { out = outG; n = N_GENE; cbase = b * 4096; }
    else { out = outD; n = N_DRUG; cbase = (b - SCAN_NBG) * 4096; }
    int o = bsum[b];
    int base = cbase + t * 16;
#pragma unroll
    for (int i = 0; i < 16; ++i) { int idx = base + i; if (idx < n) out[idx] += o; }
    if (t == 0 && b == SCAN_NBG - 1) outG[N_GENE] = NEDGE;
    if (t == 0 && b == SCAN_NBG + SCAN_NBD - 1) outD[N_DRUG] = NEDGE;
}

// ---------- 5. CSR build: merged scatter (count-down cursor) ----------
__global__ void scatter2(const int* __restrict__ s0, const int* __restrict__ d0,
                         const int* __restrict__ r0, int* __restrict__ cur0, int* __restrict__ o0,
                         const int* __restrict__ s1, const int* __restrict__ d1,
                         const int* __restrict__ r1, int* __restrict__ cur1, int* __restrict__ o1,
                         int gridE) {
    int b = blockIdx.x;
    const int *src, *dst, *row; int *cursor, *outp; int bb;
    if (b < gridE) { src = s0; dst = d0; row = r0; cursor = cur0; outp = o0; bb = b; }
    else { src = s1; dst = d1; row = r1; cursor = cur1; outp = o1; bb = b - gridE; }
    int e = bb * 256 + threadIdx.x;
    if (e < NEDGE) {
        int d = dst[e];
        int pos = row[d] + atomicSub(cursor + d, 1) - 1;
        outp[pos] = src[e];
    }
}

// ---------- 6. merged fused attention (both edge types), bf16 Q, 2-deep prefetch ----------
// One 64-lane wave per dst node. g=lane>>4 (edge slot), sl=lane&15 (dims [8sl,8sl+8)).
// 2-deep prefetch keeps VGPR < 64 (occupancy cliff) — depth-4 cost 29% occupancy (round 7).
// No max-tracking (softmax shift-invariant; |alpha| ~ 3 << 80).
__global__ __launch_bounds__(256) void fused_attn(const int* __restrict__ rowG,
                                                  const int* __restrict__ srcG,
                                                  const u16* __restrict__ QGB,
                                                  const u16* __restrict__ KVD,
                                                  u16* __restrict__ NUMG,
                                                  const int* __restrict__ rowD,
                                                  const int* __restrict__ srcD,
                                                  const u16* __restrict__ QDB,
                                                  const u16* __restrict__ KVG,
                                                  u16* __restrict__ NUMD) {
    int node = (blockIdx.x * 256 + threadIdx.x) >> 6;
    int lane = threadIdx.x & 63;
    const int* rowStart; const int* srcSorted; const u16* Qb; const u16* KV; u16* out; int nd;
    if (node < N_GENE) { rowStart = rowG; srcSorted = srcG; Qb = QGB; KV = KVD; out = NUMG; nd = node; }
    else if (node < N_GENE + N_DRUG) { rowStart = rowD; srcSorted = srcD; Qb = QDB; KV = KVG; out = NUMD; nd = node - N_GENE; }
    else return;
    const int g = lane >> 4;
    const int sl = lane & 15;

    float qr[8];
    {
        uint4 qv = *(const uint4*)(Qb + (size_t)nd * 128 + sl * 8);
        qr[0] = bflo(qv.x); qr[1] = bfhi(qv.x);
        qr[2] = bflo(qv.y); qr[3] = bfhi(qv.y);
        qr[4] = bflo(qv.z); qr[5] = bfhi(qv.z);
        qr[6] = bflo(qv.w); qr[7] = bfhi(qv.w);
    }
    int beg = rowStart[nd], end = rowStart[nd + 1];
    float s = 0.f;
    float acc[8] = {0.f, 0.f, 0.f, 0.f, 0.f, 0.f, 0.f, 0.f};

#define FETCH(t, kk, vv)                                                \
    {                                                                   \
        int sid = __shfl(sids, 4 * (t) + g);                            \
        const u16* rowp = KV + ((size_t)sid << 8);                      \
        kk = *(const uint4*)(rowp + sl * 8);                            \
        vv = *(const uint4*)(rowp + 128 + sl * 8);                      \
    }
#define COMPUTE(t, kk, vv)                                              \
    {                                                                   \
        float part = qr[0] * bflo(kk.x) + qr[1] * bfhi(kk.x)            \
                   + qr[2] * bflo(kk.y) + qr[3] * bfhi(kk.y)            \
                   + qr[4] * bflo(kk.z) + qr[5] * bfhi(kk.z)            \
                   + qr[6] * bflo(kk.w) + qr[7] * bfhi(kk.w);           \
        part += __shfl_xor(part, 1);                                    \
        part += __shfl_xor(part, 2);                                    \
        float a = (base + 4 * (t) + g < end) ? __expf(part) : 0.f;      \
        s += a;                                                         \
        acc[0] += a * bflo(vv.x); acc[1] += a * bfhi(vv.x);             \
        acc[2] += a * bflo(vv.y); acc[3] += a * bfhi(vv.y);             \
        acc[4] += a * bflo(vv.z); acc[5] += a * bfhi(vv.z);             \
        acc[6] += a * bflo(vv.w); acc[7] += a * bfhi(vv.w);             \
    }

    for (int base = beg; base < end; base += 64) {
        int bn = end - base; if (bn > 64) bn = 64;
        int ld = base + lane; if (ld > end - 1) ld = end - 1;
        int sids = srcSorted[ld];
        int nIter = (bn + 3) >> 2;
        uint4 k0, v0, k1, v1;
        FETCH(0, k0, v0);
        for (int t = 0; t < nIter; t += 2) {
            if (t + 1 < nIter) FETCH(t + 1, k1, v1);
            COMPUTE(t, k0, v0);
            if (t + 1 >= nIter) break;
            if (t + 2 < nIter) FETCH(t + 2, k0, v0);
            COMPUTE(t + 1, k1, v1);
        }
    }
#undef FETCH
#undef COMPUTE

    // cross-group reduce (sum over the 4 edge slots)
    s += __shfl_xor(s, 16);
    s += __shfl_xor(s, 32);
#pragma unroll
    for (int j = 0; j < 8; ++j) {
        acc[j] += __shfl_xor(acc[j], 16);
        acc[j] += __shfl_xor(acc[j], 32);
    }
    if (lane < 16) {
        float inv = 1.f / (s + 1e-16f);
        float r0 = gelu_exact(acc[0] * inv), r1 = gelu_exact(acc[1] * inv);
        float r2 = gelu_exact(acc[2] * inv), r3 = gelu_exact(acc[3] * inv);
        float r4 = gelu_exact(acc[4] * inv), r5 = gelu_exact(acc[5] * inv);
        float r6 = gelu_exact(acc[6] * inv), r7 = gelu_exact(acc[7] * inv);
        uint4 o;
        o.x = pkbf(r0, r1); o.y = pkbf(r2, r3); o.z = pkbf(r4, r5); o.w = pkbf(r6, r7);
        *(uint4*)(out + (size_t)nd * 128 + sl * 8) = o;
    }
}

// ---------- 7. column sum over genes (bf16 input) ----------
__global__ __launch_bounds__(128) void colsum_bf(const u16* __restrict__ X, int N,
                                                 float* __restrict__ out) {
    int c = threadIdx.x;
    float s = 0.f;
    for (int r = blockIdx.x; r < N; r += gridDim.x) s += bf2f(X[(size_t)r * 128 + c]);
    atomicAdd(out + c, s);
}

// ---------- 8a. c2 = gene_mean @ W1b + pb1 ----------
__global__ __launch_bounds__(128) void c2_kernel(const float* __restrict__ gsum,
                                                 const float* __restrict__ pW1,
                                                 const float* __restrict__ pb1,
                                                 float* __restrict__ c2) {
    int j = threadIdx.x;
    float s = pb1[j];
    for (int k = 0; k < 128; ++k)
        s += gsum[k] * (1.f / 40000.f) * pW1[(size_t)(128 + k) * 128 + j];
    c2[j] = s;
}

// ---------- 8b. predictor: out = relu(xd[didx] @ W1a + c2) @ pW2 + pb2 ----------
__global__ __launch_bounds__(256) void predictor_mfma(const u16* __restrict__ Xdb,
                                                      const int* __restrict__ didx,
                                                      const u16* __restrict__ W1at,
                                                      const float* __restrict__ c2,
                                                      const float* __restrict__ pW2,
                                                      const float* __restrict__ pb2,
                                                      float* __restrict__ out) {
    __shared__ char As[128 * 256];
    __shared__ char Bs[128 * 256];
    const int tid = threadIdx.x;
    const int rowBase = blockIdx.x * 128;

#pragma unroll
    for (int it = 0; it < 8; ++it) {
        int lin = it * 256 + tid;               // 2048 groups (row, 8 bf16)
        int row = lin >> 4, kq = lin & 15;
        int dn = didx[rowBase + row];
        uint4 v = *(const uint4*)(Xdb + (size_t)dn * 128 + kq * 8);
        *(uint4*)(As + SWZ(row, kq * 16)) = v;
        uint4 wv = *(const uint4*)(W1at + (size_t)row * 128 + kq * 8);
        *(uint4*)(Bs + SWZ(row, kq * 16)) = wv;
    }
    __syncthreads();

    const int w = tid >> 6, lane = tid & 63;
    const int r15 = lane & 15;
    const int klo = (lane >> 4) << 4;
    f32x4 acc[2][8];
#pragma unroll
    for (int mt = 0; mt < 2; ++mt)
#pragma unroll
        for (int nt = 0; nt < 8; ++nt) acc[mt][nt] = (f32x4){0.f, 0.f, 0.f, 0.f};

#pragma unroll
    for (int kb = 0; kb < 4; ++kb) {
        int kbyte = kb * 64 + klo;
        short8 af[2], bf[8];
#pragma unroll
        for (int mt = 0; mt < 2; ++mt) af[mt] = *(short8*)(As + SWZ(w * 32 + mt * 16 + r15, kbyte));
#pragma unroll
        for (int nt = 0; nt < 8; ++nt) bf[nt] = *(short8*)(Bs + SWZ(nt * 16 + r15, kbyte));
#pragma unroll
        for (int mt = 0; mt < 2; ++mt)
#pragma unroll
            for (int nt = 0; nt < 8; ++nt)
                acc[mt][nt] = __builtin_amdgcn_mfma_f32_16x16x32_bf16(af[mt], bf[nt], acc[mt][nt], 0, 0, 0);
    }

    float c2v[8], w2v[8];
#pragma unroll
    for (int nt = 0; nt < 8; ++nt) {
        int col = nt * 16 + r15;
        c2v[nt] = c2[col];
        w2v[nt] = pW2[col];
    }
    float bias2 = pb2[0];
#pragma unroll
    for (int mt = 0; mt < 2; ++mt) {
#pragma unroll
        for (int r = 0; r < 4; ++r) {
            float rsum = 0.f;
#pragma unroll
            for (int nt = 0; nt < 8; ++nt)
                rsum += fmaxf(acc[mt][nt][r] + c2v[nt], 0.f) * w2v[nt];
            rsum += __shfl_xor(rsum, 1);
            rsum += __shfl_xor(rsum, 2);
            rsum += __shfl_xor(rsum, 4);
            rsum += __shfl_xor(rsum, 8);
            if (r15 == 0)
                out[rowBase + w * 32 + mt * 16 + ((lane >> 4) << 2) + r] = rsum + bias2;
        }
    }
}

// ---------- launch ----------
extern "C" void kernel_launch(void* const* d_in, const int* in_sizes, int n_in,
                              void* d_out, int out_size, void* d_ws, size_t ws_size,
                              hipStream_t stream) {
    const float* x_drug = (const float*)d_in[0];
    const float* x_gene = (const float*)d_in[1];
    const float* kW = (const float*)d_in[2];
    const float* kb = (const float*)d_in[3];
    const float* qW = (const float*)d_in[4];
    const float* qb = (const float*)d_in[5];
    const float* vW = (const float*)d_in[6];
    const float* vb = (const float*)d_in[7];
    const float* aW = (const float*)d_in[8];
    const float* ab = (const float*)d_in[9];
    const float* skip = (const float*)d_in[10];
    const float* a_rel = (const float*)d_in[11];
    const float* m_rel = (const float*)d_in[12];
    const float* p_rel = (const float*)d_in[13];
    const float* pW1 = (const float*)d_in[14];
    const float* pb1 = (const float*)d_in[15];
    const float* pW2 = (const float*)d_in[16];
    const float* pb2 = (const float*)d_in[17];
    const int* e_dg_s = (const int*)d_in[18];
    const int* e_dg_d = (const int*)d_in[19];
    const int* e_gd_s = (const int*)d_in[20];
    const int* e_gd_d = (const int*)d_in[21];
    const int* drug_idx = (const int*)d_in[22];

    // ---- workspace layout ----
    char* base = (char*)d_ws;
    size_t off = 0;
    auto alloc = [&](size_t bytes) { char* p = base + off; off += (bytes + 255) & ~(size_t)255; return p; };
    u16*   QDB  = (u16*)alloc((size_t)N_DRUG * 128 * 2);
    u16*   QGB  = (u16*)alloc((size_t)N_GENE * 128 * 2);
    u16*   KVD  = (u16*)alloc((size_t)N_DRUG * 256 * 2);
    u16*   KVG  = (u16*)alloc((size_t)N_GENE * 256 * 2);
    float* XD0  = (float*)alloc((size_t)N_DRUG * 128 * 4);
    float* XG0  = (float*)alloc((size_t)N_GENE * 128 * 4);
    u16*   XDb  = (u16*)alloc((size_t)N_DRUG * 128 * 2);
    u16*   XGb  = (u16*)alloc((size_t)N_GENE * 128 * 2);
    u16*   NUMD = (u16*)alloc((size_t)N_DRUG * 128 * 2);
    u16*   NUMG = (u16*)alloc((size_t)N_GENE * 128 * 2);
    u16*   BFt  = (u16*)alloc((size_t)2 * 2 * 384 * 128 * 2);
    float* BB   = (float*)alloc((size_t)2 * 2 * 384 * 4);
    u16*   aWt  = (u16*)alloc((size_t)2 * 2 * 128 * 128 * 2);
    u16*   W1at = (u16*)alloc((size_t)128 * 128 * 2);
    float* GSUM = (float*)alloc(128 * 4);
    float* C2   = (float*)alloc(128 * 4);
    int* rowG = (int*)alloc(40001 * 4);
    int* rowD = (int*)alloc(20001 * 4);
    int* cntG = (int*)alloc(40000 * 4);
    int* cntD = (int*)alloc(20000 * 4);
    int* bsum = (int*)alloc(64 * 4);
    int* srcG = (int*)alloc((size_t)NEDGE * 4);
    int* srcD = (int*)alloc((size_t)NEDGE * 4);

    fuse_weights<<<768, 256, 0, stream>>>(kW, kb, qW, qb, vW, vb, a_rel, m_rel, p_rel, BFt, BB);
    prep_awt<<<256, 256, 0, stream>>>(aW, aWt);
    prep_w1at<<<64, 256, 0, stream>>>(pW1, W1at);

    // ---- build CSR by destination ----
    const int gridE = (NEDGE + 255) / 256;
    hipMemsetAsync(cntG, 0, 40000 * sizeof(int), stream);
    hipMemsetAsync(cntD, 0, 20000 * sizeof(int), stream);
    hist2<<<2 * gridE, 256, 0, stream>>>(e_dg_d, cntG, e_gd_d, cntD, gridE);
    scan_local<<<SCAN_NBG + SCAN_NBD, 256, 0, stream>>>(cntG, cntD, rowG, rowD, bsum);
    scan_bsum<<<1, 64, 0, stream>>>(bsum);
    scan_add<<<SCAN_NBG + SCAN_NBD, 256, 0, stream>>>(rowG, rowD, bsum);
    scatter2<<<2 * gridE, 256, 0, stream>>>(e_dg_s, e_dg_d, rowG, cntG, srcG,
                                            e_gd_s, e_gd_d, rowD, cntD, srcD, gridE);

    const int gyD = (N_DRUG + 127) / 128;   // 157
    const int gyG = (N_GENE + 127) / 128;   // 313
    const int gyT = gyD + gyG;              // 470

    const float* xd_cur = x_drug;
    const float* xg_cur = x_gene;

    for (int l = 0; l < 2; ++l) {
        GArgs qa = {};
        qa.Af0 = xd_cur; qa.Af1 = xg_cur;
        qa.Ab0 = XDb;    qa.Ab1 = XGb;
        qa.N0 = N_DRUG;  qa.N1 = N_GENE; qa.gy0 = gyD;
        qa.Bt0 = BFt + (size_t)(l * 2 + 0) * 384 * 128;
        qa.Bt1 = BFt + (size_t)(l * 2 + 1) * 384 * 128;
        qa.bias0 = BB + (size_t)(l * 2 + 0) * 384;
        qa.bias1 = BB + (size_t)(l * 2 + 1) * 384;
        qa.QB0 = QDB; qa.QB1 = QGB; qa.KV0 = KVD; qa.KV1 = KVG;
        qa.afmt = (l == 0) ? 0 : 1; qa.colTiles = 3; qa.mode = 2; qa.writeF32 = 0;
        gemm_mfma<<<dim3(2, gyT), 256, 0, stream>>>(qa);

        fused_attn<<<(N_GENE + N_DRUG + 3) / 4, 256, 0, stream>>>(
            rowG, srcG, QGB, KVD, NUMG, rowD, srcD, QDB, KVG, NUMD);

        GArgs oa = {};
        oa.Ab0 = NUMD; oa.Ab1 = NUMG;
        oa.N0 = N_DRUG; oa.N1 = N_GENE; oa.gy0 = gyD;
        oa.Bt0 = aWt + (size_t)(l * 2 + 0) * 16384;
        oa.Bt1 = aWt + (size_t)(l * 2 + 1) * 16384;
        oa.bias0 = ab + (size_t)(l * 2 + 0) * 128;
        oa.bias1 = ab + (size_t)(l * 2 + 1) * 128;
        oa.skip0 = skip + (l * 2 + 0); oa.skip1 = skip + (l * 2 + 1);
        oa.Xc0 = xd_cur; oa.Xc1 = xg_cur;
        oa.Xn0 = XD0; oa.Xn1 = XG0;
        oa.Xb0 = XDb; oa.Xb1 = XGb;
        oa.afmt = 1; oa.colTiles = 2; oa.mode = 1; oa.writeF32 = (l == 0) ? 1 : 0;
        gemm_mfma<<<dim3(1, gyT), 256, 0, stream>>>(oa);

        xd_cur = XD0;
        xg_cur = XG0;
    }

    hipMemsetAsync(GSUM, 0, 128 * sizeof(float), stream);
    colsum_bf<<<256, 128, 0, stream>>>(XGb, N_GENE, GSUM);
    c2_kernel<<<1, 128, 0, stream>>>(GSUM, pW1, pb1, C2);
    predictor_mfma<<<NBATCH / 128, 256, 0, stream>>>(XDb, drug_idx, W1at, C2, pW2, pb2, (float*)d_out);
}

// Round 9
// 512.915 us; speedup vs baseline: 2.4381x; 1.0236x over previous
//
#include <hip/hip_runtime.h>
#include <hip/hip_bf16.h>
#include <math.h>

#define N_DRUG 20000
#define N_GENE 40000
#define HID 128
#define NEDGE 800000
#define NBATCH 4096

typedef unsigned short u16;
typedef unsigned int u32;
typedef __attribute__((ext_vector_type(8))) short short8;
typedef __attribute__((ext_vector_type(4))) float f32x4;

// ---------- helpers ----------
__device__ inline float gelu_exact(float x) {
    return 0.5f * x * (1.f + erff(x * 0.70710678118654752f));
}
__device__ inline u16 f2bf(float f) {                 // RNE f32 -> bf16
    u32 u = __float_as_uint(f);
    u += 0x7fffu + ((u >> 16) & 1u);
    return (u16)(u >> 16);
}
__device__ inline float bflo(u32 u) { return __uint_as_float(u << 16); }
__device__ inline float bfhi(u32 u) { return __uint_as_float(u & 0xffff0000u); }
__device__ inline u32 pkbf(float a, float b) { return (u32)f2bf(a) | ((u32)f2bf(b) << 16); }

// LDS tile addressing: row-major [row][256B of k], XOR-swizzled within 256B row
#define SWZ(row, kbyte) ((row) * 256 + ((kbyte) ^ (((row) & 7) << 4)))

// ---------- 1. prologue: fuse weights + transpose preps + zero counters ----------
// blocks [0,768): BFt/BB ; [768,1024): aWt ; [1024,1088): W1at ; [1088,1323): zero cnt
__global__ __launch_bounds__(256) void prologue(const float* __restrict__ kW, const float* __restrict__ kb,
                                                const float* __restrict__ qW, const float* __restrict__ qb,
                                                const float* __restrict__ vW, const float* __restrict__ vb,
                                                const float* __restrict__ a_rel, const float* __restrict__ m_rel,
                                                const float* __restrict__ p_rel,
                                                const float* __restrict__ aW, const float* __restrict__ pW1,
                                                u16* __restrict__ BFt, float* __restrict__ BB,
                                                u16* __restrict__ aWt, u16* __restrict__ W1at,
                                                int* __restrict__ cnt) {
    int b = blockIdx.x, tid = threadIdx.x;
    if (b < 768) {
        int idx = b * 256 + tid;                       // < 196608
        int j = idx % 384;
        int k = (idx / 384) % 128;
        int lt = idx / (384 * 128);
        const float rs = 0.17677669529663687f;         // 1/sqrt(32)
        float w, bb;
        if (j < 128) {
            w = qW[(lt * 128 + k) * 128 + j];
            bb = qb[lt * 128 + j];
        } else if (j < 256) {
            int c = j - 128, h = c >> 5, e = c & 31;
            float scale = p_rel[lt * 4 + h] * rs;
            const float* ar = a_rel + ((lt * 4 + h) * 32) * 32;
            const float* kWr = kW + (lt * 128 + k) * 128 + h * 32;
            const float* kbr = kb + lt * 128 + h * 32;
            float s = 0.f, sb = 0.f;
            for (int d = 0; d < 32; d++) { float a = ar[d * 32 + e]; s += kWr[d] * a; sb += kbr[d] * a; }
            w = s * scale; bb = sb * scale;
        } else {
            int c = j - 256, h = c >> 5, e = c & 31;
            const float* mr = m_rel + ((lt * 4 + h) * 32) * 32;
            const float* vWr = vW + (lt * 128 + k) * 128 + h * 32;
            const float* vbr = vb + lt * 128 + h * 32;
            float s = 0.f, sb = 0.f;
            for (int d = 0; d < 32; d++) { float m = mr[d * 32 + e]; s += vWr[d] * m; sb += vbr[d] * m; }
            w = s; bb = sb;
        }
        BFt[((size_t)lt * 384 + j) * 128 + k] = f2bf(w);
        if (k == 0) BB[lt * 384 + j] = bb;
    } else if (b < 1024) {
        int idx = (b - 768) * 256 + tid;               // < 65536
        int k = idx & 127, j = (idx >> 7) & 127, lt = idx >> 14;
        aWt[idx] = f2bf(aW[((size_t)lt * 128 + k) * 128 + j]);
    } else if (b < 1088) {
        int idx = (b - 1024) * 256 + tid;              // < 16384
        int k = idx & 127, j = idx >> 7;
        W1at[idx] = f2bf(pW1[(size_t)k * 128 + j]);
    } else {
        int idx = (b - 1088) * 256 + tid;
        if (idx < 60000) cnt[idx] = 0;                 // cntG(40000) + cntD(20000) contiguous
    }
}

// ---------- 2. merged MFMA bf16 GEMM over both node types ----------
// Swapped-operand MFMA: mfma(bf, af) yields C^T fragments -> lane holds 4 consecutive
// COLUMNS of one row -> vectorized epilogue stores.
struct GArgs {
    const float* Af0; const float* Af1;   // f32 A (afmt 0)
    const u16* Ab0;  const u16* Ab1;      // bf16 A (afmt 1)
    int N0; int N1; int gy0;
    const u16* Bt0;  const u16* Bt1;      // [M][128] bf16 transposed weights
    const float* bias0; const float* bias1;
    u16* QB0; u16* QB1;                   // mode2: Q bf16 [N][128]
    u16* KV0; u16* KV1;                   // mode2: [k|v] bf16 [N][256]
    const float* skip0; const float* skip1;
    const float* Xc0; const float* Xc1;   // mode1: skip input f32
    float* Xn0; float* Xn1;               // mode1: f32 out (if writeF32)
    u16* Xb0; u16* Xb1;                   // mode1: bf16 out (nullable)
    float* colPart;                       // mode1 set1: per-block column partials [gyG][128]
    int afmt; int colTiles; int mode; int writeF32;
};

__global__ __launch_bounds__(256) void gemm_mfma(GArgs a) {
    __shared__ char As[128 * 256];   // 128 rows x 128 k bf16, swizzled
    __shared__ char Bs[64 * 256];    // 64 cols x 128 k bf16, swizzled
    __shared__ float sums[4][128];   // column partials (mode1 set1)
    const int tid = threadIdx.x;
    const int set = (blockIdx.y < (unsigned)a.gy0) ? 0 : 1;
    const int by = set ? (blockIdx.y - a.gy0) : blockIdx.y;
    const int rowBase = by * 128;
    const int N = set ? a.N1 : a.N0;
    const float* Af = set ? a.Af1 : a.Af0;
    const u16* Ab = set ? a.Ab1 : a.Ab0;
    const u16* Bt = set ? a.Bt1 : a.Bt0;
    const float* bias = set ? a.bias1 : a.bias0;
    u16* QB = set ? a.QB1 : a.QB0;
    u16* KV = set ? a.KV1 : a.KV0;
    const float* skipPtr = set ? a.skip1 : a.skip0;
    const float* Xcur = set ? a.Xc1 : a.Xc0;
    float* Xn = set ? a.Xn1 : a.Xn0;
    u16* Xb = set ? a.Xb1 : a.Xb0;
    const bool doCol = (a.mode == 1) && (set == 1) && (a.colPart != nullptr);

    if (a.afmt == 0) {
#pragma unroll
        for (int it = 0; it < 16; ++it) {
            int lin = it * 256 + tid;
            int row = lin >> 5, kq = lin & 31;
            int gr = rowBase + row;
            float4 av = make_float4(0.f, 0.f, 0.f, 0.f);
            if (gr < N) av = *(const float4*)(Af + (size_t)gr * 128 + kq * 4);
            uint2 p;
            p.x = pkbf(av.x, av.y);
            p.y = pkbf(av.z, av.w);
            *(uint2*)(As + SWZ(row, kq * 8)) = p;
        }
    } else {
#pragma unroll
        for (int it = 0; it < 8; ++it) {
            int lin = it * 256 + tid;
            int row = lin >> 4, kq = lin & 15;
            int gr = rowBase + row;
            uint4 v = make_uint4(0, 0, 0, 0);
            if (gr < N) v = *(const uint4*)(Ab + (size_t)gr * 128 + kq * 8);
            *(uint4*)(As + SWZ(row, kq * 16)) = v;
        }
    }

    const int w = tid >> 6, lane = tid & 63;
    const int r15 = lane & 15;
    const int klo = (lane >> 4) << 4;
    const int cq = (lane >> 4) << 2;
    float g = 0.f;
    if (a.mode == 1) g = 1.f / (1.f + expf(-skipPtr[0]));

    for (int ct = 0; ct < a.colTiles; ++ct) {
        const int colBase = (blockIdx.x * a.colTiles + ct) * 64;
        __syncthreads();   // Bs free / As staged
#pragma unroll
        for (int it = 0; it < 4; ++it) {
            int lin = it * 256 + tid;
            int j = lin >> 4, kq = lin & 15;
            uint4 v = *(const uint4*)(Bt + (size_t)(colBase + j) * 128 + kq * 8);
            *(uint4*)(Bs + SWZ(j, kq * 16)) = v;
        }
        __syncthreads();

        f32x4 acc[2][4];
#pragma unroll
        for (int mt = 0; mt < 2; ++mt)
#pragma unroll
            for (int nt = 0; nt < 4; ++nt) acc[mt][nt] = (f32x4){0.f, 0.f, 0.f, 0.f};

#pragma unroll
        for (int kb = 0; kb < 4; ++kb) {
            int kbyte = kb * 64 + klo;
            short8 af[2], bf[4];
#pragma unroll
            for (int mt = 0; mt < 2; ++mt)
                af[mt] = *(short8*)(As + SWZ(w * 32 + mt * 16 + r15, kbyte));
#pragma unroll
            for (int nt = 0; nt < 4; ++nt)
                bf[nt] = *(short8*)(Bs + SWZ(nt * 16 + r15, kbyte));
#pragma unroll
            for (int mt = 0; mt < 2; ++mt)
#pragma unroll
                for (int nt = 0; nt < 4; ++nt)
                    acc[mt][nt] = __builtin_amdgcn_mfma_f32_16x16x32_bf16(bf[nt], af[mt], acc[mt][nt], 0, 0, 0);
        }

#pragma unroll
        for (int nt = 0; nt < 4; ++nt) {
            int col = colBase + nt * 16 + cq;
            float4 bi = *(const float4*)(bias + col);
            float c0 = 0.f, c1 = 0.f, c2 = 0.f, c3 = 0.f;   // column partials
#pragma unroll
            for (int mt = 0; mt < 2; ++mt) {
                int grow = rowBase + w * 32 + mt * 16 + r15;
                if (grow >= N) continue;
                float v0 = acc[mt][nt][0] + bi.x;
                float v1 = acc[mt][nt][1] + bi.y;
                float v2 = acc[mt][nt][2] + bi.z;
                float v3 = acc[mt][nt][3] + bi.w;
                if (a.mode == 2) {
                    uint2 p; p.x = pkbf(v0, v1); p.y = pkbf(v2, v3);
                    if (col < 128) {
                        *(uint2*)(QB + (size_t)grow * 128 + col) = p;
                    } else if (col < 256) {
                        *(uint2*)(KV + (size_t)grow * 256 + (col - 128)) = p;
                    } else {
                        *(uint2*)(KV + (size_t)grow * 256 + 128 + (col - 256)) = p;
                    }
                } else {
                    float4 xv = *(const float4*)(Xcur + (size_t)grow * 128 + col);
                    float o0 = fmaxf(g * v0 + (1.f - g) * xv.x, 0.f);
                    float o1 = fmaxf(g * v1 + (1.f - g) * xv.y, 0.f);
                    float o2 = fmaxf(g * v2 + (1.f - g) * xv.z, 0.f);
                    float o3 = fmaxf(g * v3 + (1.f - g) * xv.w, 0.f);
                    if (a.writeF32)
                        *(float4*)(Xn + (size_t)grow * 128 + col) = make_float4(o0, o1, o2, o3);
                    if (Xb) {
                        uint2 p; p.x = pkbf(o0, o1); p.y = pkbf(o2, o3);
                        *(uint2*)(Xb + (size_t)grow * 128 + col) = p;
                    }
                    c0 += o0; c1 += o1; c2 += o2; c3 += o3;
                }
            }
            if (doCol) {
                // reduce over the 16 r15 lanes (same cols)
#pragma unroll
                for (int sft = 1; sft <= 8; sft <<= 1) {
                    c0 += __shfl_xor(c0, sft);
                    c1 += __shfl_xor(c1, sft);
                    c2 += __shfl_xor(c2, sft);
                    c3 += __shfl_xor(c3, sft);
                }
                if (r15 == 0) {
                    int lcol = colBase + nt * 16 + cq;   // grid.x==1 for mode1 -> lcol in [0,128)
                    *(float4*)&sums[w][lcol] = make_float4(c0, c1, c2, c3);
                }
            }
        }
    }
    if (doCol) {
        __syncthreads();
        if (tid < 128) {
            float p = sums[0][tid] + sums[1][tid] + sums[2][tid] + sums[3][tid];
            a.colPart[(size_t)by * 128 + tid] = p;
        }
    }
}

// ---------- 3. fused out-proj(layer0) + QKV(layer1), two-stage GEMM ----------
__global__ __launch_bounds__(256) void fused_out_qkv(const u16* __restrict__ NUMD, const u16* __restrict__ NUMG,
                                                     const u16* __restrict__ aWt, const float* __restrict__ ab,
                                                     const float* __restrict__ skip,
                                                     const float* __restrict__ xd, const float* __restrict__ xg,
                                                     float* __restrict__ XD0, float* __restrict__ XG0,
                                                     const u16* __restrict__ BFt, const float* __restrict__ BB,
                                                     u16* __restrict__ QDB, u16* __restrict__ QGB,
                                                     u16* __restrict__ KVD, u16* __restrict__ KVG, int gy0) {
    __shared__ char As[128 * 256];
    __shared__ char Bs[64 * 256];
    const int tid = threadIdx.x;
    const int set = (blockIdx.x < (unsigned)gy0) ? 0 : 1;
    const int by = set ? (blockIdx.x - gy0) : blockIdx.x;
    const int rowBase = by * 128;
    const int N = set ? N_GENE : N_DRUG;
    const u16* A = set ? NUMG : NUMD;
    const u16* W1 = aWt + (size_t)set * 16384;           // layer 0: lt = set
    const float* b1 = ab + (size_t)set * 128;
    const float* Xc = set ? xg : xd;
    float* Xn = set ? XG0 : XD0;
    const u16* B2 = BFt + (size_t)(2 + set) * 384 * 128; // layer 1: lt = 2+set
    const float* bb2 = BB + (size_t)(2 + set) * 384;
    u16* QB = set ? QGB : QDB;
    u16* KV = set ? KVG : KVD;
    const float g = 1.f / (1.f + expf(-skip[set]));      // layer 0

    // stage As <- NUM (bf16)
#pragma unroll
    for (int it = 0; it < 8; ++it) {
        int lin = it * 256 + tid;
        int row = lin >> 4, kq = lin & 15;
        int gr = rowBase + row;
        uint4 v = make_uint4(0, 0, 0, 0);
        if (gr < N) v = *(const uint4*)(A + (size_t)gr * 128 + kq * 8);
        *(uint4*)(As + SWZ(row, kq * 16)) = v;
    }
    __syncthreads();

    const int w = tid >> 6, lane = tid & 63;
    const int r15 = lane & 15;
    const int klo = (lane >> 4) << 4;
    const int cq = (lane >> 4) << 2;

    // ---- stage 1: X = relu(g*(NUM@W1 + b1) + (1-g)*Xc) ----
    f32x4 acc1[2][2][4];
#pragma unroll
    for (int ct = 0; ct < 2; ++ct) {
#pragma unroll
        for (int it = 0; it < 4; ++it) {
            int lin = it * 256 + tid;
            int j = lin >> 4, kq = lin & 15;
            uint4 v = *(const uint4*)(W1 + (size_t)(ct * 64 + j) * 128 + kq * 8);
            *(uint4*)(Bs + SWZ(j, kq * 16)) = v;
        }
        __syncthreads();
#pragma unroll
        for (int mt = 0; mt < 2; ++mt)
#pragma unroll
            for (int nt = 0; nt < 4; ++nt) acc1[ct][mt][nt] = (f32x4){0.f, 0.f, 0.f, 0.f};
#pragma unroll
        for (int kb = 0; kb < 4; ++kb) {
            int kbyte = kb * 64 + klo;
            short8 af[2], bf[4];
#pragma unroll
            for (int mt = 0; mt < 2; ++mt)
                af[mt] = *(short8*)(As + SWZ(w * 32 + mt * 16 + r15, kbyte));
#pragma unroll
            for (int nt = 0; nt < 4; ++nt)
                bf[nt] = *(short8*)(Bs + SWZ(nt * 16 + r15, kbyte));
#pragma unroll
            for (int mt = 0; mt < 2; ++mt)
#pragma unroll
                for (int nt = 0; nt < 4; ++nt)
                    acc1[ct][mt][nt] = __builtin_amdgcn_mfma_f32_16x16x32_bf16(bf[nt], af[mt], acc1[ct][mt][nt], 0, 0, 0);
        }
        __syncthreads();   // Bs consumed
    }
    // epilogue 1: write X f32 (layer-1 skip input), repack X bf16 into As (own rows only)
#pragma unroll
    for (int ct = 0; ct < 2; ++ct) {
#pragma unroll
        for (int nt = 0; nt < 4; ++nt) {
            int col = ct * 64 + nt * 16 + cq;
            float4 bi = *(const float4*)(b1 + col);
#pragma unroll
            for (int mt = 0; mt < 2; ++mt) {
                int row = w * 32 + mt * 16 + r15;
                int grow = rowBase + row;
                if (grow >= N) continue;
                float4 xv = *(const float4*)(Xc + (size_t)grow * 128 + col);
                float o0 = fmaxf(g * (acc1[ct][mt][nt][0] + bi.x) + (1.f - g) * xv.x, 0.f);
                float o1 = fmaxf(g * (acc1[ct][mt][nt][1] + bi.y) + (1.f - g) * xv.y, 0.f);
                float o2 = fmaxf(g * (acc1[ct][mt][nt][2] + bi.z) + (1.f - g) * xv.z, 0.f);
                float o3 = fmaxf(g * (acc1[ct][mt][nt][3] + bi.w) + (1.f - g) * xv.w, 0.f);
                *(float4*)(Xn + (size_t)grow * 128 + col) = make_float4(o0, o1, o2, o3);
                uint2 p; p.x = pkbf(o0, o1); p.y = pkbf(o2, o3);
                *(uint2*)(As + SWZ(row, col * 2)) = p;
            }
        }
    }
    // no barrier needed: each wave reads only its own As rows in stage 2

    // ---- stage 2: QKV = X @ B2 + bb2 ----
    for (int ct2 = 0; ct2 < 6; ++ct2) {
#pragma unroll
        for (int it = 0; it < 4; ++it) {
            int lin = it * 256 + tid;
            int j = lin >> 4, kq = lin & 15;
            uint4 v = *(const uint4*)(B2 + (size_t)(ct2 * 64 + j) * 128 + kq * 8);
            *(uint4*)(Bs + SWZ(j, kq * 16)) = v;
        }
        __syncthreads();
        f32x4 acc[2][4];
#pragma unroll
        for (int mt = 0; mt < 2; ++mt)
#pragma unroll
            for (int nt = 0; nt < 4; ++nt) acc[mt][nt] = (f32x4){0.f, 0.f, 0.f, 0.f};
#pragma unroll
        for (int kb = 0; kb < 4; ++kb) {
            int kbyte = kb * 64 + klo;
            short8 af[2], bf[4];
#pragma unroll
            for (int mt = 0; mt < 2; ++mt)
                af[mt] = *(short8*)(As + SWZ(w * 32 + mt * 16 + r15, kbyte));
#pragma unroll
            for (int nt = 0; nt < 4; ++nt)
                bf[nt] = *(short8*)(Bs + SWZ(nt * 16 + r15, kbyte));
#pragma unroll
            for (int mt = 0; mt < 2; ++mt)
#pragma unroll
                for (int nt = 0; nt < 4; ++nt)
                    acc[mt][nt] = __builtin_amdgcn_mfma_f32_16x16x32_bf16(bf[nt], af[mt], acc[mt][nt], 0, 0, 0);
        }
#pragma unroll
        for (int nt = 0; nt < 4; ++nt) {
            int col = ct2 * 64 + nt * 16 + cq;
            float4 bi = *(const float4*)(bb2 + col);
#pragma unroll
            for (int mt = 0; mt < 2; ++mt) {
                int grow = rowBase + w * 32 + mt * 16 + r15;
                if (grow >= N) continue;
                float v0 = acc[mt][nt][0] + bi.x;
                float v1 = acc[mt][nt][1] + bi.y;
                float v2 = acc[mt][nt][2] + bi.z;
                float v3 = acc[mt][nt][3] + bi.w;
                uint2 p; p.x = pkbf(v0, v1); p.y = pkbf(v2, v3);
                if (col < 128) {
                    *(uint2*)(QB + (size_t)grow * 128 + col) = p;
                } else if (col < 256) {
                    *(uint2*)(KV + (size_t)grow * 256 + (col - 128)) = p;
                } else {
                    *(uint2*)(KV + (size_t)grow * 256 + 128 + (col - 256)) = p;
                }
            }
        }
        __syncthreads();   // Bs consumed before next tile
    }
}

// ---------- 4. CSR build: merged histogram ----------
__global__ void hist2(const int* __restrict__ d0, int* __restrict__ c0,
                      const int* __restrict__ d1, int* __restrict__ c1, int gridE) {
    int b = blockIdx.x;
    const int* d; int* c; int bb;
    if (b < gridE) { d = d0; c = c0; bb = b; } else { d = d1; c = c1; bb = b - gridE; }
    int e = bb * 256 + threadIdx.x;
    if (e < NEDGE) atomicAdd(c + d[e], 1);
}

// ---------- 5. CSR build: hierarchical scan ----------
#define SCAN_NBG 10
#define SCAN_NBD 5
__global__ __launch_bounds__(256) void scan_local(const int* __restrict__ cntG,
                                                  const int* __restrict__ cntD,
                                                  int* __restrict__ outG, int* __restrict__ outD,
                                                  int* __restrict__ bsum) {
    __shared__ int tmp[256];
    int b = blockIdx.x, t = threadIdx.x;
    const int* cnt; int* out; int n; int cbase;
    if (b < SCAN_NBG) { cnt = cntG; out = outG; n = N_GENE; cbase = b * 4096; }
    else { cnt = cntD; out = outD; n = N_DRUG; cbase = (b - SCAN_NBG) * 4096; }
    int base = cbase + t * 16;
    int v[16], s = 0;
#pragma unroll
    for (int i = 0; i < 16; ++i) { int idx = base + i; v[i] = (idx < n) ? cnt[idx] : 0; s += v[i]; }
    tmp[t] = s;
    __syncthreads();
    for (int off = 1; off < 256; off <<= 1) {
        int add = (t >= off) ? tmp[t - off] : 0;
        __syncthreads();
        tmp[t] += add;
        __syncthreads();
    }
    int run = tmp[t] - s;
#pragma unroll
    for (int i = 0; i < 16; ++i) { int idx = base + i; if (idx < n) out[idx] = run; run += v[i]; }
    if (t == 255) bsum[b] = tmp[255];
}

// scan_add with inlined bsum prefix (bsum holds RAW block totals)
__global__ __launch_bounds__(256) void scan_add2(int* __restrict__ outG, int* __restrict__ outD,
                                                 const int* __restrict__ bsum) {
    int b = blockIdx.x, t = threadIdx.x;
    int* out; int n; int cbase; int o = 0;
    if (b < SCAN_NBG) {
        out = outG; n = N_GENE; cbase = b * 4096;
        for (int i = 0; i < b; ++i) o += bsum[i];
    } else {
        out = outD; n = N_DRUG; cbase = (b - SCAN_NBG) * 4096;
        for (int i = SCAN_NBG; i < b; ++i) o += bsum[i];
    }
    int base = cbase + t * 16;
#pragma unroll
    for (int i = 0; i < 16; ++i) { int idx = base + i; if (idx < n) out[idx] += o; }
    if (t == 0 && b == SCAN_NBG - 1) outG[N_GENE] = NEDGE;
    if (t == 0 && b == SCAN_NBG + SCAN_NBD - 1) outD[N_DRUG] = NEDGE;
}

// ---------- 6. CSR build: merged scatter (count-down cursor) ----------
__global__ void scatter2(const int* __restrict__ s0, const int* __restrict__ d0,
                         const int* __restrict__ r0, int* __restrict__ cur0, int* __restrict__ o0,
                         const int* __restrict__ s1, const int* __restrict__ d1,
                         const int* __restrict__ r1, int* __restrict__ cur1, int* __restrict__ o1,
                         int gridE) {
    int b = blockIdx.x;
    const int *src, *dst, *row; int *cursor, *outp; int bb;
    if (b < gridE) { src = s0; dst = d0; row = r0; cursor = cur0; outp = o0; bb = b; }
    else { src = s1; dst = d1; row = r1; cursor = cur1; outp = o1; bb = b - gridE; }
    int e = bb * 256 + threadIdx.x;
    if (e < NEDGE) {
        int d = dst[e];
        int pos = row[d] + atomicSub(cursor + d, 1) - 1;
        outp[pos] = src[e];
    }
}

// ---------- 7. merged fused attention, 2-deep prefetch, tmax guard ----------
__global__ __launch_bounds__(256) void fused_attn(const int* __restrict__ rowG,
                                                  const int* __restrict__ srcG,
                                                  const u16* __restrict__ QGB,
                                                  const u16* __restrict__ KVD,
                                                  u16* __restrict__ NUMG,
                                                  const int* __restrict__ rowD,
                                                  const int* __restrict__ srcD,
                                                  const u16* __restrict__ QDB,
                                                  const u16* __restrict__ KVG,
                                                  u16* __restrict__ NUMD) {
    int node = (blockIdx.x * 256 + threadIdx.x) >> 6;
    int lane = threadIdx.x & 63;
    const int* rowStart; const int* srcSorted; const u16* Qb; const u16* KV; u16* out; int nd;
    if (node < N_GENE) { rowStart = rowG; srcSorted = srcG; Qb = QGB; KV = KVD; out = NUMG; nd = node; }
    else if (node < N_GENE + N_DRUG) { rowStart = rowD; srcSorted = srcD; Qb = QDB; KV = KVG; out = NUMD; nd = node - N_GENE; }
    else return;
    const int g = lane >> 4;
    const int sl = lane & 15;

    float qr[8];
    {
        uint4 qv = *(const uint4*)(Qb + (size_t)nd * 128 + sl * 8);
        qr[0] = bflo(qv.x); qr[1] = bfhi(qv.x);
        qr[2] = bflo(qv.y); qr[3] = bfhi(qv.y);
        qr[4] = bflo(qv.z); qr[5] = bfhi(qv.z);
        qr[6] = bflo(qv.w); qr[7] = bfhi(qv.w);
    }
    int beg = rowStart[nd], end = rowStart[nd + 1];
    float s = 0.f;
    float acc[8] = {0.f, 0.f, 0.f, 0.f, 0.f, 0.f, 0.f, 0.f};

#define FETCH(t, kk, vv)                                                \
    {                                                                   \
        int sid = __shfl(sids, 4 * (t) + g);                            \
        const u16* rowp = KV + ((size_t)sid << 8);                      \
        kk = *(const uint4*)(rowp + sl * 8);                            \
        vv = *(const uint4*)(rowp + 128 + sl * 8);                      \
    }
#define COMPUTE(t, kk, vv)                                              \
    {                                                                   \
        float part = qr[0] * bflo(kk.x) + qr[1] * bfhi(kk.x)            \
                   + qr[2] * bflo(kk.y) + qr[3] * bfhi(kk.y)            \
                   + qr[4] * bflo(kk.z) + qr[5] * bfhi(kk.z)            \
                   + qr[6] * bflo(kk.w) + qr[7] * bfhi(kk.w);           \
        part += __shfl_xor(part, 1);                                    \
        part += __shfl_xor(part, 2);                                    \
        float a = ((t) < tm) ? __expf(part) : 0.f;                      \
        s += a;                                                         \
        acc[0] += a * bflo(vv.x); acc[1] += a * bfhi(vv.x);             \
        acc[2] += a * bflo(vv.y); acc[3] += a * bfhi(vv.y);             \
        acc[4] += a * bflo(vv.z); acc[5] += a * bfhi(vv.z);             \
        acc[6] += a * bflo(vv.w); acc[7] += a * bfhi(vv.w);             \
    }

    for (int base = beg; base < end; base += 64) {
        int bn = end - base; if (bn > 64) bn = 64;
        int ld = base + lane; if (ld > end - 1) ld = end - 1;
        int sids = srcSorted[ld];
        int nIter = (bn + 3) >> 2;
        int tm = (bn - g + 3) >> 2;    // valid iterations for this edge slot
        uint4 k0, v0, k1, v1;
        FETCH(0, k0, v0);
        for (int t = 0; t < nIter; t += 2) {
            if (t + 1 < nIter) FETCH(t + 1, k1, v1);
            COMPUTE(t, k0, v0);
            if (t + 1 >= nIter) break;
            if (t + 2 < nIter) FETCH(t + 2, k0, v0);
            COMPUTE(t + 1, k1, v1);
        }
    }
#undef FETCH
#undef COMPUTE

    // cross-group reduce: all lanes end with full sums
    s += __shfl_xor(s, 16);
    s += __shfl_xor(s, 32);
#pragma unroll
    for (int j = 0; j < 8; ++j) {
        acc[j] += __shfl_xor(acc[j], 16);
        acc[j] += __shfl_xor(acc[j], 32);
    }
    // epilogue spread across all 64 lanes: lane (g,sl) handles dims {sl*8+2g, sl*8+2g+1}
    float inv = 1.f / (s + 1e-16f);
    float a0, a1;
    if (g == 0)      { a0 = acc[0]; a1 = acc[1]; }
    else if (g == 1) { a0 = acc[2]; a1 = acc[3]; }
    else if (g == 2) { a0 = acc[4]; a1 = acc[5]; }
    else             { a0 = acc[6]; a1 = acc[7]; }
    float r0 = gelu_exact(a0 * inv);
    float r1 = gelu_exact(a1 * inv);
    *(u32*)(out + (size_t)nd * 128 + sl * 8 + 2 * g) = pkbf(r0, r1);
}

// ---------- 8. predictor: gsum-reduce + c2 + MLP ----------
__global__ __launch_bounds__(256) void predictor_mfma(const u16* __restrict__ Xdb,
                                                      const int* __restrict__ didx,
                                                      const u16* __restrict__ W1at,
                                                      const float* __restrict__ colPart, int nParts,
                                                      const float* __restrict__ pW1,
                                                      const float* __restrict__ pb1,
                                                      const float* __restrict__ pW2,
                                                      const float* __restrict__ pb2,
                                                      float* __restrict__ out) {
    __shared__ char As[128 * 256];
    __shared__ char Bs[128 * 256];
    __shared__ float gsL[128];
    __shared__ float c2s[128];
    const int tid = threadIdx.x;
    const int rowBase = blockIdx.x * 128;

#pragma unroll
    for (int it = 0; it < 8; ++it) {
        int lin = it * 256 + tid;
        int row = lin >> 4, kq = lin & 15;
        int dn = didx[rowBase + row];
        uint4 v = *(const uint4*)(Xdb + (size_t)dn * 128 + kq * 8);
        *(uint4*)(As + SWZ(row, kq * 16)) = v;
        uint4 wv = *(const uint4*)(W1at + (size_t)row * 128 + kq * 8);
        *(uint4*)(Bs + SWZ(row, kq * 16)) = wv;
    }
    // gene mean from column partials
    if (tid < 128) {
        float sum = 0.f;
        for (int b = 0; b < nParts; ++b) sum += colPart[(size_t)b * 128 + tid];
        gsL[tid] = sum * (1.f / 40000.f);
    }
    __syncthreads();
    if (tid < 128) {
        float s = pb1[tid];
        for (int k = 0; k < 128; ++k) s += gsL[k] * pW1[(size_t)(128 + k) * 128 + tid];
        c2s[tid] = s;
    }
    __syncthreads();

    const int w = tid >> 6, lane = tid & 63;
    const int r15 = lane & 15;
    const int klo = (lane >> 4) << 4;
    f32x4 acc[2][8];
#pragma unroll
    for (int mt = 0; mt < 2; ++mt)
#pragma unroll
        for (int nt = 0; nt < 8; ++nt) acc[mt][nt] = (f32x4){0.f, 0.f, 0.f, 0.f};

#pragma unroll
    for (int kb = 0; kb < 4; ++kb) {
        int kbyte = kb * 64 + klo;
        short8 af[2], bf[8];
#pragma unroll
        for (int mt = 0; mt < 2; ++mt) af[mt] = *(short8*)(As + SWZ(w * 32 + mt * 16 + r15, kbyte));
#pragma unroll
        for (int nt = 0; nt < 8; ++nt) bf[nt] = *(short8*)(Bs + SWZ(nt * 16 + r15, kbyte));
#pragma unroll
        for (int mt = 0; mt < 2; ++mt)
#pragma unroll
            for (int nt = 0; nt < 8; ++nt)
                acc[mt][nt] = __builtin_amdgcn_mfma_f32_16x16x32_bf16(af[mt], bf[nt], acc[mt][nt], 0, 0, 0);
    }

    float c2v[8], w2v[8];
#pragma unroll
    for (int nt = 0; nt < 8; ++nt) {
        int col = nt * 16 + r15;
        c2v[nt] = c2s[col];
        w2v[nt] = pW2[col];
    }
    float bias2 = pb2[0];
#pragma unroll
    for (int mt = 0; mt < 2; ++mt) {
#pragma unroll
        for (int r = 0; r < 4; ++r) {
            float rsum = 0.f;
#pragma unroll
            for (int nt = 0; nt < 8; ++nt)
                rsum += fmaxf(acc[mt][nt][r] + c2v[nt], 0.f) * w2v[nt];
            rsum += __shfl_xor(rsum, 1);
            rsum += __shfl_xor(rsum, 2);
            rsum += __shfl_xor(rsum, 4);
            rsum += __shfl_xor(rsum, 8);
            if (r15 == 0)
                out[rowBase + w * 32 + mt * 16 + ((lane >> 4) << 2) + r] = rsum + bias2;
        }
    }
}

// ---------- launch ----------
extern "C" void kernel_launch(void* const* d_in, const int* in_sizes, int n_in,
                              void* d_out, int out_size, void* d_ws, size_t ws_size,
                              hipStream_t stream) {
    const float* x_drug = (const float*)d_in[0];
    const float* x_gene = (const float*)d_in[1];
    const float* kW = (const float*)d_in[2];
    const float* kb = (const float*)d_in[3];
    const float* qW = (const float*)d_in[4];
    const float* qb = (const float*)d_in[5];
    const float* vW = (const float*)d_in[6];
    const float* vb = (const float*)d_in[7];
    const float* aW = (const float*)d_in[8];
    const float* ab = (const float*)d_in[9];
    const float* skip = (const float*)d_in[10];
    const float* a_rel = (const float*)d_in[11];
    const float* m_rel = (const float*)d_in[12];
    const float* p_rel = (const float*)d_in[13];
    const float* pW1 = (const float*)d_in[14];
    const float* pb1 = (const float*)d_in[15];
    const float* pW2 = (const float*)d_in[16];
    const float* pb2 = (const float*)d_in[17];
    const int* e_dg_s = (const int*)d_in[18];
    const int* e_dg_d = (const int*)d_in[19];
    const int* e_gd_s = (const int*)d_in[20];
    const int* e_gd_d = (const int*)d_in[21];
    const int* drug_idx = (const int*)d_in[22];

    const int gyD = (N_DRUG + 127) / 128;   // 157
    const int gyG = (N_GENE + 127) / 128;   // 313
    const int gyT = gyD + gyG;              // 470

    // ---- workspace layout ----
    char* base = (char*)d_ws;
    size_t off = 0;
    auto alloc = [&](size_t bytes) { char* p = base + off; off += (bytes + 255) & ~(size_t)255; return p; };
    u16*   QDB  = (u16*)alloc((size_t)N_DRUG * 128 * 2);
    u16*   QGB  = (u16*)alloc((size_t)N_GENE * 128 * 2);
    u16*   KVD  = (u16*)alloc((size_t)N_DRUG * 256 * 2);
    u16*   KVG  = (u16*)alloc((size_t)N_GENE * 256 * 2);
    float* XD0  = (float*)alloc((size_t)N_DRUG * 128 * 4);
    float* XG0  = (float*)alloc((size_t)N_GENE * 128 * 4);
    u16*   XDb  = (u16*)alloc((size_t)N_DRUG * 128 * 2);
    u16*   NUMD = (u16*)alloc((size_t)N_DRUG * 128 * 2);
    u16*   NUMG = (u16*)alloc((size_t)N_GENE * 128 * 2);
    u16*   BFt  = (u16*)alloc((size_t)2 * 2 * 384 * 128 * 2);
    float* BB   = (float*)alloc((size_t)2 * 2 * 384 * 4);
    u16*   aWt  = (u16*)alloc((size_t)2 * 2 * 128 * 128 * 2);
    u16*   W1at = (u16*)alloc((size_t)128 * 128 * 2);
    float* colPart = (float*)alloc((size_t)gyG * 128 * 4);
    int* rowG = (int*)alloc(40001 * 4);
    int* rowD = (int*)alloc(20001 * 4);
    int* cntG = (int*)alloc(40000 * 4);     // 160000 B (256-aligned) -> cntD contiguous
    int* cntD = (int*)alloc(20000 * 4);
    int* bsum = (int*)alloc(64 * 4);
    int* srcG = (int*)alloc((size_t)NEDGE * 4);
    int* srcD = (int*)alloc((size_t)NEDGE * 4);

    prologue<<<1323, 256, 0, stream>>>(kW, kb, qW, qb, vW, vb, a_rel, m_rel, p_rel,
                                       aW, pW1, BFt, BB, aWt, W1at, cntG);

    // ---- build CSR by destination ----
    const int gridE = (NEDGE + 255) / 256;
    hist2<<<2 * gridE, 256, 0, stream>>>(e_dg_d, cntG, e_gd_d, cntD, gridE);
    scan_local<<<SCAN_NBG + SCAN_NBD, 256, 0, stream>>>(cntG, cntD, rowG, rowD, bsum);
    scan_add2<<<SCAN_NBG + SCAN_NBD, 256, 0, stream>>>(rowG, rowD, bsum);
    scatter2<<<2 * gridE, 256, 0, stream>>>(e_dg_s, e_dg_d, rowG, cntG, srcG,
                                            e_gd_s, e_gd_d, rowD, cntD, srcD, gridE);

    // ---- layer 0 QKV ----
    GArgs qa = {};
    qa.Af0 = x_drug; qa.Af1 = x_gene;
    qa.N0 = N_DRUG;  qa.N1 = N_GENE; qa.gy0 = gyD;
    qa.Bt0 = BFt;                    qa.Bt1 = BFt + (size_t)1 * 384 * 128;
    qa.bias0 = BB;                   qa.bias1 = BB + 384;
    qa.QB0 = QDB; qa.QB1 = QGB; qa.KV0 = KVD; qa.KV1 = KVG;
    qa.afmt = 0; qa.colTiles = 3; qa.mode = 2; qa.writeF32 = 0;
    gemm_mfma<<<dim3(2, gyT), 256, 0, stream>>>(qa);

    // ---- layer 0 attention ----
    fused_attn<<<(N_GENE + N_DRUG + 3) / 4, 256, 0, stream>>>(
        rowG, srcG, QGB, KVD, NUMG, rowD, srcD, QDB, KVG, NUMD);

    // ---- layer 0 out-proj fused with layer 1 QKV ----
    fused_out_qkv<<<gyT, 256, 0, stream>>>(NUMD, NUMG, aWt, ab, skip, x_drug, x_gene,
                                           XD0, XG0, BFt, BB, QDB, QGB, KVD, KVG, gyD);

    // ---- layer 1 attention ----
    fused_attn<<<(N_GENE + N_DRUG + 3) / 4, 256, 0, stream>>>(
        rowG, srcG, QGB, KVD, NUMG, rowD, srcD, QDB, KVG, NUMD);

    // ---- layer 1 out-proj (+ gene column partials) ----
    GArgs oa = {};
    oa.Ab0 = NUMD; oa.Ab1 = NUMG;
    oa.N0 = N_DRUG; oa.N1 = N_GENE; oa.gy0 = gyD;
    oa.Bt0 = aWt + (size_t)2 * 16384; oa.Bt1 = aWt + (size_t)3 * 16384;
    oa.bias0 = ab + 2 * 128;          oa.bias1 = ab + 3 * 128;
    oa.skip0 = skip + 2;              oa.skip1 = skip + 3;
    oa.Xc0 = XD0; oa.Xc1 = XG0;
    oa.Xb0 = XDb; oa.Xb1 = nullptr;
    oa.colPart = colPart;
    oa.afmt = 1; oa.colTiles = 2; oa.mode = 1; oa.writeF32 = 0;
    gemm_mfma<<<dim3(1, gyT), 256, 0, stream>>>(oa);

    // ---- predictor (gsum reduce + c2 + MLP) ----
    predictor_mfma<<<NBATCH / 128, 256, 0, stream>>>(XDb, drug_idx, W1at, colPart, gyG,
                                                     pW1, pb1, pW2, pb2, (float*)d_out);
}